// Round 1
// baseline (5039.901 us; speedup 1.0000x reference)
//
#include <hip/hip_runtime.h>
#include <hip/hip_bf16.h>
#include <cstddef>

#define N_NODES 50000
#define N_EDGES 800000
#define N_REL 8
#define F_IN 256
#define F_HID 512
#define F_OUT 128

// ---------- int64-vs-int32 edge dtype detection ----------
// If harness pushed int64, the int32 view of edge_type has 0 at every odd
// index (high words of values 0..7). If int32, odd slots are random 0..7
// (P(all 64 zero) = 8^-64 ~ 0).
__global__ void detect64_kernel(const int* __restrict__ et, int* __restrict__ flag) {
    int v = et[2 * threadIdx.x + 1];
    unsigned long long any = __ballot(v != 0);
    if (threadIdx.x == 0) flag[0] = (any == 0ULL) ? 1 : 0;
}

__device__ __forceinline__ long long ld_idx(const void* __restrict__ p, size_t i, int is64) {
    return is64 ? ((const long long*)p)[i] : (long long)((const int*)p)[i];
}

// ---------- per-(dst, rel) edge counts ----------
__global__ void count_kernel(const void* __restrict__ etype, const void* __restrict__ eidx,
                             const int* __restrict__ flag, float* __restrict__ cnt) {
    int e = blockIdx.x * blockDim.x + threadIdx.x;
    if (e >= N_EDGES) return;
    int is64 = flag[0];
    long long rt  = ld_idx(etype, e, is64);
    long long dst = ld_idx(eidx, (size_t)N_EDGES + e, is64);
    atomicAdd(&cnt[dst * N_REL + rt], 1.0f);
}

__global__ void inv_kernel(const float* __restrict__ cnt, float* __restrict__ invc) {
    int i = blockIdx.x * blockDim.x + threadIdx.x;
    if (i >= N_NODES * N_REL) return;
    invc[i] = 1.0f / fmaxf(cnt[i], 1.0f);
}

// ---------- scatter-add of source features into agg[n][rl][f] ----------
// one wave (64 lanes) per edge; F/64 coalesced f32 atomics per lane
__global__ void scatter_kernel(const float* __restrict__ X, int F,
                               const void* __restrict__ eidx, const void* __restrict__ etype,
                               const int* __restrict__ flag,
                               float* __restrict__ agg, int r0, int cR) {
    int wid  = (blockIdx.x * blockDim.x + threadIdx.x) >> 6;
    int lane = threadIdx.x & 63;
    if (wid >= N_EDGES) return;
    int is64 = flag[0];
    long long rt = ld_idx(etype, wid, is64);
    int rl = (int)rt - r0;
    if (rl < 0 || rl >= cR) return;
    long long src = ld_idx(eidx, wid, is64);
    long long dst = ld_idx(eidx, (size_t)N_EDGES + wid, is64);
    const float* xr = X + (size_t)src * F;
    float* ar = agg + ((size_t)dst * cR + rl) * (size_t)F;
    for (int f = lane; f < F; f += 64) atomicAdd(&ar[f], xr[f]);
}

// ---------- in-place scale agg rows by 1/max(cnt,1) ----------
__global__ void scale_kernel(float* __restrict__ agg, const float* __restrict__ invc,
                             int F4, int r0, int cR) {
    long long g = (long long)blockIdx.x * blockDim.x + threadIdx.x;
    long long tot = (long long)N_NODES * cR * F4;
    if (g >= tot) return;
    int cf  = cR * F4;
    int n   = (int)(g / cf);
    int rem = (int)(g % cf);
    int rl  = rem / F4;
    float s = invc[(size_t)n * N_REL + r0 + rl];
    float4* p = (float4*)agg + g;
    float4 v = *p;
    v.x *= s; v.y *= s; v.z *= s; v.w *= s;
    *p = v;
}

// ---------- tiled f32 GEMM: C[M,Nc] (+)= [A1 | A2] x [B1 ; B2] (+bias)(relu) ----------
#define BM 64
#define BN 64
#define BK 32

__global__ __launch_bounds__(256) void gemm_kernel(
    const float* __restrict__ A1, int K1, int lda1,
    const float* __restrict__ A2, int K2, int lda2,
    const float* __restrict__ B1, const float* __restrict__ B2,
    const float* __restrict__ bias,
    float* __restrict__ C, int M, int Nc,
    int accumulate, int do_relu)
{
    __shared__ float As[BK][BM + 4];
    __shared__ float Bs[BK][BN + 4];
    int bm = blockIdx.y * BM;
    int bn = blockIdx.x * BN;
    int tid = threadIdx.x;
    int tx = tid & 15, ty = tid >> 4;
    float acc[4][4] = {};
    int Ktot = K1 + K2;
    for (int k0 = 0; k0 < Ktot; k0 += BK) {
        const float* A; const float* B; int kbase; int lda;
        if (k0 < K1) { A = A1; B = B1; kbase = k0;      lda = lda1; }
        else         { A = A2; B = B2; kbase = k0 - K1; lda = lda2; }
        #pragma unroll
        for (int it = 0; it < 2; ++it) {
            int li = tid + it * 256;
            int m  = li >> 3;
            int kk = (li & 7) << 2;
            float4 v = make_float4(0.f, 0.f, 0.f, 0.f);
            int gm = bm + m;
            if (gm < M) v = *(const float4*)&A[(size_t)gm * lda + kbase + kk];
            As[kk + 0][m] = v.x; As[kk + 1][m] = v.y;
            As[kk + 2][m] = v.z; As[kk + 3][m] = v.w;
        }
        #pragma unroll
        for (int it = 0; it < 2; ++it) {
            int li = tid + it * 256;
            int kk = li >> 4;
            int n  = (li & 15) << 2;
            float4 v = *(const float4*)&B[(size_t)(kbase + kk) * Nc + bn + n];
            *(float4*)&Bs[kk][n] = v;
        }
        __syncthreads();
        #pragma unroll
        for (int k = 0; k < BK; ++k) {
            float a[4], b[4];
            *(float4*)a = *(const float4*)&As[k][ty << 2];
            *(float4*)b = *(const float4*)&Bs[k][tx << 2];
            #pragma unroll
            for (int i = 0; i < 4; ++i)
                #pragma unroll
                for (int j = 0; j < 4; ++j)
                    acc[i][j] = fmaf(a[i], b[j], acc[i][j]);
        }
        __syncthreads();
    }
    float bv[4] = {0.f, 0.f, 0.f, 0.f};
    if (bias) { *(float4*)bv = *(const float4*)&bias[bn + (tx << 2)]; }
    #pragma unroll
    for (int i = 0; i < 4; ++i) {
        int gm = bm + (ty << 2) + i;
        if (gm >= M) continue;
        float* cp = &C[(size_t)gm * Nc + bn + (tx << 2)];
        float4 v;
        v.x = acc[i][0] + bv[0]; v.y = acc[i][1] + bv[1];
        v.z = acc[i][2] + bv[2]; v.w = acc[i][3] + bv[3];
        if (accumulate) {
            float4 c = *(const float4*)cp;
            v.x += c.x; v.y += c.y; v.z += c.z; v.w += c.w;
        }
        if (do_relu) {
            v.x = fmaxf(v.x, 0.f); v.y = fmaxf(v.y, 0.f);
            v.z = fmaxf(v.z, 0.f); v.w = fmaxf(v.w, 0.f);
        }
        *(float4*)cp = v;
    }
}

// ---------- row log_softmax over 128 cols, one wave per row ----------
__global__ void logsoftmax_kernel(float* __restrict__ h) {
    int row  = blockIdx.x * 4 + (threadIdx.x >> 6);
    int lane = threadIdx.x & 63;
    if (row >= N_NODES) return;
    float* p = h + (size_t)row * F_OUT;
    float a = p[lane], b = p[lane + 64];
    float m = fmaxf(a, b);
    #pragma unroll
    for (int o = 32; o > 0; o >>= 1) m = fmaxf(m, __shfl_xor(m, o));
    float s = expf(a - m) + expf(b - m);
    #pragma unroll
    for (int o = 32; o > 0; o >>= 1) s += __shfl_xor(s, o);
    float lse = m + logf(s);
    p[lane] = a - lse;
    p[lane + 64] = b - lse;
}

extern "C" void kernel_launch(void* const* d_in, const int* in_sizes, int n_in,
                              void* d_out, int out_size, void* d_ws, size_t ws_size,
                              hipStream_t stream) {
    const float* x     = (const float*)d_in[0];
    const void*  eidx  = d_in[1];
    const void*  etype = d_in[2];
    const float* w1    = (const float*)d_in[3];
    const float* root1 = (const float*)d_in[4];
    const float* b1    = (const float*)d_in[5];
    const float* w2    = (const float*)d_in[6];
    const float* root2 = (const float*)d_in[7];
    const float* b2    = (const float*)d_in[8];

    float* h_out = (float*)d_out;                          // [N,128] logits -> log_softmax
    float* emb   = (float*)d_out + (size_t)N_NODES * F_OUT; // [N,512] relu output

    char*  ws   = (char*)d_ws;
    int*   flag = (int*)ws;                                 // 256B header
    float* cnt  = (float*)(ws + 256);
    float* invc = cnt + (size_t)N_NODES * N_REL;
    float* agg  = invc + (size_t)N_NODES * N_REL;
    size_t hdr  = 256 + 2 * (size_t)N_NODES * N_REL * 4;
    size_t aggAvail = (ws_size > hdr) ? (ws_size - hdr) : 0;

    int cR1 = (int)(aggAvail / ((size_t)N_NODES * F_IN * 4));
    cR1 = cR1 > N_REL ? N_REL : (cR1 < 1 ? 1 : cR1);
    int cR2 = (int)(aggAvail / ((size_t)N_NODES * F_HID * 4));
    cR2 = cR2 > N_REL ? N_REL : (cR2 < 1 ? 1 : cR2);

    hipMemsetAsync(cnt, 0, (size_t)N_NODES * N_REL * 4, stream);
    detect64_kernel<<<1, 64, 0, stream>>>((const int*)etype, flag);
    count_kernel<<<(N_EDGES + 255) / 256, 256, 0, stream>>>(etype, eidx, flag, cnt);
    inv_kernel<<<(N_NODES * N_REL + 255) / 256, 256, 0, stream>>>(cnt, invc);

    // ---------------- layer 1 ----------------
    for (int r0 = 0; r0 < N_REL; r0 += cR1) {
        int cR = (cR1 < N_REL - r0) ? cR1 : (N_REL - r0);
        hipMemsetAsync(agg, 0, (size_t)N_NODES * cR * F_IN * 4, stream);
        scatter_kernel<<<(N_EDGES * 64 + 255) / 256, 256, 0, stream>>>(
            x, F_IN, eidx, etype, flag, agg, r0, cR);
        long long tot4 = (long long)N_NODES * cR * (F_IN / 4);
        scale_kernel<<<(int)((tot4 + 255) / 256), 256, 0, stream>>>(agg, invc, F_IN / 4, r0, cR);
        int first = (r0 == 0);
        int last  = (r0 + cR >= N_REL);
        dim3 grid(F_HID / BN, (N_NODES + BM - 1) / BM);
        gemm_kernel<<<grid, 256, 0, stream>>>(
            agg, cR * F_IN, cR * F_IN,
            first ? x : nullptr, first ? F_IN : 0, F_IN,
            w1 + (size_t)r0 * F_IN * F_HID, root1,
            first ? b1 : nullptr,
            emb, N_NODES, F_HID,
            first ? 0 : 1, last ? 1 : 0);
    }

    // ---------------- layer 2 ----------------
    for (int r0 = 0; r0 < N_REL; r0 += cR2) {
        int cR = (cR2 < N_REL - r0) ? cR2 : (N_REL - r0);
        hipMemsetAsync(agg, 0, (size_t)N_NODES * cR * F_HID * 4, stream);
        scatter_kernel<<<(N_EDGES * 64 + 255) / 256, 256, 0, stream>>>(
            emb, F_HID, eidx, etype, flag, agg, r0, cR);
        long long tot4 = (long long)N_NODES * cR * (F_HID / 4);
        scale_kernel<<<(int)((tot4 + 255) / 256), 256, 0, stream>>>(agg, invc, F_HID / 4, r0, cR);
        int first = (r0 == 0);
        dim3 grid(F_OUT / BN, (N_NODES + BM - 1) / BM);
        gemm_kernel<<<grid, 256, 0, stream>>>(
            agg, cR * F_HID, cR * F_HID,
            first ? emb : nullptr, first ? F_HID : 0, F_HID,
            w2 + (size_t)r0 * F_HID * F_OUT, root2,
            first ? b2 : nullptr,
            h_out, N_NODES, F_OUT,
            first ? 0 : 1, 0);
    }

    logsoftmax_kernel<<<(N_NODES + 3) / 4, 256, 0, stream>>>(h_out);
}

// Round 2
// 2181.918 us; speedup vs baseline: 2.3098x; 2.3098x over previous
//
#include <hip/hip_runtime.h>
#include <hip/hip_bf16.h>
#include <cstddef>
#include <cstdint>

#define N_NODES 50000
#define N_EDGES 800000
#define N_REL 8
#define F_IN 256
#define F_HID 512
#define F_OUT 128

typedef __attribute__((ext_vector_type(8))) short short8;   // 8 bf16 (4 VGPRs)
typedef __attribute__((ext_vector_type(4))) float f32x4;    // MFMA C/D

// ---------- int64-vs-int32 edge dtype detection ----------
__global__ void detect64_kernel(const int* __restrict__ et, int* __restrict__ flag) {
    int v = et[2 * threadIdx.x + 1];
    unsigned long long any = __ballot(v != 0);
    if (threadIdx.x == 0) flag[0] = (any == 0ULL) ? 1 : 0;
}

__device__ __forceinline__ long long ld_idx(const void* __restrict__ p, size_t i, int is64) {
    return is64 ? ((const long long*)p)[i] : (long long)((const int*)p)[i];
}

// ---------- per-(dst, rel) edge counts ----------
__global__ void count_kernel(const void* __restrict__ etype, const void* __restrict__ eidx,
                             const int* __restrict__ flag, float* __restrict__ cnt) {
    int e = blockIdx.x * blockDim.x + threadIdx.x;
    if (e >= N_EDGES) return;
    int is64 = flag[0];
    long long rt  = ld_idx(etype, e, is64);
    long long dst = ld_idx(eidx, (size_t)N_EDGES + e, is64);
    atomicAdd(&cnt[dst * N_REL + rt], 1.0f);
}

__global__ void inv_kernel(const float* __restrict__ cnt, float* __restrict__ invc) {
    int i = blockIdx.x * blockDim.x + threadIdx.x;
    if (i >= N_NODES * N_REL) return;
    invc[i] = 1.0f / fmaxf(cnt[i], 1.0f);
}

// ---------- layer-1 scatter: agg[n][rl][f] += x[src][f] * invc[dst,rt] ----------
__global__ void scatter1_kernel(const float* __restrict__ X,
                                const void* __restrict__ eidx, const void* __restrict__ etype,
                                const int* __restrict__ flag, const float* __restrict__ invc,
                                float* __restrict__ agg, int r0, int cR) {
    int wid  = (blockIdx.x * blockDim.x + threadIdx.x) >> 6;
    int lane = threadIdx.x & 63;
    if (wid >= N_EDGES) return;
    int is64 = flag[0];
    long long rt = ld_idx(etype, wid, is64);
    int rl = (int)rt - r0;
    if (rl < 0 || rl >= cR) return;
    long long src = ld_idx(eidx, wid, is64);
    long long dst = ld_idx(eidx, (size_t)N_EDGES + wid, is64);
    float s = invc[dst * N_REL + rt];
    const float* xr = X + (size_t)src * F_IN;
    float* ar = agg + ((size_t)dst * cR + rl) * (size_t)F_IN;
    #pragma unroll
    for (int it = 0; it < F_IN / 64; ++it) {
        int f = lane + it * 64;
        atomicAdd(&ar[f], xr[f] * s);
    }
}

// ---------- f32 -> bf16 convert (4 elems / thread) ----------
__global__ void cvt_bf16_kernel(const float* __restrict__ in, __hip_bfloat16* __restrict__ out,
                                long long n4) {
    long long g = (long long)blockIdx.x * blockDim.x + threadIdx.x;
    if (g >= n4) return;
    float4 v = ((const float4*)in)[g];
    __hip_bfloat162 lo, hi;
    lo.x = __float2bfloat16(v.x); lo.y = __float2bfloat16(v.y);
    hi.x = __float2bfloat16(v.z); hi.y = __float2bfloat16(v.w);
    *(__hip_bfloat162*)&out[4 * g]     = lo;
    *(__hip_bfloat162*)&out[4 * g + 2] = hi;
}

// ---------- weight preps: build BT[n][k] bf16 (K-transposed) ----------
__global__ void make_bt1_kernel(const float* __restrict__ w1, const float* __restrict__ root1,
                                __hip_bfloat16* __restrict__ bt) {
    int g = blockIdx.x * blockDim.x + threadIdx.x;
    if (g >= F_HID * (N_REL * F_IN + F_IN)) return;
    const int Kt = N_REL * F_IN + F_IN; // 2304
    int n = g / Kt, k = g % Kt;
    float v;
    if (k < N_REL * F_IN) v = w1[(size_t)(k >> 8) * F_IN * F_HID + (size_t)(k & 255) * F_HID + n];
    else                  v = root1[(size_t)(k - N_REL * F_IN) * F_HID + n];
    bt[g] = __float2bfloat16(v);
}

__global__ void make_bt2_kernel(const float* __restrict__ w2, __hip_bfloat16* __restrict__ bt) {
    int g = blockIdx.x * blockDim.x + threadIdx.x;
    if (g >= N_REL * F_OUT * F_HID) return;
    int n = g / F_HID, k = g % F_HID;
    int r = n >> 7, o = n & 127;
    bt[g] = __float2bfloat16(w2[(size_t)r * F_HID * F_OUT + (size_t)k * F_OUT + o]);
}

__global__ void make_rt2_kernel(const float* __restrict__ root2, __hip_bfloat16* __restrict__ bt) {
    int g = blockIdx.x * blockDim.x + threadIdx.x;
    if (g >= F_OUT * F_HID) return;
    int o = g / F_HID, k = g % F_HID;
    bt[g] = __float2bfloat16(root2[(size_t)k * F_OUT + o]);
}

// ---------- bf16 MFMA GEMM ----------
// C[M,Nc] (+)= [A1 | A2] x B, where B is given K-transposed: BT[n][k].
// A1: [M,K1] lda1, A2: [M,K2] lda2 (bf16, row-major). BTa/BTb: rows n (len ldbt),
// BTa holds k in [0,K1), BTb holds k in [0,K2) (both offset views into one array).
// Epilogue: +bias (opt), +C (opt accumulate, f32), relu (opt); writes f32 Cf (opt)
// and bf16 Cb (opt).
#define GBM 128
#define GBN 128
#define GBK 64

__global__ __launch_bounds__(256) void gemm_mfma_kernel(
    const __hip_bfloat16* __restrict__ A1, int K1, int lda1,
    const __hip_bfloat16* __restrict__ A2, int K2, int lda2,
    const __hip_bfloat16* __restrict__ BTa, const __hip_bfloat16* __restrict__ BTb, int ldbt,
    const float* __restrict__ bias,
    float* __restrict__ Cf, __hip_bfloat16* __restrict__ Cb,
    int M, int Nc, int accumulate, int do_relu)
{
    __shared__ __align__(16) __hip_bfloat16 As[GBM * GBK]; // [128][64] row-major (m,k)
    __shared__ __align__(16) __hip_bfloat16 Bs[GBN * GBK]; // [128][64] row-major (n,k)

    const int bm = blockIdx.y * GBM;
    const int bn = blockIdx.x * GBN;
    const int lane = threadIdx.x & 63;
    const int wv   = threadIdx.x >> 6;   // 0..3
    const int wr   = wv >> 1;            // wave row (0/1): 64 rows
    const int wc   = wv & 1;             // wave col (0/1): 64 cols
    const int r15  = lane & 15;
    const int ksel = lane >> 4;          // 0..3

    f32x4 acc[4][4] = {};
    const int Ktot = K1 + K2;

    for (int k0 = 0; k0 < Ktot; k0 += GBK) {
        // ---- stage A tile (16 KB) + B tile (16 KB), 4 segs each per wave ----
        const int seg_row = lane >> 3;        // 0..7 rows within segment
        const int seg_col = (lane & 7) * 8;   // bf16 col
        #pragma unroll
        for (int c = 0; c < 4; ++c) {
            int s = wv * 4 + c;               // 0..15
            int row = s * 8 + seg_row;        // 0..127
            int gr = bm + row; if (gr >= M) gr = M - 1;
            const __hip_bfloat16* gp;
            if (k0 < K1) gp = A1 + (size_t)gr * lda1 + (k0 + seg_col);
            else         gp = A2 + (size_t)gr * lda2 + (k0 - K1 + seg_col);
            __builtin_amdgcn_global_load_lds(
                (const __attribute__((address_space(1))) void*)gp,
                (__attribute__((address_space(3))) void*)&As[s * 512], 16, 0, 0);
        }
        #pragma unroll
        for (int c = 0; c < 4; ++c) {
            int s = wv * 4 + c;
            int n = bn + s * 8 + seg_row;     // always < Nc (Nc % 128 == 0)
            const __hip_bfloat16* gp;
            if (k0 < K1) gp = BTa + (size_t)n * ldbt + (k0 + seg_col);
            else         gp = BTb + (size_t)n * ldbt + (k0 - K1 + seg_col);
            __builtin_amdgcn_global_load_lds(
                (const __attribute__((address_space(1))) void*)gp,
                (__attribute__((address_space(3))) void*)&Bs[s * 512], 16, 0, 0);
        }
        __syncthreads();

        // ---- fragments + MFMA ----
        short8 a[4][2], b[4][2];
        #pragma unroll
        for (int i = 0; i < 4; ++i)
            #pragma unroll
            for (int h = 0; h < 2; ++h)
                a[i][h] = *(const short8*)&As[(wr * 64 + i * 16 + r15) * GBK + h * 32 + ksel * 8];
        #pragma unroll
        for (int j = 0; j < 4; ++j)
            #pragma unroll
            for (int h = 0; h < 2; ++h)
                b[j][h] = *(const short8*)&Bs[(wc * 64 + j * 16 + r15) * GBK + h * 32 + ksel * 8];
        #pragma unroll
        for (int i = 0; i < 4; ++i)
            #pragma unroll
            for (int j = 0; j < 4; ++j)
                #pragma unroll
                for (int h = 0; h < 2; ++h)
                    acc[i][j] = __builtin_amdgcn_mfma_f32_16x16x32_bf16(
                        a[i][h], b[j][h], acc[i][j], 0, 0, 0);
        __syncthreads();
    }

    // ---- epilogue ----
    float bv[4];
    #pragma unroll
    for (int j = 0; j < 4; ++j)
        bv[j] = bias ? bias[bn + wc * 64 + j * 16 + r15] : 0.0f;

    #pragma unroll
    for (int i = 0; i < 4; ++i) {
        #pragma unroll
        for (int q = 0; q < 4; ++q) {
            int row = bm + wr * 64 + i * 16 + ksel * 4 + q;
            if (row >= M) continue;
            #pragma unroll
            for (int j = 0; j < 4; ++j) {
                int col = bn + wc * 64 + j * 16 + r15;
                float v = acc[i][j][q] + bv[j];
                size_t off = (size_t)row * Nc + col;
                if (accumulate) v += Cf[off];
                if (do_relu) v = fmaxf(v, 0.0f);
                if (Cf) Cf[off] = v;
                if (Cb) Cb[off] = __float2bfloat16(v);
            }
        }
    }
}

// ---------- layer-2 scatter: h[dst] += z[src, r*128 + :] * invc[dst,r] ----------
__global__ void scatter2_kernel(const __hip_bfloat16* __restrict__ z,
                                const void* __restrict__ eidx, const void* __restrict__ etype,
                                const int* __restrict__ flag, const float* __restrict__ invc,
                                float* __restrict__ h) {
    int wid  = (blockIdx.x * blockDim.x + threadIdx.x) >> 6;
    int lane = threadIdx.x & 63;
    if (wid >= N_EDGES) return;
    int is64 = flag[0];
    long long rt  = ld_idx(etype, wid, is64);
    long long src = ld_idx(eidx, wid, is64);
    long long dst = ld_idx(eidx, (size_t)N_EDGES + wid, is64);
    float s = invc[dst * N_REL + rt];
    const __hip_bfloat16* zr = z + (size_t)src * (N_REL * F_OUT) + rt * F_OUT;
    __hip_bfloat162 v = *(const __hip_bfloat162*)&zr[2 * lane];
    float* hp = h + (size_t)dst * F_OUT + 2 * lane;
    atomicAdd(hp,     __bfloat162float(v.x) * s);
    atomicAdd(hp + 1, __bfloat162float(v.y) * s);
}

// ---------- row log_softmax over 128 cols, one wave per row ----------
__global__ void logsoftmax_kernel(float* __restrict__ h) {
    int row  = blockIdx.x * 4 + (threadIdx.x >> 6);
    int lane = threadIdx.x & 63;
    if (row >= N_NODES) return;
    float* p = h + (size_t)row * F_OUT;
    float a = p[lane], b = p[lane + 64];
    float m = fmaxf(a, b);
    #pragma unroll
    for (int o = 32; o > 0; o >>= 1) m = fmaxf(m, __shfl_xor(m, o));
    float s = expf(a - m) + expf(b - m);
    #pragma unroll
    for (int o = 32; o > 0; o >>= 1) s += __shfl_xor(s, o);
    float lse = m + logf(s);
    p[lane] = a - lse;
    p[lane + 64] = b - lse;
}

extern "C" void kernel_launch(void* const* d_in, const int* in_sizes, int n_in,
                              void* d_out, int out_size, void* d_ws, size_t ws_size,
                              hipStream_t stream) {
    const float* x     = (const float*)d_in[0];
    const void*  eidx  = d_in[1];
    const void*  etype = d_in[2];
    const float* w1    = (const float*)d_in[3];
    const float* root1 = (const float*)d_in[4];
    const float* b1    = (const float*)d_in[5];
    const float* w2    = (const float*)d_in[6];
    const float* root2 = (const float*)d_in[7];
    const float* b2    = (const float*)d_in[8];

    float* h_out = (float*)d_out;                            // [N,128]
    float* emb   = (float*)d_out + (size_t)N_NODES * F_OUT;  // [N,512] f32 (output #2)

    // ---- workspace carve-up ----
    char* ws = (char*)d_ws;
    size_t off = 0;
    auto take = [&](size_t bytes) { char* p = ws + off; off = (off + bytes + 255) & ~(size_t)255; return p; };
    int*   flag = (int*)take(256);
    float* cnt  = (float*)take((size_t)N_NODES * N_REL * 4);
    float* invc = (float*)take((size_t)N_NODES * N_REL * 4);
    __hip_bfloat16* xb   = (__hip_bfloat16*)take((size_t)N_NODES * F_IN * 2);
    __hip_bfloat16* embb = (__hip_bfloat16*)take((size_t)N_NODES * F_HID * 2);
    __hip_bfloat16* z    = (__hip_bfloat16*)take((size_t)N_NODES * N_REL * F_OUT * 2);
    __hip_bfloat16* bt1  = (__hip_bfloat16*)take((size_t)F_HID * (N_REL * F_IN + F_IN) * 2);
    __hip_bfloat16* bt2  = (__hip_bfloat16*)take((size_t)N_REL * F_OUT * F_HID * 2);
    __hip_bfloat16* rt2  = (__hip_bfloat16*)take((size_t)F_OUT * F_HID * 2);

    size_t avail = (ws_size > off) ? (ws_size - off) : 0;
    // per-relation chunk: agg f32 + aggb bf16 = N * 256 * 6 bytes
    int cR1 = (int)(avail / ((size_t)N_NODES * F_IN * 6));
    cR1 = cR1 > N_REL ? N_REL : (cR1 < 1 ? 1 : cR1);
    float* agg = (float*)take((size_t)N_NODES * cR1 * F_IN * 4);
    __hip_bfloat16* aggb = (__hip_bfloat16*)take((size_t)N_NODES * cR1 * F_IN * 2);

    // ---- one-time (per call) preps ----
    cvt_bf16_kernel<<<(N_NODES * F_IN / 4 + 255) / 256, 256, 0, stream>>>(
        x, xb, (long long)N_NODES * F_IN / 4);
    {
        int tot = F_HID * (N_REL * F_IN + F_IN);
        make_bt1_kernel<<<(tot + 255) / 256, 256, 0, stream>>>(w1, root1, bt1);
        tot = N_REL * F_OUT * F_HID;
        make_bt2_kernel<<<(tot + 255) / 256, 256, 0, stream>>>(w2, bt2);
        tot = F_OUT * F_HID;
        make_rt2_kernel<<<(tot + 255) / 256, 256, 0, stream>>>(root2, rt2);
    }
    hipMemsetAsync(cnt, 0, (size_t)N_NODES * N_REL * 4, stream);
    detect64_kernel<<<1, 64, 0, stream>>>((const int*)etype, flag);
    count_kernel<<<(N_EDGES + 255) / 256, 256, 0, stream>>>(etype, eidx, flag, cnt);
    inv_kernel<<<(N_NODES * N_REL + 255) / 256, 256, 0, stream>>>(cnt, invc);

    const int MBLK = (N_NODES + GBM - 1) / GBM; // 391

    // ---------------- layer 1: emb = relu([agg | x] @ [w1; root1] + b1) ----------------
    for (int r0 = 0; r0 < N_REL; r0 += cR1) {
        int cR = (cR1 < N_REL - r0) ? cR1 : (N_REL - r0);
        hipMemsetAsync(agg, 0, (size_t)N_NODES * cR * F_IN * 4, stream);
        scatter1_kernel<<<(N_EDGES * 64 + 255) / 256, 256, 0, stream>>>(
            x, eidx, etype, flag, invc, agg, r0, cR);
        long long n4 = (long long)N_NODES * cR * F_IN / 4;
        cvt_bf16_kernel<<<(int)((n4 + 255) / 256), 256, 0, stream>>>(agg, aggb, n4);
        int first = (r0 == 0), last = (r0 + cR >= N_REL);
        dim3 grid(F_HID / GBN, MBLK);
        gemm_mfma_kernel<<<grid, 256, 0, stream>>>(
            aggb, cR * F_IN, cR * F_IN,
            first ? xb : nullptr, first ? F_IN : 0, F_IN,
            bt1 + (size_t)r0 * F_IN, bt1 + (size_t)N_REL * F_IN, N_REL * F_IN + F_IN,
            first ? b1 : nullptr,
            emb, last ? embb : nullptr,
            N_NODES, F_HID, first ? 0 : 1, last ? 1 : 0);
    }

    // ---------------- layer 2 (transform-first) ----------------
    // z[n, r*128+o] = emb_b[n] @ w2[r]   (bf16 out)
    {
        dim3 grid((N_REL * F_OUT) / GBN, MBLK);
        gemm_mfma_kernel<<<grid, 256, 0, stream>>>(
            embb, F_HID, F_HID, nullptr, 0, 0,
            bt2, nullptr, F_HID,
            nullptr, nullptr, z, N_NODES, N_REL * F_OUT, 0, 0);
    }
    // h = emb_b @ root2 + b2   (f32 out, then scatter adds)
    {
        dim3 grid(F_OUT / GBN, MBLK);
        gemm_mfma_kernel<<<grid, 256, 0, stream>>>(
            embb, F_HID, F_HID, nullptr, 0, 0,
            rt2, nullptr, F_HID,
            b2, h_out, nullptr, N_NODES, F_OUT, 0, 0);
    }
    scatter2_kernel<<<(N_EDGES * 64 + 255) / 256, 256, 0, stream>>>(
        z, eidx, etype, flag, invc, h_out);

    logsoftmax_kernel<<<(N_NODES + 3) / 4, 256, 0, stream>>>(h_out);
}

// Round 4
// 835.312 us; speedup vs baseline: 6.0336x; 2.6121x over previous
//
#include <hip/hip_runtime.h>
#include <hip/hip_bf16.h>
#include <cstddef>
#include <cstdint>

#define N_NODES 50000
#define N_EDGES 800000
#define N_REL 8
#define F_IN 256
#define F_HID 512
#define F_OUT 128
#define NC2 (N_REL * F_OUT + F_OUT)   // 1152: w2 cols + root2 cols

typedef __attribute__((ext_vector_type(8))) short short8;   // 8 bf16 (4 VGPRs)
typedef __attribute__((ext_vector_type(4))) float f32x4;    // MFMA C/D

__device__ __forceinline__ float bf2f(unsigned short u) {
    return __uint_as_float(((unsigned)u) << 16);
}
__device__ __forceinline__ unsigned short f2bf(float f) {
    __hip_bfloat16 h = __float2bfloat16(f);
    return *reinterpret_cast<unsigned short*>(&h);
}

// ---------- int64-vs-int32 edge dtype detection ----------
__global__ void detect64_kernel(const int* __restrict__ et, int* __restrict__ flag) {
    int v = et[2 * threadIdx.x + 1];
    unsigned long long any = __ballot(v != 0);
    if (threadIdx.x == 0) flag[0] = (any == 0ULL) ? 1 : 0;
}

__device__ __forceinline__ long long ld_idx(const void* __restrict__ p, size_t i, int is64) {
    return is64 ? ((const long long*)p)[i] : (long long)((const int*)p)[i];
}

// ---------- per-(dst, rel) edge counts (int) ----------
__global__ void count_kernel(const void* __restrict__ etype, const void* __restrict__ eidx,
                             const int* __restrict__ flag, unsigned* __restrict__ cnt8) {
    int e = blockIdx.x * blockDim.x + threadIdx.x;
    if (e >= N_EDGES) return;
    int is64 = flag[0];
    long long rt  = ld_idx(etype, e, is64);
    long long dst = ld_idx(eidx, (size_t)N_EDGES + e, is64);
    atomicAdd(&cnt8[dst * N_REL + rt], 1u);
}

__global__ void inv_kernel(const unsigned* __restrict__ cnt8, float* __restrict__ invc) {
    int i = blockIdx.x * blockDim.x + threadIdx.x;
    if (i >= N_NODES * N_REL) return;
    unsigned c = cnt8[i];
    invc[i] = 1.0f / (float)(c ? c : 1u);
}

// ---------- single-block exclusive scan of per-dst counts ----------
__global__ __launch_bounds__(1024) void scan_kernel(const unsigned* __restrict__ cnt8,
                                                    int* __restrict__ offsets) {
    __shared__ int lds[1024];
    const int t = threadIdx.x;
    const int CH = (N_NODES + 1023) / 1024;  // 49
    int lo = t * CH;
    int hi = lo + CH; if (hi > N_NODES) hi = N_NODES;
    if (lo > N_NODES) lo = N_NODES;
    int s = 0;
    for (int i = lo; i < hi; ++i) {
        int c = 0;
        #pragma unroll
        for (int r = 0; r < N_REL; ++r) c += (int)cnt8[i * N_REL + r];
        s += c;
    }
    lds[t] = s;
    __syncthreads();
    for (int o = 1; o < 1024; o <<= 1) {
        int v = (t >= o) ? lds[t - o] : 0;
        __syncthreads();
        lds[t] += v;
        __syncthreads();
    }
    int run = (t == 0) ? 0 : lds[t - 1];
    for (int i = lo; i < hi; ++i) {
        offsets[i] = run;
        int c = 0;
        #pragma unroll
        for (int r = 0; r < N_REL; ++r) c += (int)cnt8[i * N_REL + r];
        run += c;
    }
    if (t == 1023) offsets[N_NODES] = run;
}

// ---------- bucket edges into CSR: ebuf[pos] = (src<<3)|rel ----------
__global__ void build_kernel(const void* __restrict__ eidx, const void* __restrict__ etype,
                             const int* __restrict__ flag, const int* __restrict__ offsets,
                             int* __restrict__ cursor, unsigned* __restrict__ ebuf) {
    int e = blockIdx.x * blockDim.x + threadIdx.x;
    if (e >= N_EDGES) return;
    int is64 = flag[0];
    int rt  = (int)ld_idx(etype, e, is64);
    int src = (int)ld_idx(eidx, e, is64);
    int dst = (int)ld_idx(eidx, (size_t)N_EDGES + e, is64);
    int pos = offsets[dst] + atomicAdd(&cursor[dst], 1);
    ebuf[pos] = ((unsigned)src << 3) | (unsigned)rt;
}

// ---------- f32 -> bf16 convert (4 elems / thread) ----------
__global__ void cvt_bf16_kernel(const float* __restrict__ in, __hip_bfloat16* __restrict__ out,
                                long long n4) {
    long long g = (long long)blockIdx.x * blockDim.x + threadIdx.x;
    if (g >= n4) return;
    float4 v = ((const float4*)in)[g];
    unsigned short o[4];
    o[0] = f2bf(v.x); o[1] = f2bf(v.y); o[2] = f2bf(v.z); o[3] = f2bf(v.w);
    *(short4*)&out[4 * g] = *(const short4*)o;
}

// ---------- weight preps: BT[n][k] bf16 (K-transposed) ----------
__global__ void make_bt1_kernel(const float* __restrict__ w1, const float* __restrict__ root1,
                                __hip_bfloat16* __restrict__ bt) {
    int g = blockIdx.x * blockDim.x + threadIdx.x;
    const int Kt = N_REL * F_IN + F_IN; // 2304
    if (g >= F_HID * Kt) return;
    int n = g / Kt, k = g % Kt;
    float v;
    if (k < N_REL * F_IN) v = w1[(size_t)(k >> 8) * F_IN * F_HID + (size_t)(k & 255) * F_HID + n];
    else                  v = root1[(size_t)(k - N_REL * F_IN) * F_HID + n];
    bt[g] = __float2bfloat16(v);
}

__global__ void make_bt2_kernel(const float* __restrict__ w2, const float* __restrict__ root2,
                                __hip_bfloat16* __restrict__ bt) {
    int g = blockIdx.x * blockDim.x + threadIdx.x;
    if (g >= NC2 * F_HID) return;
    int n = g / F_HID, k = g % F_HID;
    float v = (n < N_REL * F_OUT)
                  ? w2[(size_t)(n >> 7) * F_HID * F_OUT + (size_t)k * F_OUT + (n & 127)]
                  : root2[(size_t)k * F_OUT + (n - N_REL * F_OUT)];
    bt[g] = __float2bfloat16(v);
}

// ---------- layer-1 gather: one wave per dst, all rels in registers ----------
template <int CR>
__global__ __launch_bounds__(256) void gather1_kernel(
    const __hip_bfloat16* __restrict__ xb, const unsigned* __restrict__ ebuf,
    const int* __restrict__ offsets, const float* __restrict__ invc,
    __hip_bfloat16* __restrict__ aggb, int r0)
{
    int wid  = (blockIdx.x * blockDim.x + threadIdx.x) >> 6;
    int lane = threadIdx.x & 63;
    if (wid >= N_NODES) return;
    int e0 = offsets[wid], e1 = offsets[wid + 1];
    float acc[CR][4];
    #pragma unroll
    for (int c = 0; c < CR; ++c)
        #pragma unroll
        for (int j = 0; j < 4; ++j) acc[c][j] = 0.0f;

    for (int e = e0; e < e1; ++e) {
        unsigned u = ebuf[e];
        int rl = (int)(u & 7u) - r0;
        if (CR < N_REL && (unsigned)rl >= (unsigned)CR) continue;
        unsigned src = u >> 3;
        short4 v = *(const short4*)&xb[(size_t)src * F_IN + lane * 4];
        float f0 = bf2f((unsigned short)v.x), f1 = bf2f((unsigned short)v.y);
        float f2 = bf2f((unsigned short)v.z), f3 = bf2f((unsigned short)v.w);
        int rls = __builtin_amdgcn_readfirstlane(rl);
        #pragma unroll
        for (int c = 0; c < CR; ++c)
            if (rls == c) { acc[c][0] += f0; acc[c][1] += f1; acc[c][2] += f2; acc[c][3] += f3; }
    }
    #pragma unroll
    for (int c = 0; c < CR; ++c) {
        float s = invc[(size_t)wid * N_REL + r0 + c];
        unsigned short o[4];
        o[0] = f2bf(acc[c][0] * s);
        o[1] = f2bf(acc[c][1] * s);
        o[2] = f2bf(acc[c][2] * s);
        o[3] = f2bf(acc[c][3] * s);
        *(short4*)&aggb[((size_t)wid * CR + c) * F_IN + lane * 4] = *(const short4*)o;
    }
}

// ---------- layer-2 gather + root + bias + log_softmax, one wave per dst ----------
__global__ __launch_bounds__(256) void gather2_kernel(
    const __hip_bfloat16* __restrict__ z, const unsigned* __restrict__ ebuf,
    const int* __restrict__ offsets, const float* __restrict__ invc,
    const float* __restrict__ b2, float* __restrict__ h)
{
    int wid  = (blockIdx.x * blockDim.x + threadIdx.x) >> 6;
    int lane = threadIdx.x & 63;
    if (wid >= N_NODES) return;
    int e0 = offsets[wid], e1 = offsets[wid + 1];
    float a0 = 0.0f, a1 = 0.0f;
    for (int e = e0; e < e1; ++e) {
        unsigned u = ebuf[e];
        int rt = (int)(u & 7u);
        unsigned src = u >> 3;
        float s = invc[(size_t)wid * N_REL + rt];
        unsigned pv = *(const unsigned*)&z[(size_t)src * NC2 + rt * F_OUT + lane * 2];
        a0 += s * bf2f((unsigned short)(pv & 0xffffu));
        a1 += s * bf2f((unsigned short)(pv >> 16));
    }
    unsigned rv = *(const unsigned*)&z[(size_t)wid * NC2 + N_REL * F_OUT + lane * 2];
    a0 += bf2f((unsigned short)(rv & 0xffffu)) + b2[lane * 2];
    a1 += bf2f((unsigned short)(rv >> 16))     + b2[lane * 2 + 1];

    float m = fmaxf(a0, a1);
    #pragma unroll
    for (int o = 32; o > 0; o >>= 1) m = fmaxf(m, __shfl_xor(m, o));
    float sum = expf(a0 - m) + expf(a1 - m);
    #pragma unroll
    for (int o = 32; o > 0; o >>= 1) sum += __shfl_xor(sum, o);
    float lse = m + logf(sum);
    h[(size_t)wid * F_OUT + lane * 2]     = a0 - lse;
    h[(size_t)wid * F_OUT + lane * 2 + 1] = a1 - lse;
}

// ---------- bf16 MFMA GEMM ----------
#define GBM 128
#define GBN 128
#define GBK 64

__global__ __launch_bounds__(256) void gemm_mfma_kernel(
    const __hip_bfloat16* __restrict__ A1, int K1, int lda1,
    const __hip_bfloat16* __restrict__ A2, int K2, int lda2,
    const __hip_bfloat16* __restrict__ BTa, const __hip_bfloat16* __restrict__ BTb, int ldbt,
    const float* __restrict__ bias,
    float* __restrict__ Cf, __hip_bfloat16* __restrict__ Cb,
    int M, int Nc, int accumulate, int do_relu)
{
    __shared__ __align__(16) __hip_bfloat16 As[GBM * GBK];
    __shared__ __align__(16) __hip_bfloat16 Bs[GBN * GBK];

    const int bm = blockIdx.y * GBM;
    const int bn = blockIdx.x * GBN;
    const int lane = threadIdx.x & 63;
    const int wv   = threadIdx.x >> 6;
    const int wr   = wv >> 1;
    const int wc   = wv & 1;
    const int r15  = lane & 15;
    const int ksel = lane >> 4;

    f32x4 acc[4][4] = {};
    const int Ktot = K1 + K2;

    for (int k0 = 0; k0 < Ktot; k0 += GBK) {
        const int seg_row = lane >> 3;
        const int seg_col = (lane & 7) * 8;
        #pragma unroll
        for (int c = 0; c < 4; ++c) {
            int s = wv * 4 + c;
            int row = s * 8 + seg_row;
            int gr = bm + row; if (gr >= M) gr = M - 1;
            const __hip_bfloat16* gp;
            if (k0 < K1) gp = A1 + (size_t)gr * lda1 + (k0 + seg_col);
            else         gp = A2 + (size_t)gr * lda2 + (k0 - K1 + seg_col);
            __builtin_amdgcn_global_load_lds(
                (const __attribute__((address_space(1))) void*)gp,
                (__attribute__((address_space(3))) void*)&As[s * 512], 16, 0, 0);
        }
        #pragma unroll
        for (int c = 0; c < 4; ++c) {
            int s = wv * 4 + c;
            int n = bn + s * 8 + seg_row;
            const __hip_bfloat16* gp;
            if (k0 < K1) gp = BTa + (size_t)n * ldbt + (k0 + seg_col);
            else         gp = BTb + (size_t)n * ldbt + (k0 - K1 + seg_col);
            __builtin_amdgcn_global_load_lds(
                (const __attribute__((address_space(1))) void*)gp,
                (__attribute__((address_space(3))) void*)&Bs[s * 512], 16, 0, 0);
        }
        __syncthreads();

        short8 a[4][2], b[4][2];
        #pragma unroll
        for (int i = 0; i < 4; ++i)
            #pragma unroll
            for (int h = 0; h < 2; ++h)
                a[i][h] = *(const short8*)&As[(wr * 64 + i * 16 + r15) * GBK + h * 32 + ksel * 8];
        #pragma unroll
        for (int j = 0; j < 4; ++j)
            #pragma unroll
            for (int h = 0; h < 2; ++h)
                b[j][h] = *(const short8*)&Bs[(wc * 64 + j * 16 + r15) * GBK + h * 32 + ksel * 8];
        #pragma unroll
        for (int i = 0; i < 4; ++i)
            #pragma unroll
            for (int j = 0; j < 4; ++j)
                #pragma unroll
                for (int h = 0; h < 2; ++h)
                    acc[i][j] = __builtin_amdgcn_mfma_f32_16x16x32_bf16(
                        a[i][h], b[j][h], acc[i][j], 0, 0, 0);
        __syncthreads();
    }

    float bv[4];
    #pragma unroll
    for (int j = 0; j < 4; ++j)
        bv[j] = bias ? bias[bn + wc * 64 + j * 16 + r15] : 0.0f;

    #pragma unroll
    for (int i = 0; i < 4; ++i) {
        #pragma unroll
        for (int q = 0; q < 4; ++q) {
            int row = bm + wr * 64 + i * 16 + ksel * 4 + q;
            if (row >= M) continue;
            #pragma unroll
            for (int j = 0; j < 4; ++j) {
                int col = bn + wc * 64 + j * 16 + r15;
                float v = acc[i][j][q] + bv[j];
                size_t off = (size_t)row * Nc + col;
                if (accumulate) v += Cf[off];
                if (do_relu) v = fmaxf(v, 0.0f);
                if (Cf) Cf[off] = v;
                if (Cb) Cb[off] = __float2bfloat16(v);
            }
        }
    }
}

extern "C" void kernel_launch(void* const* d_in, const int* in_sizes, int n_in,
                              void* d_out, int out_size, void* d_ws, size_t ws_size,
                              hipStream_t stream) {
    const float* x     = (const float*)d_in[0];
    const void*  eidx  = d_in[1];
    const void*  etype = d_in[2];
    const float* w1    = (const float*)d_in[3];
    const float* root1 = (const float*)d_in[4];
    const float* b1    = (const float*)d_in[5];
    const float* w2    = (const float*)d_in[6];
    const float* root2 = (const float*)d_in[7];
    const float* b2    = (const float*)d_in[8];

    float* h_out = (float*)d_out;                            // [N,128]
    float* emb   = (float*)d_out + (size_t)N_NODES * F_OUT;  // [N,512] f32 (output #2)

    // ---- workspace carve-up ----
    char* ws = (char*)d_ws;
    size_t off = 0;
    auto take = [&](size_t bytes) { char* p = ws + off; off = (off + bytes + 255) & ~(size_t)255; return p; };
    int*      flag    = (int*)take(256);
    unsigned* cnt8    = (unsigned*)take((size_t)N_NODES * N_REL * 4);
    float*    invc    = (float*)take((size_t)N_NODES * N_REL * 4);
    int*      offsets = (int*)take(((size_t)N_NODES + 1) * 4);
    int*      cursor  = (int*)take((size_t)N_NODES * 4);
    unsigned* ebuf    = (unsigned*)take((size_t)N_EDGES * 4);
    __hip_bfloat16* xb   = (__hip_bfloat16*)take((size_t)N_NODES * F_IN * 2);
    __hip_bfloat16* embb = (__hip_bfloat16*)take((size_t)N_NODES * F_HID * 2);
    __hip_bfloat16* bt1  = (__hip_bfloat16*)take((size_t)F_HID * (N_REL * F_IN + F_IN) * 2);
    __hip_bfloat16* bt2  = (__hip_bfloat16*)take((size_t)NC2 * F_HID * 2);

    size_t avail = (ws_size > off) ? (ws_size - off) : 0;
    size_t agg8bytes = (size_t)N_NODES * N_REL * F_IN * 2;   // 204.8 MB
    size_t zbytes    = (size_t)N_NODES * NC2 * 2;            // 115.2 MB
    int CR = (avail >= agg8bytes) ? 8 : 4;
    size_t ubytes = agg8bytes > zbytes ? agg8bytes : zbytes;
    if (CR == 4) ubytes = zbytes;
    char* uni = take(ubytes);
    __hip_bfloat16* aggb = (__hip_bfloat16*)uni;   // layer-1 A-tile (dead after GEMM1)
    __hip_bfloat16* z    = (__hip_bfloat16*)uni;   // layer-2 transformed msgs (aliases aggb)

    // ---- prep ----
    detect64_kernel<<<1, 64, 0, stream>>>((const int*)etype, flag);
    (void)hipMemsetAsync(cnt8, 0, (size_t)N_NODES * N_REL * 4, stream);
    (void)hipMemsetAsync(cursor, 0, (size_t)N_NODES * 4, stream);
    count_kernel<<<(N_EDGES + 255) / 256, 256, 0, stream>>>(etype, eidx, flag, cnt8);
    inv_kernel<<<(N_NODES * N_REL + 255) / 256, 256, 0, stream>>>(cnt8, invc);
    scan_kernel<<<1, 1024, 0, stream>>>(cnt8, offsets);
    build_kernel<<<(N_EDGES + 255) / 256, 256, 0, stream>>>(eidx, etype, flag, offsets, cursor, ebuf);

    cvt_bf16_kernel<<<(N_NODES * F_IN / 4 + 255) / 256, 256, 0, stream>>>(
        x, xb, (long long)N_NODES * F_IN / 4);
    {
        int tot = F_HID * (N_REL * F_IN + F_IN);
        make_bt1_kernel<<<(tot + 255) / 256, 256, 0, stream>>>(w1, root1, bt1);
        tot = NC2 * F_HID;
        make_bt2_kernel<<<(tot + 255) / 256, 256, 0, stream>>>(w2, root2, bt2);
    }

    const int MBLK = (N_NODES + GBM - 1) / GBM;       // 391
    const int GWAVE_BLOCKS = (N_NODES * 64 + 255) / 256;

    // ---------------- layer 1: emb = relu([agg | x] @ [w1; root1] + b1) ----------------
    for (int r0 = 0; r0 < N_REL; r0 += CR) {
        if (CR == 8)
            gather1_kernel<8><<<GWAVE_BLOCKS, 256, 0, stream>>>(xb, ebuf, offsets, invc, aggb, r0);
        else
            gather1_kernel<4><<<GWAVE_BLOCKS, 256, 0, stream>>>(xb, ebuf, offsets, invc, aggb, r0);
        int first = (r0 == 0), last = (r0 + CR >= N_REL);
        dim3 grid(F_HID / GBN, MBLK);
        gemm_mfma_kernel<<<grid, 256, 0, stream>>>(
            aggb, CR * F_IN, CR * F_IN,
            first ? xb : nullptr, first ? F_IN : 0, F_IN,
            bt1 + (size_t)r0 * F_IN, bt1 + (size_t)N_REL * F_IN, N_REL * F_IN + F_IN,
            first ? b1 : nullptr,
            emb, last ? embb : nullptr,
            N_NODES, F_HID, first ? 0 : 1, last ? 1 : 0);
    }

    // ---------------- layer 2: z[n] = embb[n] @ [w2_0..w2_7 | root2]  (bf16) ----------------
    {
        dim3 grid(NC2 / GBN, MBLK);
        gemm_mfma_kernel<<<grid, 256, 0, stream>>>(
            embb, F_HID, F_HID, nullptr, 0, 0,
            bt2, nullptr, F_HID,
            nullptr, nullptr, z, N_NODES, NC2, 0, 0);
    }

    // gather messages + root + bias + log_softmax, single pass
    gather2_kernel<<<GWAVE_BLOCKS, 256, 0, stream>>>(z, ebuf, offsets, invc, b2, h_out);
}

// Round 5
// 799.308 us; speedup vs baseline: 6.3053x; 1.0450x over previous
//
#include <hip/hip_runtime.h>
#include <hip/hip_bf16.h>
#include <cstddef>
#include <cstdint>

#define N_NODES 50000
#define N_EDGES 800000
#define N_REL 8
#define F_IN 256
#define F_HID 512
#define F_OUT 128
#define NC2 (N_REL * F_OUT + F_OUT)   // 1152: w2 cols + root2 cols

typedef __attribute__((ext_vector_type(8))) short short8;   // 8 bf16 (4 VGPRs)
typedef __attribute__((ext_vector_type(4))) float f32x4;    // MFMA C/D

__device__ __forceinline__ float bf2f(unsigned short u) {
    return __uint_as_float(((unsigned)u) << 16);
}
__device__ __forceinline__ unsigned short f2bf(float f) {
    __hip_bfloat16 h = __float2bfloat16(f);
    return *reinterpret_cast<unsigned short*>(&h);
}

// ---------- int64-vs-int32 edge dtype detection ----------
__global__ void detect64_kernel(const int* __restrict__ et, int* __restrict__ flag) {
    int v = et[2 * threadIdx.x + 1];
    unsigned long long any = __ballot(v != 0);
    if (threadIdx.x == 0) flag[0] = (any == 0ULL) ? 1 : 0;
}

__device__ __forceinline__ long long ld_idx(const void* __restrict__ p, size_t i, int is64) {
    return is64 ? ((const long long*)p)[i] : (long long)((const int*)p)[i];
}

// ---------- per-(dst, rel) edge counts (int) ----------
__global__ void count_kernel(const void* __restrict__ etype, const void* __restrict__ eidx,
                             const int* __restrict__ flag, unsigned* __restrict__ cnt8) {
    int e = blockIdx.x * blockDim.x + threadIdx.x;
    if (e >= N_EDGES) return;
    int is64 = flag[0];
    long long rt  = ld_idx(etype, e, is64);
    long long dst = ld_idx(eidx, (size_t)N_EDGES + e, is64);
    atomicAdd(&cnt8[dst * N_REL + rt], 1u);
}

__global__ void inv_kernel(const unsigned* __restrict__ cnt8, float* __restrict__ invc) {
    int i = blockIdx.x * blockDim.x + threadIdx.x;
    if (i >= N_NODES * N_REL) return;
    unsigned c = cnt8[i];
    invc[i] = 1.0f / (float)(c ? c : 1u);
}

// ---------- single-block exclusive scan of per-dst counts ----------
__global__ __launch_bounds__(1024) void scan_kernel(const unsigned* __restrict__ cnt8,
                                                    int* __restrict__ offsets) {
    __shared__ int lds[1024];
    const int t = threadIdx.x;
    const int CH = (N_NODES + 1023) / 1024;  // 49
    int lo = t * CH;
    int hi = lo + CH; if (hi > N_NODES) hi = N_NODES;
    if (lo > N_NODES) lo = N_NODES;
    int s = 0;
    for (int i = lo; i < hi; ++i) {
        int c = 0;
        #pragma unroll
        for (int r = 0; r < N_REL; ++r) c += (int)cnt8[i * N_REL + r];
        s += c;
    }
    lds[t] = s;
    __syncthreads();
    for (int o = 1; o < 1024; o <<= 1) {
        int v = (t >= o) ? lds[t - o] : 0;
        __syncthreads();
        lds[t] += v;
        __syncthreads();
    }
    int run = (t == 0) ? 0 : lds[t - 1];
    for (int i = lo; i < hi; ++i) {
        offsets[i] = run;
        int c = 0;
        #pragma unroll
        for (int r = 0; r < N_REL; ++r) c += (int)cnt8[i * N_REL + r];
        run += c;
    }
    if (t == 1023) offsets[N_NODES] = run;
}

// ---------- bucket edges into CSR: ebuf[pos] = (src<<3)|rel ----------
__global__ void build_kernel(const void* __restrict__ eidx, const void* __restrict__ etype,
                             const int* __restrict__ flag, const int* __restrict__ offsets,
                             int* __restrict__ cursor, unsigned* __restrict__ ebuf) {
    int e = blockIdx.x * blockDim.x + threadIdx.x;
    if (e >= N_EDGES) return;
    int is64 = flag[0];
    int rt  = (int)ld_idx(etype, e, is64);
    int src = (int)ld_idx(eidx, e, is64);
    int dst = (int)ld_idx(eidx, (size_t)N_EDGES + e, is64);
    int pos = offsets[dst] + atomicAdd(&cursor[dst], 1);
    ebuf[pos] = ((unsigned)src << 3) | (unsigned)rt;
}

// ---------- f32 -> bf16 convert (4 elems / thread) ----------
__global__ void cvt_bf16_kernel(const float* __restrict__ in, __hip_bfloat16* __restrict__ out,
                                long long n4) {
    long long g = (long long)blockIdx.x * blockDim.x + threadIdx.x;
    if (g >= n4) return;
    float4 v = ((const float4*)in)[g];
    unsigned short o[4];
    o[0] = f2bf(v.x); o[1] = f2bf(v.y); o[2] = f2bf(v.z); o[3] = f2bf(v.w);
    *(short4*)&out[4 * g] = *(const short4*)o;
}

// ---------- weight preps: BT[n][k] bf16 (K-transposed) ----------
__global__ void make_bt1_kernel(const float* __restrict__ w1, const float* __restrict__ root1,
                                __hip_bfloat16* __restrict__ bt) {
    int g = blockIdx.x * blockDim.x + threadIdx.x;
    const int Kt = N_REL * F_IN + F_IN; // 2304
    if (g >= F_HID * Kt) return;
    int n = g / Kt, k = g % Kt;
    float v;
    if (k < N_REL * F_IN) v = w1[(size_t)(k >> 8) * F_IN * F_HID + (size_t)(k & 255) * F_HID + n];
    else                  v = root1[(size_t)(k - N_REL * F_IN) * F_HID + n];
    bt[g] = __float2bfloat16(v);
}

__global__ void make_bt2_kernel(const float* __restrict__ w2, const float* __restrict__ root2,
                                __hip_bfloat16* __restrict__ bt) {
    int g = blockIdx.x * blockDim.x + threadIdx.x;
    if (g >= NC2 * F_HID) return;
    int n = g / F_HID, k = g % F_HID;
    float v = (n < N_REL * F_OUT)
                  ? w2[(size_t)(n >> 7) * F_HID * F_OUT + (size_t)k * F_OUT + (n & 127)]
                  : root2[(size_t)k * F_OUT + (n - N_REL * F_OUT)];
    bt[g] = __float2bfloat16(v);
}

// ---------- layer-1 gather: one wave per dst, all rels in registers ----------
template <int CR>
__global__ __launch_bounds__(256) void gather1_kernel(
    const __hip_bfloat16* __restrict__ xb, const unsigned* __restrict__ ebuf,
    const int* __restrict__ offsets, const float* __restrict__ invc,
    __hip_bfloat16* __restrict__ aggb, int r0)
{
    int wid  = (blockIdx.x * blockDim.x + threadIdx.x) >> 6;
    int lane = threadIdx.x & 63;
    if (wid >= N_NODES) return;
    int e0 = offsets[wid], e1 = offsets[wid + 1];
    float acc[CR][4];
    #pragma unroll
    for (int c = 0; c < CR; ++c)
        #pragma unroll
        for (int j = 0; j < 4; ++j) acc[c][j] = 0.0f;

    for (int e = e0; e < e1; ++e) {
        unsigned u = ebuf[e];
        int rl = (int)(u & 7u) - r0;
        if (CR < N_REL && (unsigned)rl >= (unsigned)CR) continue;
        unsigned src = u >> 3;
        short4 v = *(const short4*)&xb[(size_t)src * F_IN + lane * 4];
        float f0 = bf2f((unsigned short)v.x), f1 = bf2f((unsigned short)v.y);
        float f2 = bf2f((unsigned short)v.z), f3 = bf2f((unsigned short)v.w);
        int rls = __builtin_amdgcn_readfirstlane(rl);
        #pragma unroll
        for (int c = 0; c < CR; ++c)
            if (rls == c) { acc[c][0] += f0; acc[c][1] += f1; acc[c][2] += f2; acc[c][3] += f3; }
    }
    #pragma unroll
    for (int c = 0; c < CR; ++c) {
        float s = invc[(size_t)wid * N_REL + r0 + c];
        unsigned short o[4];
        o[0] = f2bf(acc[c][0] * s);
        o[1] = f2bf(acc[c][1] * s);
        o[2] = f2bf(acc[c][2] * s);
        o[3] = f2bf(acc[c][3] * s);
        *(short4*)&aggb[((size_t)wid * CR + c) * F_IN + lane * 4] = *(const short4*)o;
    }
}

// ---------- layer-2 gather + root + bias + log_softmax, one wave per dst ----------
__global__ __launch_bounds__(256) void gather2_kernel(
    const __hip_bfloat16* __restrict__ z, const unsigned* __restrict__ ebuf,
    const int* __restrict__ offsets, const float* __restrict__ invc,
    const float* __restrict__ b2, float* __restrict__ h)
{
    int wid  = (blockIdx.x * blockDim.x + threadIdx.x) >> 6;
    int lane = threadIdx.x & 63;
    if (wid >= N_NODES) return;
    int e0 = offsets[wid], e1 = offsets[wid + 1];
    float a0 = 0.0f, a1 = 0.0f;
    for (int e = e0; e < e1; ++e) {
        unsigned u = ebuf[e];
        int rt = (int)(u & 7u);
        unsigned src = u >> 3;
        float s = invc[(size_t)wid * N_REL + rt];
        unsigned pv = *(const unsigned*)&z[(size_t)src * NC2 + rt * F_OUT + lane * 2];
        a0 += s * bf2f((unsigned short)(pv & 0xffffu));
        a1 += s * bf2f((unsigned short)(pv >> 16));
    }
    unsigned rv = *(const unsigned*)&z[(size_t)wid * NC2 + N_REL * F_OUT + lane * 2];
    a0 += bf2f((unsigned short)(rv & 0xffffu)) + b2[lane * 2];
    a1 += bf2f((unsigned short)(rv >> 16))     + b2[lane * 2 + 1];

    float m = fmaxf(a0, a1);
    #pragma unroll
    for (int o = 32; o > 0; o >>= 1) m = fmaxf(m, __shfl_xor(m, o));
    float sum = expf(a0 - m) + expf(a1 - m);
    #pragma unroll
    for (int o = 32; o > 0; o >>= 1) sum += __shfl_xor(sum, o);
    float lse = m + logf(sum);
    h[(size_t)wid * F_OUT + lane * 2]     = a0 - lse;
    h[(size_t)wid * F_OUT + lane * 2 + 1] = a1 - lse;
}

// ---------- bf16 MFMA GEMM (1-D grid, XCD swizzle, T2 LDS swizzle) ----------
#define GBM 128
#define GBN 128
#define GBK 64

__global__ __launch_bounds__(256) void gemm_mfma_kernel(
    const __hip_bfloat16* __restrict__ A1, int K1, int lda1,
    const __hip_bfloat16* __restrict__ A2, int K2, int lda2,
    const __hip_bfloat16* __restrict__ BTa, const __hip_bfloat16* __restrict__ BTb, int ldbt,
    const float* __restrict__ bias,
    float* __restrict__ Cf, __hip_bfloat16* __restrict__ Cb,
    int M, int Nc, int accumulate, int do_relu,
    int gridX, int nwg)
{
    __shared__ __align__(16) __hip_bfloat16 As[GBM * GBK];
    __shared__ __align__(16) __hip_bfloat16 Bs[GBN * GBK];

    // --- bijective XCD swizzle (m204): blocks sharing an A-panel (consecutive
    // logical wgid, bx fastest) land in the same XCD's contiguous chunk ---
    int bid = blockIdx.x;
    int q = nwg >> 3, r = nwg & 7;
    int xcd = bid & 7, ii = bid >> 3;
    int wg = (xcd < r ? xcd * (q + 1) : r * (q + 1) + (xcd - r) * q) + ii;
    const int bm = (wg / gridX) * GBM;
    const int bn = (wg % gridX) * GBN;

    const int lane = threadIdx.x & 63;
    const int wv   = threadIdx.x >> 6;
    const int wr   = wv >> 1;
    const int wc   = wv & 1;
    const int r15  = lane & 15;
    const int ksel = lane >> 4;

    f32x4 acc[4][4] = {};
    const int Ktot = K1 + K2;

    // T2 staging: LDS dest stays linear (gload_lds writes base+lane*16); the
    // GLOBAL source column is pre-permuted so that LDS[row][b16] holds
    // global[row][b16 ^ (row&7)] (16-byte units).
    const int seg_row = lane >> 3;                         // row within 8-row segment
    const int seg_col = (((lane & 7) ^ seg_row)) * 8;      // bf16 element col (swizzled)

    for (int k0 = 0; k0 < Ktot; k0 += GBK) {
        #pragma unroll
        for (int c = 0; c < 4; ++c) {
            int s = wv * 4 + c;
            int row = s * 8 + seg_row;
            int gr = bm + row; if (gr >= M) gr = M - 1;
            const __hip_bfloat16* gp;
            if (k0 < K1) gp = A1 + (size_t)gr * lda1 + (k0 + seg_col);
            else         gp = A2 + (size_t)gr * lda2 + (k0 - K1 + seg_col);
            __builtin_amdgcn_global_load_lds(
                (const __attribute__((address_space(1))) void*)gp,
                (__attribute__((address_space(3))) void*)&As[s * 512], 16, 0, 0);
        }
        #pragma unroll
        for (int c = 0; c < 4; ++c) {
            int s = wv * 4 + c;
            int n = bn + s * 8 + seg_row;
            const __hip_bfloat16* gp;
            if (k0 < K1) gp = BTa + (size_t)n * ldbt + (k0 + seg_col);
            else         gp = BTb + (size_t)n * ldbt + (k0 - K1 + seg_col);
            __builtin_amdgcn_global_load_lds(
                (const __attribute__((address_space(1))) void*)gp,
                (__attribute__((address_space(3))) void*)&Bs[s * 512], 16, 0, 0);
        }
        __syncthreads();

        short8 a[4][2], b[4][2];
        const int rsw = (r15 & 7) << 3;   // element-unit XOR for the read side
        #pragma unroll
        for (int i = 0; i < 4; ++i)
            #pragma unroll
            for (int h = 0; h < 2; ++h) {
                int col = (h * 32 + ksel * 8) ^ rsw;
                a[i][h] = *(const short8*)&As[(wr * 64 + i * 16 + r15) * GBK + col];
            }
        #pragma unroll
        for (int j = 0; j < 4; ++j)
            #pragma unroll
            for (int h = 0; h < 2; ++h) {
                int col = (h * 32 + ksel * 8) ^ rsw;
                b[j][h] = *(const short8*)&Bs[(wc * 64 + j * 16 + r15) * GBK + col];
            }
        #pragma unroll
        for (int i = 0; i < 4; ++i)
            #pragma unroll
            for (int j = 0; j < 4; ++j)
                #pragma unroll
                for (int h = 0; h < 2; ++h)
                    acc[i][j] = __builtin_amdgcn_mfma_f32_16x16x32_bf16(
                        a[i][h], b[j][h], acc[i][j], 0, 0, 0);
        __syncthreads();
    }

    float bv[4];
    #pragma unroll
    for (int j = 0; j < 4; ++j)
        bv[j] = bias ? bias[bn + wc * 64 + j * 16 + r15] : 0.0f;

    #pragma unroll
    for (int i = 0; i < 4; ++i) {
        #pragma unroll
        for (int q2 = 0; q2 < 4; ++q2) {
            int row = bm + wr * 64 + i * 16 + ksel * 4 + q2;
            if (row >= M) continue;
            #pragma unroll
            for (int j = 0; j < 4; ++j) {
                int col = bn + wc * 64 + j * 16 + r15;
                float v = acc[i][j][q2] + bv[j];
                size_t off = (size_t)row * Nc + col;
                if (accumulate) v += Cf[off];
                if (do_relu) v = fmaxf(v, 0.0f);
                if (Cf) Cf[off] = v;
                if (Cb) Cb[off] = __float2bfloat16(v);
            }
        }
    }
}

extern "C" void kernel_launch(void* const* d_in, const int* in_sizes, int n_in,
                              void* d_out, int out_size, void* d_ws, size_t ws_size,
                              hipStream_t stream) {
    const float* x     = (const float*)d_in[0];
    const void*  eidx  = d_in[1];
    const void*  etype = d_in[2];
    const float* w1    = (const float*)d_in[3];
    const float* root1 = (const float*)d_in[4];
    const float* b1    = (const float*)d_in[5];
    const float* w2    = (const float*)d_in[6];
    const float* root2 = (const float*)d_in[7];
    const float* b2    = (const float*)d_in[8];

    float* h_out = (float*)d_out;                            // [N,128]
    float* emb   = (float*)d_out + (size_t)N_NODES * F_OUT;  // [N,512] f32 (output #2)

    // ---- workspace carve-up ----
    char* ws = (char*)d_ws;
    size_t off = 0;
    auto take = [&](size_t bytes) { char* p = ws + off; off = (off + bytes + 255) & ~(size_t)255; return p; };
    int*      flag    = (int*)take(256);
    unsigned* cnt8    = (unsigned*)take((size_t)N_NODES * N_REL * 4);
    float*    invc    = (float*)take((size_t)N_NODES * N_REL * 4);
    int*      offsets = (int*)take(((size_t)N_NODES + 1) * 4);
    int*      cursor  = (int*)take((size_t)N_NODES * 4);
    unsigned* ebuf    = (unsigned*)take((size_t)N_EDGES * 4);
    __hip_bfloat16* xb   = (__hip_bfloat16*)take((size_t)N_NODES * F_IN * 2);
    __hip_bfloat16* embb = (__hip_bfloat16*)take((size_t)N_NODES * F_HID * 2);
    __hip_bfloat16* bt1  = (__hip_bfloat16*)take((size_t)F_HID * (N_REL * F_IN + F_IN) * 2);
    __hip_bfloat16* bt2  = (__hip_bfloat16*)take((size_t)NC2 * F_HID * 2);

    size_t avail = (ws_size > off) ? (ws_size - off) : 0;
    size_t agg8bytes = (size_t)N_NODES * N_REL * F_IN * 2;   // 204.8 MB
    size_t zbytes    = (size_t)N_NODES * NC2 * 2;            // 115.2 MB
    int CR = (avail >= agg8bytes) ? 8 : 4;
    size_t ubytes = agg8bytes > zbytes ? agg8bytes : zbytes;
    if (CR == 4) ubytes = zbytes;
    char* uni = take(ubytes);
    __hip_bfloat16* aggb = (__hip_bfloat16*)uni;   // layer-1 A-tile (dead after GEMM1)
    __hip_bfloat16* z    = (__hip_bfloat16*)uni;   // layer-2 transformed msgs (aliases aggb)

    // ---- prep ----
    detect64_kernel<<<1, 64, 0, stream>>>((const int*)etype, flag);
    (void)hipMemsetAsync(cnt8, 0, (size_t)N_NODES * N_REL * 4, stream);
    (void)hipMemsetAsync(cursor, 0, (size_t)N_NODES * 4, stream);
    count_kernel<<<(N_EDGES + 255) / 256, 256, 0, stream>>>(etype, eidx, flag, cnt8);
    inv_kernel<<<(N_NODES * N_REL + 255) / 256, 256, 0, stream>>>(cnt8, invc);
    scan_kernel<<<1, 1024, 0, stream>>>(cnt8, offsets);
    build_kernel<<<(N_EDGES + 255) / 256, 256, 0, stream>>>(eidx, etype, flag, offsets, cursor, ebuf);

    cvt_bf16_kernel<<<(N_NODES * F_IN / 4 + 255) / 256, 256, 0, stream>>>(
        x, xb, (long long)N_NODES * F_IN / 4);
    {
        int tot = F_HID * (N_REL * F_IN + F_IN);
        make_bt1_kernel<<<(tot + 255) / 256, 256, 0, stream>>>(w1, root1, bt1);
        tot = NC2 * F_HID;
        make_bt2_kernel<<<(tot + 255) / 256, 256, 0, stream>>>(w2, root2, bt2);
    }

    const int MBLK = (N_NODES + GBM - 1) / GBM;       // 391
    const int GWAVE_BLOCKS = (N_NODES * 64 + 255) / 256;

    // ---------------- layer 1: emb = relu([agg | x] @ [w1; root1] + b1) ----------------
    for (int r0 = 0; r0 < N_REL; r0 += CR) {
        if (CR == 8)
            gather1_kernel<8><<<GWAVE_BLOCKS, 256, 0, stream>>>(xb, ebuf, offsets, invc, aggb, r0);
        else
            gather1_kernel<4><<<GWAVE_BLOCKS, 256, 0, stream>>>(xb, ebuf, offsets, invc, aggb, r0);
        int first = (r0 == 0), last = (r0 + CR >= N_REL);
        int gX = F_HID / GBN, nwg = gX * MBLK;
        gemm_mfma_kernel<<<nwg, 256, 0, stream>>>(
            aggb, CR * F_IN, CR * F_IN,
            first ? xb : nullptr, first ? F_IN : 0, F_IN,
            bt1 + (size_t)r0 * F_IN, bt1 + (size_t)N_REL * F_IN, N_REL * F_IN + F_IN,
            first ? b1 : nullptr,
            emb, last ? embb : nullptr,
            N_NODES, F_HID, first ? 0 : 1, last ? 1 : 0,
            gX, nwg);
    }

    // ---------------- layer 2: z[n] = embb[n] @ [w2_0..w2_7 | root2]  (bf16) ----------------
    {
        int gX = NC2 / GBN, nwg = gX * MBLK;
        gemm_mfma_kernel<<<nwg, 256, 0, stream>>>(
            embb, F_HID, F_HID, nullptr, 0, 0,
            bt2, nullptr, F_HID,
            nullptr, nullptr, z, N_NODES, NC2, 0, 0,
            gX, nwg);
    }

    // gather messages + root + bias + log_softmax, single pass
    gather2_kernel<<<GWAVE_BLOCKS, 256, 0, stream>>>(z, ebuf, offsets, invc, b2, h_out);
}

// Round 6
// 775.110 us; speedup vs baseline: 6.5022x; 1.0312x over previous
//
#include <hip/hip_runtime.h>
#include <hip/hip_bf16.h>
#include <cstddef>
#include <cstdint>

#define N_NODES 50000
#define N_EDGES 800000
#define N_REL 8
#define F_IN 256
#define F_HID 512
#define F_OUT 128
#define NC2 (N_REL * F_OUT + F_OUT)   // 1152: w2 cols + root2 cols

typedef __attribute__((ext_vector_type(8))) short short8;   // 8 bf16 (4 VGPRs)
typedef __attribute__((ext_vector_type(4))) float f32x4;    // MFMA C/D

__device__ __forceinline__ float bf2f(unsigned short u) {
    return __uint_as_float(((unsigned)u) << 16);
}
__device__ __forceinline__ unsigned short f2bf(float f) {
    __hip_bfloat16 h = __float2bfloat16(f);
    return *reinterpret_cast<unsigned short*>(&h);
}

// ---------- int64-vs-int32 edge dtype detection ----------
__global__ void detect64_kernel(const int* __restrict__ et, int* __restrict__ flag) {
    int v = et[2 * threadIdx.x + 1];
    unsigned long long any = __ballot(v != 0);
    if (threadIdx.x == 0) flag[0] = (any == 0ULL) ? 1 : 0;
}

__device__ __forceinline__ long long ld_idx(const void* __restrict__ p, size_t i, int is64) {
    return is64 ? ((const long long*)p)[i] : (long long)((const int*)p)[i];
}

// ---------- per-(dst, rel) edge counts (int) ----------
__global__ void count_kernel(const void* __restrict__ etype, const void* __restrict__ eidx,
                             const int* __restrict__ flag, unsigned* __restrict__ cnt8) {
    int e = blockIdx.x * blockDim.x + threadIdx.x;
    if (e >= N_EDGES) return;
    int is64 = flag[0];
    long long rt  = ld_idx(etype, e, is64);
    long long dst = ld_idx(eidx, (size_t)N_EDGES + e, is64);
    atomicAdd(&cnt8[dst * N_REL + rt], 1u);
}

__global__ void inv_kernel(const unsigned* __restrict__ cnt8, float* __restrict__ invc) {
    int i = blockIdx.x * blockDim.x + threadIdx.x;
    if (i >= N_NODES * N_REL) return;
    unsigned c = cnt8[i];
    invc[i] = 1.0f / (float)(c ? c : 1u);
}

// ---------- single-block exclusive scan of per-dst counts ----------
__global__ __launch_bounds__(1024) void scan_kernel(const unsigned* __restrict__ cnt8,
                                                    int* __restrict__ offsets) {
    __shared__ int lds[1024];
    const int t = threadIdx.x;
    const int CH = (N_NODES + 1023) / 1024;  // 49
    int lo = t * CH;
    int hi = lo + CH; if (hi > N_NODES) hi = N_NODES;
    if (lo > N_NODES) lo = N_NODES;
    int s = 0;
    for (int i = lo; i < hi; ++i) {
        int c = 0;
        #pragma unroll
        for (int r = 0; r < N_REL; ++r) c += (int)cnt8[i * N_REL + r];
        s += c;
    }
    lds[t] = s;
    __syncthreads();
    for (int o = 1; o < 1024; o <<= 1) {
        int v = (t >= o) ? lds[t - o] : 0;
        __syncthreads();
        lds[t] += v;
        __syncthreads();
    }
    int run = (t == 0) ? 0 : lds[t - 1];
    for (int i = lo; i < hi; ++i) {
        offsets[i] = run;
        int c = 0;
        #pragma unroll
        for (int r = 0; r < N_REL; ++r) c += (int)cnt8[i * N_REL + r];
        run += c;
    }
    if (t == 1023) offsets[N_NODES] = run;
}

// ---------- bucket edges into CSR: ebuf[pos] = (src<<3)|rel ----------
__global__ void build_kernel(const void* __restrict__ eidx, const void* __restrict__ etype,
                             const int* __restrict__ flag, const int* __restrict__ offsets,
                             int* __restrict__ cursor, unsigned* __restrict__ ebuf) {
    int e = blockIdx.x * blockDim.x + threadIdx.x;
    if (e >= N_EDGES) return;
    int is64 = flag[0];
    int rt  = (int)ld_idx(etype, e, is64);
    int src = (int)ld_idx(eidx, e, is64);
    int dst = (int)ld_idx(eidx, (size_t)N_EDGES + e, is64);
    int pos = offsets[dst] + atomicAdd(&cursor[dst], 1);
    ebuf[pos] = ((unsigned)src << 3) | (unsigned)rt;
}

// ---------- f32 -> bf16 convert (4 elems / thread) ----------
__global__ void cvt_bf16_kernel(const float* __restrict__ in, __hip_bfloat16* __restrict__ out,
                                long long n4) {
    long long g = (long long)blockIdx.x * blockDim.x + threadIdx.x;
    if (g >= n4) return;
    float4 v = ((const float4*)in)[g];
    unsigned short o[4];
    o[0] = f2bf(v.x); o[1] = f2bf(v.y); o[2] = f2bf(v.z); o[3] = f2bf(v.w);
    *(short4*)&out[4 * g] = *(const short4*)o;
}

// ---------- weight preps: BT[n][k] bf16 (K-transposed) ----------
__global__ void make_bt1_kernel(const float* __restrict__ w1, const float* __restrict__ root1,
                                __hip_bfloat16* __restrict__ bt) {
    int g = blockIdx.x * blockDim.x + threadIdx.x;
    const int Kt = N_REL * F_IN + F_IN; // 2304
    if (g >= F_HID * Kt) return;
    int n = g / Kt, k = g % Kt;
    float v;
    if (k < N_REL * F_IN) v = w1[(size_t)(k >> 8) * F_IN * F_HID + (size_t)(k & 255) * F_HID + n];
    else                  v = root1[(size_t)(k - N_REL * F_IN) * F_HID + n];
    bt[g] = __float2bfloat16(v);
}

__global__ void make_bt2_kernel(const float* __restrict__ w2, const float* __restrict__ root2,
                                __hip_bfloat16* __restrict__ bt) {
    int g = blockIdx.x * blockDim.x + threadIdx.x;
    if (g >= NC2 * F_HID) return;
    int n = g / F_HID, k = g % F_HID;
    float v = (n < N_REL * F_OUT)
                  ? w2[(size_t)(n >> 7) * F_HID * F_OUT + (size_t)k * F_OUT + (n & 127)]
                  : root2[(size_t)k * F_OUT + (n - N_REL * F_OUT)];
    bt[g] = __float2bfloat16(v);
}

// ---------- layer-1 gather: one wave per dst, all rels in registers ----------
template <int CR>
__global__ __launch_bounds__(256) void gather1_kernel(
    const __hip_bfloat16* __restrict__ xb, const unsigned* __restrict__ ebuf,
    const int* __restrict__ offsets, const float* __restrict__ invc,
    __hip_bfloat16* __restrict__ aggb, int r0)
{
    int wid  = (blockIdx.x * blockDim.x + threadIdx.x) >> 6;
    int lane = threadIdx.x & 63;
    if (wid >= N_NODES) return;
    int e0 = offsets[wid], e1 = offsets[wid + 1];
    float acc[CR][4];
    #pragma unroll
    for (int c = 0; c < CR; ++c)
        #pragma unroll
        for (int j = 0; j < 4; ++j) acc[c][j] = 0.0f;

    for (int e = e0; e < e1; ++e) {
        unsigned u = ebuf[e];
        int rl = (int)(u & 7u) - r0;
        if (CR < N_REL && (unsigned)rl >= (unsigned)CR) continue;
        unsigned src = u >> 3;
        short4 v = *(const short4*)&xb[(size_t)src * F_IN + lane * 4];
        float f0 = bf2f((unsigned short)v.x), f1 = bf2f((unsigned short)v.y);
        float f2 = bf2f((unsigned short)v.z), f3 = bf2f((unsigned short)v.w);
        int rls = __builtin_amdgcn_readfirstlane(rl);
        #pragma unroll
        for (int c = 0; c < CR; ++c)
            if (rls == c) { acc[c][0] += f0; acc[c][1] += f1; acc[c][2] += f2; acc[c][3] += f3; }
    }
    #pragma unroll
    for (int c = 0; c < CR; ++c) {
        float s = invc[(size_t)wid * N_REL + r0 + c];
        unsigned short o[4];
        o[0] = f2bf(acc[c][0] * s);
        o[1] = f2bf(acc[c][1] * s);
        o[2] = f2bf(acc[c][2] * s);
        o[3] = f2bf(acc[c][3] * s);
        *(short4*)&aggb[((size_t)wid * CR + c) * F_IN + lane * 4] = *(const short4*)o;
    }
}

// ---------- layer-2 gather + root + bias + log_softmax, one wave per dst ----------
__global__ __launch_bounds__(256) void gather2_kernel(
    const __hip_bfloat16* __restrict__ z, const unsigned* __restrict__ ebuf,
    const int* __restrict__ offsets, const float* __restrict__ invc,
    const float* __restrict__ b2, float* __restrict__ h)
{
    int wid  = (blockIdx.x * blockDim.x + threadIdx.x) >> 6;
    int lane = threadIdx.x & 63;
    if (wid >= N_NODES) return;
    int e0 = offsets[wid], e1 = offsets[wid + 1];
    float a0 = 0.0f, a1 = 0.0f;
    for (int e = e0; e < e1; ++e) {
        unsigned u = ebuf[e];
        int rt = (int)(u & 7u);
        unsigned src = u >> 3;
        float s = invc[(size_t)wid * N_REL + rt];
        unsigned pv = *(const unsigned*)&z[(size_t)src * NC2 + rt * F_OUT + lane * 2];
        a0 += s * bf2f((unsigned short)(pv & 0xffffu));
        a1 += s * bf2f((unsigned short)(pv >> 16));
    }
    unsigned rv = *(const unsigned*)&z[(size_t)wid * NC2 + N_REL * F_OUT + lane * 2];
    a0 += bf2f((unsigned short)(rv & 0xffffu)) + b2[lane * 2];
    a1 += bf2f((unsigned short)(rv >> 16))     + b2[lane * 2 + 1];

    float m = fmaxf(a0, a1);
    #pragma unroll
    for (int o = 32; o > 0; o >>= 1) m = fmaxf(m, __shfl_xor(m, o));
    float sum = expf(a0 - m) + expf(a1 - m);
    #pragma unroll
    for (int o = 32; o > 0; o >>= 1) sum += __shfl_xor(sum, o);
    float lse = m + logf(sum);
    h[(size_t)wid * F_OUT + lane * 2]     = a0 - lse;
    h[(size_t)wid * F_OUT + lane * 2 + 1] = a1 - lse;
}

// ---------- bf16 MFMA GEMM: XCD swizzle + T2 swizzle + dbuf prefetch pipeline ----------
#define GBM 128
#define GBN 128
#define GBK 64

__global__ __launch_bounds__(256) void gemm_mfma_kernel(
    const __hip_bfloat16* __restrict__ A1, int K1, int lda1,
    const __hip_bfloat16* __restrict__ A2, int K2, int lda2,
    const __hip_bfloat16* __restrict__ BTa, const __hip_bfloat16* __restrict__ BTb, int ldbt,
    const float* __restrict__ bias,
    float* __restrict__ Cf, __hip_bfloat16* __restrict__ Cb,
    int M, int Nc, int accumulate, int do_relu,
    int gridX, int nwg)
{
    __shared__ __align__(16) __hip_bfloat16 As[2][GBM * GBK];
    __shared__ __align__(16) __hip_bfloat16 Bs[2][GBN * GBK];

    // --- bijective XCD swizzle (m204) ---
    int bid = blockIdx.x;
    int q = nwg >> 3, r = nwg & 7;
    int xcd = bid & 7, ii = bid >> 3;
    int wg = (xcd < r ? xcd * (q + 1) : r * (q + 1) + (xcd - r) * q) + ii;
    const int bm = (wg / gridX) * GBM;
    const int bn = (wg % gridX) * GBN;

    const int lane = threadIdx.x & 63;
    const int wv   = threadIdx.x >> 6;
    const int wr   = wv >> 1;
    const int wc   = wv & 1;
    const int r15  = lane & 15;
    const int ksel = lane >> 4;

    // T2 staging: linear LDS dest; pre-permuted GLOBAL source column so
    // LDS[row][c8] = global[row][c8 ^ (row&7)] (8-elem units).
    const int seg_row = lane >> 3;
    const int seg_col = (((lane & 7) ^ seg_row)) * 8;

    // hoisted per-segment row bases (row index is K-invariant)
    const __hip_bfloat16* a1p[4];
    const __hip_bfloat16* a2p[4];
    const __hip_bfloat16* bap[4];
    const __hip_bfloat16* bbp[4];
    #pragma unroll
    for (int c = 0; c < 4; ++c) {
        int s = wv * 4 + c;
        int row = s * 8 + seg_row;
        int gr = bm + row; if (gr >= M) gr = M - 1;
        a1p[c] = A1 + (size_t)gr * lda1 + seg_col;
        a2p[c] = A2 ? (A2 + (size_t)gr * lda2 + seg_col) : nullptr;
        int n = bn + row;
        bap[c] = BTa + (size_t)n * ldbt + seg_col;
        bbp[c] = BTb ? (BTb + (size_t)n * ldbt + seg_col) : nullptr;
    }

    const int Ktot = K1 + K2;
    const int nT = Ktot / GBK;

    auto stage = [&](int k0, int bi) {
        #pragma unroll
        for (int c = 0; c < 4; ++c) {
            int s = wv * 4 + c;
            const __hip_bfloat16* gp = (k0 < K1) ? (a1p[c] + k0) : (a2p[c] + (k0 - K1));
            __builtin_amdgcn_global_load_lds(
                (const __attribute__((address_space(1))) void*)gp,
                (__attribute__((address_space(3))) void*)&As[bi][s * 512], 16, 0, 0);
        }
        #pragma unroll
        for (int c = 0; c < 4; ++c) {
            int s = wv * 4 + c;
            const __hip_bfloat16* gp = (k0 < K1) ? (bap[c] + k0) : (bbp[c] + (k0 - K1));
            __builtin_amdgcn_global_load_lds(
                (const __attribute__((address_space(1))) void*)gp,
                (__attribute__((address_space(3))) void*)&Bs[bi][s * 512], 16, 0, 0);
        }
    };

    f32x4 acc[4][4] = {};

    // prologue: stage tile 0, drain, enter pipeline
    stage(0, 0);
    __syncthreads();

    int cur = 0;
    for (int t = 0; t < nT; ++t) {
        // 1) issue next-tile prefetch into the other buffer (overlaps compute)
        if (t + 1 < nT) stage((t + 1) * GBK, cur ^ 1);

        // 2) ds_read fragments of current tile
        short8 a[4][2], b[4][2];
        const int rsw = (r15 & 7) << 3;
        #pragma unroll
        for (int i = 0; i < 4; ++i)
            #pragma unroll
            for (int h = 0; h < 2; ++h) {
                int col = (h * 32 + ksel * 8) ^ rsw;
                a[i][h] = *(const short8*)&As[cur][(wr * 64 + i * 16 + r15) * GBK + col];
            }
        #pragma unroll
        for (int j = 0; j < 4; ++j)
            #pragma unroll
            for (int h = 0; h < 2; ++h) {
                int col = (h * 32 + ksel * 8) ^ rsw;
                b[j][h] = *(const short8*)&Bs[cur][(wc * 64 + j * 16 + r15) * GBK + col];
            }

        // 3) MFMA cluster (T5)
        __builtin_amdgcn_s_setprio(1);
        #pragma unroll
        for (int i = 0; i < 4; ++i)
            #pragma unroll
            for (int j = 0; j < 4; ++j)
                #pragma unroll
                for (int h = 0; h < 2; ++h)
                    acc[i][j] = __builtin_amdgcn_mfma_f32_16x16x32_bf16(
                        a[i][h], b[j][h], acc[i][j], 0, 0, 0);
        __builtin_amdgcn_s_setprio(0);

        // 4) single barrier (drains vmcnt -> next tile ready), flip
        __syncthreads();
        cur ^= 1;
    }

    float bv[4];
    #pragma unroll
    for (int j = 0; j < 4; ++j)
        bv[j] = bias ? bias[bn + wc * 64 + j * 16 + r15] : 0.0f;

    #pragma unroll
    for (int i = 0; i < 4; ++i) {
        #pragma unroll
        for (int q2 = 0; q2 < 4; ++q2) {
            int row = bm + wr * 64 + i * 16 + ksel * 4 + q2;
            if (row >= M) continue;
            #pragma unroll
            for (int j = 0; j < 4; ++j) {
                int col = bn + wc * 64 + j * 16 + r15;
                float v = acc[i][j][q2] + bv[j];
                size_t off = (size_t)row * Nc + col;
                if (accumulate) v += Cf[off];
                if (do_relu) v = fmaxf(v, 0.0f);
                if (Cf) Cf[off] = v;
                if (Cb) Cb[off] = __float2bfloat16(v);
            }
        }
    }
}

extern "C" void kernel_launch(void* const* d_in, const int* in_sizes, int n_in,
                              void* d_out, int out_size, void* d_ws, size_t ws_size,
                              hipStream_t stream) {
    const float* x     = (const float*)d_in[0];
    const void*  eidx  = d_in[1];
    const void*  etype = d_in[2];
    const float* w1    = (const float*)d_in[3];
    const float* root1 = (const float*)d_in[4];
    const float* b1    = (const float*)d_in[5];
    const float* w2    = (const float*)d_in[6];
    const float* root2 = (const float*)d_in[7];
    const float* b2    = (const float*)d_in[8];

    float* h_out = (float*)d_out;                            // [N,128]
    float* emb   = (float*)d_out + (size_t)N_NODES * F_OUT;  // [N,512] f32 (output #2)

    // ---- workspace carve-up ----
    char* ws = (char*)d_ws;
    size_t off = 0;
    auto take = [&](size_t bytes) { char* p = ws + off; off = (off + bytes + 255) & ~(size_t)255; return p; };
    int*      flag    = (int*)take(256);
    unsigned* cnt8    = (unsigned*)take((size_t)N_NODES * N_REL * 4);
    float*    invc    = (float*)take((size_t)N_NODES * N_REL * 4);
    int*      offsets = (int*)take(((size_t)N_NODES + 1) * 4);
    int*      cursor  = (int*)take((size_t)N_NODES * 4);
    unsigned* ebuf    = (unsigned*)take((size_t)N_EDGES * 4);
    __hip_bfloat16* xb   = (__hip_bfloat16*)take((size_t)N_NODES * F_IN * 2);
    __hip_bfloat16* embb = (__hip_bfloat16*)take((size_t)N_NODES * F_HID * 2);
    __hip_bfloat16* bt1  = (__hip_bfloat16*)take((size_t)F_HID * (N_REL * F_IN + F_IN) * 2);
    __hip_bfloat16* bt2  = (__hip_bfloat16*)take((size_t)NC2 * F_HID * 2);

    size_t avail = (ws_size > off) ? (ws_size - off) : 0;
    size_t agg8bytes = (size_t)N_NODES * N_REL * F_IN * 2;   // 204.8 MB
    size_t zbytes    = (size_t)N_NODES * NC2 * 2;            // 115.2 MB
    int CR = (avail >= agg8bytes) ? 8 : 4;
    size_t ubytes = agg8bytes > zbytes ? agg8bytes : zbytes;
    if (CR == 4) ubytes = zbytes;
    char* uni = take(ubytes);
    __hip_bfloat16* aggb = (__hip_bfloat16*)uni;   // layer-1 A-tile (dead after GEMM1)
    __hip_bfloat16* z    = (__hip_bfloat16*)uni;   // layer-2 transformed msgs (aliases aggb)

    // ---- prep ----
    detect64_kernel<<<1, 64, 0, stream>>>((const int*)etype, flag);
    (void)hipMemsetAsync(cnt8, 0, (size_t)N_NODES * N_REL * 4, stream);
    (void)hipMemsetAsync(cursor, 0, (size_t)N_NODES * 4, stream);
    count_kernel<<<(N_EDGES + 255) / 256, 256, 0, stream>>>(etype, eidx, flag, cnt8);
    inv_kernel<<<(N_NODES * N_REL + 255) / 256, 256, 0, stream>>>(cnt8, invc);
    scan_kernel<<<1, 1024, 0, stream>>>(cnt8, offsets);
    build_kernel<<<(N_EDGES + 255) / 256, 256, 0, stream>>>(eidx, etype, flag, offsets, cursor, ebuf);

    cvt_bf16_kernel<<<(N_NODES * F_IN / 4 + 255) / 256, 256, 0, stream>>>(
        x, xb, (long long)N_NODES * F_IN / 4);
    {
        int tot = F_HID * (N_REL * F_IN + F_IN);
        make_bt1_kernel<<<(tot + 255) / 256, 256, 0, stream>>>(w1, root1, bt1);
        tot = NC2 * F_HID;
        make_bt2_kernel<<<(tot + 255) / 256, 256, 0, stream>>>(w2, root2, bt2);
    }

    const int MBLK = (N_NODES + GBM - 1) / GBM;       // 391
    const int GWAVE_BLOCKS = (N_NODES * 64 + 255) / 256;

    // ---------------- layer 1: emb = relu([agg | x] @ [w1; root1] + b1) ----------------
    for (int r0 = 0; r0 < N_REL; r0 += CR) {
        if (CR == 8)
            gather1_kernel<8><<<GWAVE_BLOCKS, 256, 0, stream>>>(xb, ebuf, offsets, invc, aggb, r0);
        else
            gather1_kernel<4><<<GWAVE_BLOCKS, 256, 0, stream>>>(xb, ebuf, offsets, invc, aggb, r0);
        int first = (r0 == 0), last = (r0 + CR >= N_REL);
        int gX = F_HID / GBN, nwg = gX * MBLK;
        gemm_mfma_kernel<<<nwg, 256, 0, stream>>>(
            aggb, CR * F_IN, CR * F_IN,
            first ? xb : nullptr, first ? F_IN : 0, F_IN,
            bt1 + (size_t)r0 * F_IN, bt1 + (size_t)N_REL * F_IN, N_REL * F_IN + F_IN,
            first ? b1 : nullptr,
            emb, last ? embb : nullptr,
            N_NODES, F_HID, first ? 0 : 1, last ? 1 : 0,
            gX, nwg);
    }

    // ---------------- layer 2: z[n] = embb[n] @ [w2_0..w2_7 | root2]  (bf16) ----------------
    {
        int gX = NC2 / GBN, nwg = gX * MBLK;
        gemm_mfma_kernel<<<nwg, 256, 0, stream>>>(
            embb, F_HID, F_HID, nullptr, 0, 0,
            bt2, nullptr, F_HID,
            nullptr, nullptr, z, N_NODES, NC2, 0, 0,
            gX, nwg);
    }

    // gather messages + root + bias + log_softmax, single pass
    gather2_kernel<<<GWAVE_BLOCKS, 256, 0, stream>>>(z, ebuf, offsets, invc, b2, h_out);
}

// Round 7
// 769.987 us; speedup vs baseline: 6.5454x; 1.0067x over previous
//
#include <hip/hip_runtime.h>
#include <hip/hip_bf16.h>
#include <cstddef>
#include <cstdint>

#define N_NODES 50000
#define N_EDGES 800000
#define N_REL 8
#define F_IN 256
#define F_HID 512
#define F_OUT 128
#define NC2 (N_REL * F_OUT + F_OUT)   // 1152

typedef __attribute__((ext_vector_type(8))) short short8;
typedef __attribute__((ext_vector_type(4))) float f32x4;

__device__ __forceinline__ float bf2f(unsigned short u) {
    return __uint_as_float(((unsigned)u) << 16);
}
__device__ __forceinline__ unsigned short f2bf(float f) {
    __hip_bfloat16 h = __float2bfloat16(f);
    return *reinterpret_cast<unsigned short*>(&h);
}

// ---------- int64-vs-int32 edge dtype detection ----------
__global__ void detect64_kernel(const int* __restrict__ et, int* __restrict__ flag) {
    int v = et[2 * threadIdx.x + 1];
    unsigned long long any = __ballot(v != 0);
    if (threadIdx.x == 0) flag[0] = (any == 0ULL) ? 1 : 0;
}

__device__ __forceinline__ long long ld_idx(const void* __restrict__ p, size_t i, int is64) {
    return is64 ? ((const long long*)p)[i] : (long long)((const int*)p)[i];
}

__global__ void count_kernel(const void* __restrict__ etype, const void* __restrict__ eidx,
                             const int* __restrict__ flag, unsigned* __restrict__ cnt8) {
    int e = blockIdx.x * blockDim.x + threadIdx.x;
    if (e >= N_EDGES) return;
    int is64 = flag[0];
    long long rt  = ld_idx(etype, e, is64);
    long long dst = ld_idx(eidx, (size_t)N_EDGES + e, is64);
    atomicAdd(&cnt8[dst * N_REL + rt], 1u);
}

__global__ void inv_kernel(const unsigned* __restrict__ cnt8, float* __restrict__ invc) {
    int i = blockIdx.x * blockDim.x + threadIdx.x;
    if (i >= N_NODES * N_REL) return;
    unsigned c = cnt8[i];
    invc[i] = 1.0f / (float)(c ? c : 1u);
}

__global__ __launch_bounds__(1024) void scan_kernel(const unsigned* __restrict__ cnt8,
                                                    int* __restrict__ offsets) {
    __shared__ int lds[1024];
    const int t = threadIdx.x;
    const int CH = (N_NODES + 1023) / 1024;
    int lo = t * CH;
    int hi = lo + CH; if (hi > N_NODES) hi = N_NODES;
    if (lo > N_NODES) lo = N_NODES;
    int s = 0;
    for (int i = lo; i < hi; ++i) {
        int c = 0;
        #pragma unroll
        for (int r = 0; r < N_REL; ++r) c += (int)cnt8[i * N_REL + r];
        s += c;
    }
    lds[t] = s;
    __syncthreads();
    for (int o = 1; o < 1024; o <<= 1) {
        int v = (t >= o) ? lds[t - o] : 0;
        __syncthreads();
        lds[t] += v;
        __syncthreads();
    }
    int run = (t == 0) ? 0 : lds[t - 1];
    for (int i = lo; i < hi; ++i) {
        offsets[i] = run;
        int c = 0;
        #pragma unroll
        for (int r = 0; r < N_REL; ++r) c += (int)cnt8[i * N_REL + r];
        run += c;
    }
    if (t == 1023) offsets[N_NODES] = run;
}

__global__ void build_kernel(const void* __restrict__ eidx, const void* __restrict__ etype,
                             const int* __restrict__ flag, const int* __restrict__ offsets,
                             int* __restrict__ cursor, unsigned* __restrict__ ebuf) {
    int e = blockIdx.x * blockDim.x + threadIdx.x;
    if (e >= N_EDGES) return;
    int is64 = flag[0];
    int rt  = (int)ld_idx(etype, e, is64);
    int src = (int)ld_idx(eidx, e, is64);
    int dst = (int)ld_idx(eidx, (size_t)N_EDGES + e, is64);
    int pos = offsets[dst] + atomicAdd(&cursor[dst], 1);
    ebuf[pos] = ((unsigned)src << 3) | (unsigned)rt;
}

__global__ void cvt_bf16_kernel(const float* __restrict__ in, __hip_bfloat16* __restrict__ out,
                                long long n4) {
    long long g = (long long)blockIdx.x * blockDim.x + threadIdx.x;
    if (g >= n4) return;
    float4 v = ((const float4*)in)[g];
    unsigned short o[4];
    o[0] = f2bf(v.x); o[1] = f2bf(v.y); o[2] = f2bf(v.z); o[3] = f2bf(v.w);
    *(short4*)&out[4 * g] = *(const short4*)o;
}

__global__ void make_bt1_kernel(const float* __restrict__ w1, const float* __restrict__ root1,
                                __hip_bfloat16* __restrict__ bt) {
    int g = blockIdx.x * blockDim.x + threadIdx.x;
    const int Kt = N_REL * F_IN + F_IN;
    if (g >= F_HID * Kt) return;
    int n = g / Kt, k = g % Kt;
    float v;
    if (k < N_REL * F_IN) v = w1[(size_t)(k >> 8) * F_IN * F_HID + (size_t)(k & 255) * F_HID + n];
    else                  v = root1[(size_t)(k - N_REL * F_IN) * F_HID + n];
    bt[g] = __float2bfloat16(v);
}

__global__ void make_bt2_kernel(const float* __restrict__ w2, const float* __restrict__ root2,
                                __hip_bfloat16* __restrict__ bt) {
    int g = blockIdx.x * blockDim.x + threadIdx.x;
    if (g >= NC2 * F_HID) return;
    int n = g / F_HID, k = g % F_HID;
    float v = (n < N_REL * F_OUT)
                  ? w2[(size_t)(n >> 7) * F_HID * F_OUT + (size_t)k * F_OUT + (n & 127)]
                  : root2[(size_t)k * F_OUT + (n - N_REL * F_OUT)];
    bt[g] = __float2bfloat16(v);
}

// ---------- layer-1 gather ----------
template <int CR>
__global__ __launch_bounds__(256) void gather1_kernel(
    const __hip_bfloat16* __restrict__ xb, const unsigned* __restrict__ ebuf,
    const int* __restrict__ offsets, const float* __restrict__ invc,
    __hip_bfloat16* __restrict__ aggb, int r0)
{
    int wid  = (blockIdx.x * blockDim.x + threadIdx.x) >> 6;
    int lane = threadIdx.x & 63;
    if (wid >= N_NODES) return;
    int e0 = offsets[wid], e1 = offsets[wid + 1];
    float acc[CR][4];
    #pragma unroll
    for (int c = 0; c < CR; ++c)
        #pragma unroll
        for (int j = 0; j < 4; ++j) acc[c][j] = 0.0f;

    for (int e = e0; e < e1; ++e) {
        unsigned u = ebuf[e];
        int rl = (int)(u & 7u) - r0;
        if (CR < N_REL && (unsigned)rl >= (unsigned)CR) continue;
        unsigned src = u >> 3;
        short4 v = *(const short4*)&xb[(size_t)src * F_IN + lane * 4];
        float f0 = bf2f((unsigned short)v.x), f1 = bf2f((unsigned short)v.y);
        float f2 = bf2f((unsigned short)v.z), f3 = bf2f((unsigned short)v.w);
        int rls = __builtin_amdgcn_readfirstlane(rl);
        #pragma unroll
        for (int c = 0; c < CR; ++c)
            if (rls == c) { acc[c][0] += f0; acc[c][1] += f1; acc[c][2] += f2; acc[c][3] += f3; }
    }
    #pragma unroll
    for (int c = 0; c < CR; ++c) {
        float s = invc[(size_t)wid * N_REL + r0 + c];
        unsigned short o[4];
        o[0] = f2bf(acc[c][0] * s);
        o[1] = f2bf(acc[c][1] * s);
        o[2] = f2bf(acc[c][2] * s);
        o[3] = f2bf(acc[c][3] * s);
        *(short4*)&aggb[((size_t)wid * CR + c) * F_IN + lane * 4] = *(const short4*)o;
    }
}

// ---------- layer-2 gather + root + bias + log_softmax ----------
__global__ __launch_bounds__(256) void gather2_kernel(
    const __hip_bfloat16* __restrict__ z, const unsigned* __restrict__ ebuf,
    const int* __restrict__ offsets, const float* __restrict__ invc,
    const float* __restrict__ b2, float* __restrict__ h)
{
    int wid  = (blockIdx.x * blockDim.x + threadIdx.x) >> 6;
    int lane = threadIdx.x & 63;
    if (wid >= N_NODES) return;
    int e0 = offsets[wid], e1 = offsets[wid + 1];
    float a0 = 0.0f, a1 = 0.0f;
    for (int e = e0; e < e1; ++e) {
        unsigned u = ebuf[e];
        int rt = (int)(u & 7u);
        unsigned src = u >> 3;
        float s = invc[(size_t)wid * N_REL + rt];
        unsigned pv = *(const unsigned*)&z[(size_t)src * NC2 + rt * F_OUT + lane * 2];
        a0 += s * bf2f((unsigned short)(pv & 0xffffu));
        a1 += s * bf2f((unsigned short)(pv >> 16));
    }
    unsigned rv = *(const unsigned*)&z[(size_t)wid * NC2 + N_REL * F_OUT + lane * 2];
    a0 += bf2f((unsigned short)(rv & 0xffffu)) + b2[lane * 2];
    a1 += bf2f((unsigned short)(rv >> 16))     + b2[lane * 2 + 1];

    float m = fmaxf(a0, a1);
    #pragma unroll
    for (int o = 32; o > 0; o >>= 1) m = fmaxf(m, __shfl_xor(m, o));
    float sum = expf(a0 - m) + expf(a1 - m);
    #pragma unroll
    for (int o = 32; o > 0; o >>= 1) sum += __shfl_xor(sum, o);
    float lse = m + logf(sum);
    h[(size_t)wid * F_OUT + lane * 2]     = a0 - lse;
    h[(size_t)wid * F_OUT + lane * 2 + 1] = a1 - lse;
}

// ================= 8-phase counted-vmcnt GEMM (layer 1) =================
// BM=128, BN=256, BK=64, 512 threads = 8 waves (2M x 4N), 64x64 out/wave.
// LDS: 2 K-tile buffers, each split into halves: A halves 64x64 (1 load/thd),
// B halves 128x64 (2 loads/thd). Staging schedule (iteration consumes kt0=2it
// in buf0 phases 1-4, kt1 in buf1 phases 5-8):
//   ph1: A0(kt1)->buf1   ph2: A1(kt1)->buf1   ph3: B0(kt0+2)->buf0
//   ph4: B1(kt0+2)->buf0 [vmcnt(4): kt1 complete, kt0+2 B in flight]
//   ph5: A0(kt0+2)->buf0 ph6: A1(kt0+2)->buf0 ph7: B0(kt1+2)->buf1
//   ph8: B1(kt1+2)->buf1 [vmcnt(4): kt0+2 complete]
// Region safety: buf.B last read ph2 (staged ph3+), buf.A last read ph3
// (staged ph5+ / next-it ph1+) -- every write >=1 barrier after last read.
#define TBM 128
#define TBN 256
#define TBK 64

#define BARX do { __builtin_amdgcn_s_barrier(); __builtin_amdgcn_sched_barrier(0); } while (0)
#define VMW(N) asm volatile("s_waitcnt vmcnt(" #N ")" ::: "memory")
#define MFMA_Q(QR, QC) do {                                                        \
    __builtin_amdgcn_s_setprio(1);                                                 \
    _Pragma("unroll") for (int i2 = 0; i2 < 2; ++i2)                               \
    _Pragma("unroll") for (int j2 = 0; j2 < 2; ++j2)                               \
    _Pragma("unroll") for (int h = 0; h < 2; ++h)                                  \
        acc[(QR)*2 + i2][(QC)*2 + j2] = __builtin_amdgcn_mfma_f32_16x16x32_bf16(   \
            a[i2][h], b[(QC)*2 + j2][h], acc[(QR)*2 + i2][(QC)*2 + j2], 0, 0, 0);  \
    __builtin_amdgcn_s_setprio(0); } while (0)

__global__ __launch_bounds__(512) void gemm_mfma8_kernel(
    const __hip_bfloat16* __restrict__ A1, int K1, int lda1,
    const __hip_bfloat16* __restrict__ A2, int K2, int lda2,
    const __hip_bfloat16* __restrict__ BTa, const __hip_bfloat16* __restrict__ BTb, int ldbt,
    const float* __restrict__ bias,
    float* __restrict__ Cf, __hip_bfloat16* __restrict__ Cb,
    int M, int Nc, int accumulate, int do_relu,
    int gridX, int nwg)
{
    __shared__ __align__(16) __hip_bfloat16 As[2][2 * 4096];   // [buf][half 64x64]
    __shared__ __align__(16) __hip_bfloat16 Bs[2][2 * 8192];   // [buf][half 128x64]

    // bijective XCD swizzle (m204)
    int bid = blockIdx.x;
    int qq = nwg >> 3, rr = nwg & 7;
    int xcd = bid & 7, ii = bid >> 3;
    int wg = (xcd < rr ? xcd * (qq + 1) : rr * (qq + 1) + (xcd - rr) * qq) + ii;
    const int bm = (wg / gridX) * TBM;
    const int bn = (wg % gridX) * TBN;

    const int tid  = threadIdx.x;
    const int lane = tid & 63;
    const int wv   = tid >> 6;      // 0..7
    const int wr   = wv >> 2;       // 0..1
    const int wc   = wv & 3;        // 0..3
    const int r15  = lane & 15;
    const int ksel = lane >> 4;
    const int rsw  = (r15 & 7) << 3;

    const int srow   = tid >> 3;                          // 0..63
    const int swz8   = ((lane & 7) ^ (lane >> 3)) * 8;    // T2 pre-swizzled source col
    const int ldsoff = wv * 512;                          // wave-uniform dest

    const int Ktot = K1 + K2;
    const int nT   = Ktot / TBK;    // even for all our K
    const int nIt  = nT / 2;

    auto stageA = [&](int kt, int bi, int hh) {
        int k0 = kt * TBK;
        const __hip_bfloat16* base = A1; int ld = lda1;
        if (k0 >= K1) { base = A2; ld = lda2; k0 -= K1; }
        int gr = bm + hh * 64 + srow; if (gr >= M) gr = M - 1;
        const __hip_bfloat16* gp = base + (size_t)gr * ld + k0 + swz8;
        __builtin_amdgcn_global_load_lds(
            (const __attribute__((address_space(1))) void*)gp,
            (__attribute__((address_space(3))) void*)&As[bi][hh * 4096 + ldsoff], 16, 0, 0);
    };
    auto stageB = [&](int kt, int bi, int hh) {
        int k0 = kt * TBK;
        const __hip_bfloat16* base = BTa;
        if (k0 >= K1) { base = BTb; k0 -= K1; }
        int n0 = bn + hh * 128 + srow;
        const __hip_bfloat16* gp = base + (size_t)n0 * ldbt + k0 + swz8;
        __builtin_amdgcn_global_load_lds(
            (const __attribute__((address_space(1))) void*)gp,
            (__attribute__((address_space(3))) void*)&Bs[bi][hh * 8192 + ldsoff], 16, 0, 0);
        gp += (size_t)64 * ldbt;
        __builtin_amdgcn_global_load_lds(
            (const __attribute__((address_space(1))) void*)gp,
            (__attribute__((address_space(3))) void*)&Bs[bi][hh * 8192 + 4096 + ldsoff], 16, 0, 0);
    };

    short8 a[2][2], b[4][2];
    auto loadA2 = [&](int bi, int fr0) {
        #pragma unroll
        for (int i2 = 0; i2 < 2; ++i2)
            #pragma unroll
            for (int h = 0; h < 2; ++h)
                a[i2][h] = *(const short8*)&As[bi][wr * 4096 +
                    ((fr0 + i2) * 16 + r15) * 64 + ((h * 32 + ksel * 8) ^ rsw)];
    };
    auto loadB2 = [&](int bi, int fc0) {
        #pragma unroll
        for (int j2 = 0; j2 < 2; ++j2)
            #pragma unroll
            for (int h = 0; h < 2; ++h)
                b[fc0 + j2][h] = *(const short8*)&Bs[bi][(wc >> 1) * 8192 +
                    ((wc & 1) * 64 + (fc0 + j2) * 16 + r15) * 64 + ((h * 32 + ksel * 8) ^ rsw)];
    };

    f32x4 acc[4][4] = {};

    // prologue: kt0 full (6 insts) + kt1 B (4 insts); wait kt0 (oldest 6)
    stageA(0, 0, 0); stageA(0, 0, 1); stageB(0, 0, 0); stageB(0, 0, 1);
    stageB(1, 1, 0); stageB(1, 1, 1);
    VMW(4);
    BARX;

    for (int it = 0; it < nIt; ++it) {
        const int kt0 = 2 * it, kt1 = 2 * it + 1;
        const bool last = (it == nIt - 1);
        // ---- half 0: consume buf0 (kt0) ----
        loadA2(0, 0); loadB2(0, 0); stageA(kt1, 1, 0);
        BARX; MFMA_Q(0, 0); BARX;
        loadB2(0, 2); stageA(kt1, 1, 1);
        BARX; MFMA_Q(0, 1); BARX;
        loadA2(0, 2); if (!last) stageB(kt0 + 2, 0, 0);
        BARX; MFMA_Q(1, 0); BARX;
        if (!last) stageB(kt0 + 2, 0, 1);
        BARX; MFMA_Q(1, 1);
        if (last) { VMW(0); } else { VMW(4); }
        BARX;
        // ---- half 1: consume buf1 (kt1) ----
        loadA2(1, 0); loadB2(1, 0); if (!last) stageA(kt1 + 1, 0, 0);
        BARX; MFMA_Q(0, 0); BARX;
        loadB2(1, 2); if (!last) stageA(kt1 + 1, 0, 1);
        BARX; MFMA_Q(0, 1); BARX;
        loadA2(1, 2); if (!last) stageB(kt1 + 2, 1, 0);
        BARX; MFMA_Q(1, 0); BARX;
        if (!last) stageB(kt1 + 2, 1, 1);
        BARX; MFMA_Q(1, 1);
        if (!last) { VMW(4); }
        BARX;
    }

    // epilogue
    float bv[4];
    #pragma unroll
    for (int fc = 0; fc < 4; ++fc)
        bv[fc] = bias ? bias[bn + wc * 64 + fc * 16 + r15] : 0.0f;

    #pragma unroll
    for (int fr = 0; fr < 4; ++fr) {
        #pragma unroll
        for (int q2 = 0; q2 < 4; ++q2) {
            int row = bm + wr * 64 + fr * 16 + ksel * 4 + q2;
            if (row >= M) continue;
            #pragma unroll
            for (int fc = 0; fc < 4; ++fc) {
                int col = bn + wc * 64 + fc * 16 + r15;
                float v = acc[fr][fc][q2] + bv[fc];
                size_t off = (size_t)row * Nc + col;
                if (accumulate) v += Cf[off];
                if (do_relu) v = fmaxf(v, 0.0f);
                if (Cf) Cf[off] = v;
                if (Cb) Cb[off] = __float2bfloat16(v);
            }
        }
    }
}

// ---------- 2-phase 128x128 GEMM (kept for gemm2, Nc not /256) ----------
#define GBM 128
#define GBN 128
#define GBK 64

__global__ __launch_bounds__(256) void gemm_mfma_kernel(
    const __hip_bfloat16* __restrict__ A1, int K1, int lda1,
    const __hip_bfloat16* __restrict__ A2, int K2, int lda2,
    const __hip_bfloat16* __restrict__ BTa, const __hip_bfloat16* __restrict__ BTb, int ldbt,
    const float* __restrict__ bias,
    float* __restrict__ Cf, __hip_bfloat16* __restrict__ Cb,
    int M, int Nc, int accumulate, int do_relu,
    int gridX, int nwg)
{
    __shared__ __align__(16) __hip_bfloat16 As[2][GBM * GBK];
    __shared__ __align__(16) __hip_bfloat16 Bs[2][GBN * GBK];

    int bid = blockIdx.x;
    int qq = nwg >> 3, rr = nwg & 7;
    int xcd = bid & 7, ii = bid >> 3;
    int wg = (xcd < rr ? xcd * (qq + 1) : rr * (qq + 1) + (xcd - rr) * qq) + ii;
    const int bm = (wg / gridX) * GBM;
    const int bn = (wg % gridX) * GBN;

    const int lane = threadIdx.x & 63;
    const int wv   = threadIdx.x >> 6;
    const int wr   = wv >> 1;
    const int wc   = wv & 1;
    const int r15  = lane & 15;
    const int ksel = lane >> 4;

    const int seg_row = lane >> 3;
    const int seg_col = (((lane & 7) ^ seg_row)) * 8;

    const __hip_bfloat16* a1p[4];
    const __hip_bfloat16* a2p[4];
    const __hip_bfloat16* bap[4];
    const __hip_bfloat16* bbp[4];
    #pragma unroll
    for (int c = 0; c < 4; ++c) {
        int s = wv * 4 + c;
        int row = s * 8 + seg_row;
        int gr = bm + row; if (gr >= M) gr = M - 1;
        a1p[c] = A1 + (size_t)gr * lda1 + seg_col;
        a2p[c] = A2 ? (A2 + (size_t)gr * lda2 + seg_col) : nullptr;
        int n = bn + row;
        bap[c] = BTa + (size_t)n * ldbt + seg_col;
        bbp[c] = BTb ? (BTb + (size_t)n * ldbt + seg_col) : nullptr;
    }

    const int Ktot = K1 + K2;
    const int nT = Ktot / GBK;

    auto stage = [&](int k0, int bi) {
        #pragma unroll
        for (int c = 0; c < 4; ++c) {
            int s = wv * 4 + c;
            const __hip_bfloat16* gp = (k0 < K1) ? (a1p[c] + k0) : (a2p[c] + (k0 - K1));
            __builtin_amdgcn_global_load_lds(
                (const __attribute__((address_space(1))) void*)gp,
                (__attribute__((address_space(3))) void*)&As[bi][s * 512], 16, 0, 0);
        }
        #pragma unroll
        for (int c = 0; c < 4; ++c) {
            int s = wv * 4 + c;
            const __hip_bfloat16* gp = (k0 < K1) ? (bap[c] + k0) : (bbp[c] + (k0 - K1));
            __builtin_amdgcn_global_load_lds(
                (const __attribute__((address_space(1))) void*)gp,
                (__attribute__((address_space(3))) void*)&Bs[bi][s * 512], 16, 0, 0);
        }
    };

    f32x4 acc[4][4] = {};
    stage(0, 0);
    __syncthreads();

    int cur = 0;
    for (int t = 0; t < nT; ++t) {
        if (t + 1 < nT) stage((t + 1) * GBK, cur ^ 1);
        short8 a[4][2], b[4][2];
        const int rsw = (r15 & 7) << 3;
        #pragma unroll
        for (int i = 0; i < 4; ++i)
            #pragma unroll
            for (int h = 0; h < 2; ++h) {
                int col = (h * 32 + ksel * 8) ^ rsw;
                a[i][h] = *(const short8*)&As[cur][(wr * 64 + i * 16 + r15) * GBK + col];
            }
        #pragma unroll
        for (int j = 0; j < 4; ++j)
            #pragma unroll
            for (int h = 0; h < 2; ++h) {
                int col = (h * 32 + ksel * 8) ^ rsw;
                b[j][h] = *(const short8*)&Bs[cur][(wc * 64 + j * 16 + r15) * GBK + col];
            }
        __builtin_amdgcn_s_setprio(1);
        #pragma unroll
        for (int i = 0; i < 4; ++i)
            #pragma unroll
            for (int j = 0; j < 4; ++j)
                #pragma unroll
                for (int h = 0; h < 2; ++h)
                    acc[i][j] = __builtin_amdgcn_mfma_f32_16x16x32_bf16(
                        a[i][h], b[j][h], acc[i][j], 0, 0, 0);
        __builtin_amdgcn_s_setprio(0);
        __syncthreads();
        cur ^= 1;
    }

    float bv[4];
    #pragma unroll
    for (int j = 0; j < 4; ++j)
        bv[j] = bias ? bias[bn + wc * 64 + j * 16 + r15] : 0.0f;

    #pragma unroll
    for (int i = 0; i < 4; ++i) {
        #pragma unroll
        for (int q2 = 0; q2 < 4; ++q2) {
            int row = bm + wr * 64 + i * 16 + ksel * 4 + q2;
            if (row >= M) continue;
            #pragma unroll
            for (int j = 0; j < 4; ++j) {
                int col = bn + wc * 64 + j * 16 + r15;
                float v = acc[i][j][q2] + bv[j];
                size_t off = (size_t)row * Nc + col;
                if (accumulate) v += Cf[off];
                if (do_relu) v = fmaxf(v, 0.0f);
                if (Cf) Cf[off] = v;
                if (Cb) Cb[off] = __float2bfloat16(v);
            }
        }
    }
}

extern "C" void kernel_launch(void* const* d_in, const int* in_sizes, int n_in,
                              void* d_out, int out_size, void* d_ws, size_t ws_size,
                              hipStream_t stream) {
    const float* x     = (const float*)d_in[0];
    const void*  eidx  = d_in[1];
    const void*  etype = d_in[2];
    const float* w1    = (const float*)d_in[3];
    const float* root1 = (const float*)d_in[4];
    const float* b1    = (const float*)d_in[5];
    const float* w2    = (const float*)d_in[6];
    const float* root2 = (const float*)d_in[7];
    const float* b2    = (const float*)d_in[8];

    float* h_out = (float*)d_out;
    float* emb   = (float*)d_out + (size_t)N_NODES * F_OUT;

    char* ws = (char*)d_ws;
    size_t off = 0;
    auto take = [&](size_t bytes) { char* p = ws + off; off = (off + bytes + 255) & ~(size_t)255; return p; };
    int*      flag    = (int*)take(256);
    unsigned* cnt8    = (unsigned*)take((size_t)N_NODES * N_REL * 4);
    float*    invc    = (float*)take((size_t)N_NODES * N_REL * 4);
    int*      offsets = (int*)take(((size_t)N_NODES + 1) * 4);
    int*      cursor  = (int*)take((size_t)N_NODES * 4);
    unsigned* ebuf    = (unsigned*)take((size_t)N_EDGES * 4);
    __hip_bfloat16* xb   = (__hip_bfloat16*)take((size_t)N_NODES * F_IN * 2);
    __hip_bfloat16* embb = (__hip_bfloat16*)take((size_t)N_NODES * F_HID * 2);
    __hip_bfloat16* bt1  = (__hip_bfloat16*)take((size_t)F_HID * (N_REL * F_IN + F_IN) * 2);
    __hip_bfloat16* bt2  = (__hip_bfloat16*)take((size_t)NC2 * F_HID * 2);

    size_t avail = (ws_size > off) ? (ws_size - off) : 0;
    size_t agg8bytes = (size_t)N_NODES * N_REL * F_IN * 2;
    size_t zbytes    = (size_t)N_NODES * NC2 * 2;
    int CR = (avail >= agg8bytes) ? 8 : 4;
    size_t ubytes = agg8bytes > zbytes ? agg8bytes : zbytes;
    if (CR == 4) ubytes = zbytes;
    char* uni = take(ubytes);
    __hip_bfloat16* aggb = (__hip_bfloat16*)uni;
    __hip_bfloat16* z    = (__hip_bfloat16*)uni;

    detect64_kernel<<<1, 64, 0, stream>>>((const int*)etype, flag);
    (void)hipMemsetAsync(cnt8, 0, (size_t)N_NODES * N_REL * 4, stream);
    (void)hipMemsetAsync(cursor, 0, (size_t)N_NODES * 4, stream);
    count_kernel<<<(N_EDGES + 255) / 256, 256, 0, stream>>>(etype, eidx, flag, cnt8);
    inv_kernel<<<(N_NODES * N_REL + 255) / 256, 256, 0, stream>>>(cnt8, invc);
    scan_kernel<<<1, 1024, 0, stream>>>(cnt8, offsets);
    build_kernel<<<(N_EDGES + 255) / 256, 256, 0, stream>>>(eidx, etype, flag, offsets, cursor, ebuf);

    cvt_bf16_kernel<<<(N_NODES * F_IN / 4 + 255) / 256, 256, 0, stream>>>(
        x, xb, (long long)N_NODES * F_IN / 4);
    {
        int tot = F_HID * (N_REL * F_IN + F_IN);
        make_bt1_kernel<<<(tot + 255) / 256, 256, 0, stream>>>(w1, root1, bt1);
        tot = NC2 * F_HID;
        make_bt2_kernel<<<(tot + 255) / 256, 256, 0, stream>>>(w2, root2, bt2);
    }

    const int MBLK128 = (N_NODES + GBM - 1) / GBM;    // 391 (2-phase kernel)
    const int MBLK8   = (N_NODES + TBM - 1) / TBM;    // 391 (8-phase kernel)
    const int GWAVE_BLOCKS = (N_NODES * 64 + 255) / 256;

    // ---------------- layer 1 (8-phase GEMM) ----------------
    for (int r0 = 0; r0 < N_REL; r0 += CR) {
        if (CR == 8)
            gather1_kernel<8><<<GWAVE_BLOCKS, 256, 0, stream>>>(xb, ebuf, offsets, invc, aggb, r0);
        else
            gather1_kernel<4><<<GWAVE_BLOCKS, 256, 0, stream>>>(xb, ebuf, offsets, invc, aggb, r0);
        int first = (r0 == 0), last = (r0 + CR >= N_REL);
        int gX = F_HID / TBN, nwg = gX * MBLK8;       // 2 x 391
        gemm_mfma8_kernel<<<nwg, 512, 0, stream>>>(
            aggb, CR * F_IN, CR * F_IN,
            first ? xb : nullptr, first ? F_IN : 0, F_IN,
            bt1 + (size_t)r0 * F_IN, bt1 + (size_t)N_REL * F_IN, N_REL * F_IN + F_IN,
            first ? b1 : nullptr,
            emb, last ? embb : nullptr,
            N_NODES, F_HID, first ? 0 : 1, last ? 1 : 0,
            gX, nwg);
    }

    // ---------------- layer 2 (2-phase GEMM, Nc=1152) ----------------
    {
        int gX = NC2 / GBN, nwg = gX * MBLK128;
        gemm_mfma_kernel<<<nwg, 256, 0, stream>>>(
            embb, F_HID, F_HID, nullptr, 0, 0,
            bt2, nullptr, F_HID,
            nullptr, nullptr, z, N_NODES, NC2, 0, 0,
            gX, nwg);
    }

    gather2_kernel<<<GWAVE_BLOCKS, 256, 0, stream>>>(z, ebuf, offsets, invc, b2, h_out);
}

// Round 8
// 742.720 us; speedup vs baseline: 6.7857x; 1.0367x over previous
//
#include <hip/hip_runtime.h>
#include <hip/hip_bf16.h>
#include <cstddef>
#include <cstdint>

#define N_NODES 50000
#define N_EDGES 800000
#define N_REL 8
#define F_IN 256
#define F_HID 512
#define F_OUT 128
#define NC2 (N_REL * F_OUT + F_OUT)   // 1152

typedef __attribute__((ext_vector_type(8))) short short8;
typedef __attribute__((ext_vector_type(4))) float f32x4;

__device__ __forceinline__ float bf2f(unsigned short u) {
    return __uint_as_float(((unsigned)u) << 16);
}
__device__ __forceinline__ unsigned short f2bf(float f) {
    __hip_bfloat16 h = __float2bfloat16(f);
    return *reinterpret_cast<unsigned short*>(&h);
}

// ---------- int64-vs-int32 edge dtype detection ----------
__global__ void detect64_kernel(const int* __restrict__ et, int* __restrict__ flag) {
    int v = et[2 * threadIdx.x + 1];
    unsigned long long any = __ballot(v != 0);
    if (threadIdx.x == 0) flag[0] = (any == 0ULL) ? 1 : 0;
}

__device__ __forceinline__ long long ld_idx(const void* __restrict__ p, size_t i, int is64) {
    return is64 ? ((const long long*)p)[i] : (long long)((const int*)p)[i];
}

__global__ void count_kernel(const void* __restrict__ etype, const void* __restrict__ eidx,
                             const int* __restrict__ flag, unsigned* __restrict__ cnt8) {
    int e = blockIdx.x * blockDim.x + threadIdx.x;
    if (e >= N_EDGES) return;
    int is64 = flag[0];
    long long rt  = ld_idx(etype, e, is64);
    long long dst = ld_idx(eidx, (size_t)N_EDGES + e, is64);
    atomicAdd(&cnt8[dst * N_REL + rt], 1u);
}

__global__ void inv_kernel(const unsigned* __restrict__ cnt8, float* __restrict__ invc) {
    int i = blockIdx.x * blockDim.x + threadIdx.x;
    if (i >= N_NODES * N_REL) return;
    unsigned c = cnt8[i];
    invc[i] = 1.0f / (float)(c ? c : 1u);
}

__global__ __launch_bounds__(1024) void scan_kernel(const unsigned* __restrict__ cnt8,
                                                    int* __restrict__ offsets) {
    __shared__ int lds[1024];
    const int t = threadIdx.x;
    const int CH = (N_NODES + 1023) / 1024;
    int lo = t * CH;
    int hi = lo + CH; if (hi > N_NODES) hi = N_NODES;
    if (lo > N_NODES) lo = N_NODES;
    int s = 0;
    for (int i = lo; i < hi; ++i) {
        int c = 0;
        #pragma unroll
        for (int r = 0; r < N_REL; ++r) c += (int)cnt8[i * N_REL + r];
        s += c;
    }
    lds[t] = s;
    __syncthreads();
    for (int o = 1; o < 1024; o <<= 1) {
        int v = (t >= o) ? lds[t - o] : 0;
        __syncthreads();
        lds[t] += v;
        __syncthreads();
    }
    int run = (t == 0) ? 0 : lds[t - 1];
    for (int i = lo; i < hi; ++i) {
        offsets[i] = run;
        int c = 0;
        #pragma unroll
        for (int r = 0; r < N_REL; ++r) c += (int)cnt8[i * N_REL + r];
        run += c;
    }
    if (t == 1023) offsets[N_NODES] = run;
}

__global__ void build_kernel(const void* __restrict__ eidx, const void* __restrict__ etype,
                             const int* __restrict__ flag, const int* __restrict__ offsets,
                             int* __restrict__ cursor, unsigned* __restrict__ ebuf) {
    int e = blockIdx.x * blockDim.x + threadIdx.x;
    if (e >= N_EDGES) return;
    int is64 = flag[0];
    int rt  = (int)ld_idx(etype, e, is64);
    int src = (int)ld_idx(eidx, e, is64);
    int dst = (int)ld_idx(eidx, (size_t)N_EDGES + e, is64);
    int pos = offsets[dst] + atomicAdd(&cursor[dst], 1);
    ebuf[pos] = ((unsigned)src << 3) | (unsigned)rt;
}

__global__ void cvt_bf16_kernel(const float* __restrict__ in, __hip_bfloat16* __restrict__ out,
                                long long n4) {
    long long g = (long long)blockIdx.x * blockDim.x + threadIdx.x;
    if (g >= n4) return;
    float4 v = ((const float4*)in)[g];
    unsigned short o[4];
    o[0] = f2bf(v.x); o[1] = f2bf(v.y); o[2] = f2bf(v.z); o[3] = f2bf(v.w);
    *(short4*)&out[4 * g] = *(const short4*)o;
}

__global__ void make_bt1_kernel(const float* __restrict__ w1, const float* __restrict__ root1,
                                __hip_bfloat16* __restrict__ bt) {
    int g = blockIdx.x * blockDim.x + threadIdx.x;
    const int Kt = N_REL * F_IN + F_IN;
    if (g >= F_HID * Kt) return;
    int n = g / Kt, k = g % Kt;
    float v;
    if (k < N_REL * F_IN) v = w1[(size_t)(k >> 8) * F_IN * F_HID + (size_t)(k & 255) * F_HID + n];
    else                  v = root1[(size_t)(k - N_REL * F_IN) * F_HID + n];
    bt[g] = __float2bfloat16(v);
}

__global__ void make_bt2_kernel(const float* __restrict__ w2, const float* __restrict__ root2,
                                __hip_bfloat16* __restrict__ bt) {
    int g = blockIdx.x * blockDim.x + threadIdx.x;
    if (g >= NC2 * F_HID) return;
    int n = g / F_HID, k = g % F_HID;
    float v = (n < N_REL * F_OUT)
                  ? w2[(size_t)(n >> 7) * F_HID * F_OUT + (size_t)k * F_OUT + (n & 127)]
                  : root2[(size_t)k * F_OUT + (n - N_REL * F_OUT)];
    bt[g] = __float2bfloat16(v);
}

// ---------- layer-1 gather ----------
template <int CR>
__global__ __launch_bounds__(256) void gather1_kernel(
    const __hip_bfloat16* __restrict__ xb, const unsigned* __restrict__ ebuf,
    const int* __restrict__ offsets, const float* __restrict__ invc,
    __hip_bfloat16* __restrict__ aggb, int r0)
{
    int wid  = (blockIdx.x * blockDim.x + threadIdx.x) >> 6;
    int lane = threadIdx.x & 63;
    if (wid >= N_NODES) return;
    int e0 = offsets[wid], e1 = offsets[wid + 1];
    float acc[CR][4];
    #pragma unroll
    for (int c = 0; c < CR; ++c)
        #pragma unroll
        for (int j = 0; j < 4; ++j) acc[c][j] = 0.0f;

    for (int e = e0; e < e1; ++e) {
        unsigned u = ebuf[e];
        int rl = (int)(u & 7u) - r0;
        if (CR < N_REL && (unsigned)rl >= (unsigned)CR) continue;
        unsigned src = u >> 3;
        short4 v = *(const short4*)&xb[(size_t)src * F_IN + lane * 4];
        float f0 = bf2f((unsigned short)v.x), f1 = bf2f((unsigned short)v.y);
        float f2 = bf2f((unsigned short)v.z), f3 = bf2f((unsigned short)v.w);
        int rls = __builtin_amdgcn_readfirstlane(rl);
        #pragma unroll
        for (int c = 0; c < CR; ++c)
            if (rls == c) { acc[c][0] += f0; acc[c][1] += f1; acc[c][2] += f2; acc[c][3] += f3; }
    }
    #pragma unroll
    for (int c = 0; c < CR; ++c) {
        float s = invc[(size_t)wid * N_REL + r0 + c];
        unsigned short o[4];
        o[0] = f2bf(acc[c][0] * s);
        o[1] = f2bf(acc[c][1] * s);
        o[2] = f2bf(acc[c][2] * s);
        o[3] = f2bf(acc[c][3] * s);
        *(short4*)&aggb[((size_t)wid * CR + c) * F_IN + lane * 4] = *(const short4*)o;
    }
}

// ---------- layer-2 gather + root + bias + log_softmax ----------
__global__ __launch_bounds__(256) void gather2_kernel(
    const __hip_bfloat16* __restrict__ z, const unsigned* __restrict__ ebuf,
    const int* __restrict__ offsets, const float* __restrict__ invc,
    const float* __restrict__ b2, float* __restrict__ h)
{
    int wid  = (blockIdx.x * blockDim.x + threadIdx.x) >> 6;
    int lane = threadIdx.x & 63;
    if (wid >= N_NODES) return;
    int e0 = offsets[wid], e1 = offsets[wid + 1];
    float a0 = 0.0f, a1 = 0.0f;
    for (int e = e0; e < e1; ++e) {
        unsigned u = ebuf[e];
        int rt = (int)(u & 7u);
        unsigned src = u >> 3;
        float s = invc[(size_t)wid * N_REL + rt];
        unsigned pv = *(const unsigned*)&z[(size_t)src * NC2 + rt * F_OUT + lane * 2];
        a0 += s * bf2f((unsigned short)(pv & 0xffffu));
        a1 += s * bf2f((unsigned short)(pv >> 16));
    }
    unsigned rv = *(const unsigned*)&z[(size_t)wid * NC2 + N_REL * F_OUT + lane * 2];
    a0 += bf2f((unsigned short)(rv & 0xffffu)) + b2[lane * 2];
    a1 += bf2f((unsigned short)(rv >> 16))     + b2[lane * 2 + 1];

    float m = fmaxf(a0, a1);
    #pragma unroll
    for (int o = 32; o > 0; o >>= 1) m = fmaxf(m, __shfl_xor(m, o));
    float sum = expf(a0 - m) + expf(a1 - m);
    #pragma unroll
    for (int o = 32; o > 0; o >>= 1) sum += __shfl_xor(sum, o);
    float lse = m + logf(sum);
    h[(size_t)wid * F_OUT + lane * 2]     = a0 - lse;
    h[(size_t)wid * F_OUT + lane * 2 + 1] = a1 - lse;
}

// ======== unified 8-phase counted-vmcnt GEMM, 128x128, 4 waves, 64KB LDS ========
// 2 blocks/CU. Per K-tile: A 128x64 (4 insts/thd) + B 128x64 (4 insts/thd).
// Iteration (2 K-tiles kt0,kt1): phases 1-4 consume buf0(kt0), 5-8 consume buf1(kt1).
// Staging ledger (per-thread issue order; VMW(4) keeps newest 4 in flight):
//   entering iter: [B(kt1)->b1 x4] outstanding, buf0 complete.
//   ph1-2: A(kt1)->b1 x4   ph3-4: B(kt0+2)->b0 x4
//   VMW(4): queue=[B(kt1)4][A(kt1)4][B(kt0+2)4] -> buf1 complete.
//   ph5-6: A(kt0+2)->b0 x4 ph7-8: B(kt1+2)->b1 x4
//   VMW(4): queue=[B(kt0+2)4][A(kt0+2)4][B(kt1+2)4] -> buf0(kt0+2) complete.
// Write-after-read: b1.A written ph1-2, last read prev ph7 (>=2 barriers);
// b0.B written ph3-4, last read ph2; b0.A written ph5-6, last read ph3;
// b1.B written ph7-8, last read ph6. All separated by >=1 barrier.
#define TBM 128
#define TBN 128
#define TBK 64

#define BARX do { __builtin_amdgcn_s_barrier(); __builtin_amdgcn_sched_barrier(0); } while (0)
#define VMW(N) asm volatile("s_waitcnt vmcnt(" #N ")" ::: "memory")
#define MFMA_Q(QR, QC) do {                                                        \
    __builtin_amdgcn_s_setprio(1);                                                 \
    _Pragma("unroll") for (int i2 = 0; i2 < 2; ++i2)                               \
    _Pragma("unroll") for (int j2 = 0; j2 < 2; ++j2)                               \
    _Pragma("unroll") for (int h = 0; h < 2; ++h)                                  \
        acc[(QR)*2 + i2][(QC)*2 + j2] = __builtin_amdgcn_mfma_f32_16x16x32_bf16(   \
            a[i2][h], b[(QC)*2 + j2][h], acc[(QR)*2 + i2][(QC)*2 + j2], 0, 0, 0);  \
    __builtin_amdgcn_s_setprio(0); } while (0)

__global__ __launch_bounds__(256, 2) void gemm8p_kernel(
    const __hip_bfloat16* __restrict__ A1, int K1, int lda1,
    const __hip_bfloat16* __restrict__ A2, int K2, int lda2,
    const __hip_bfloat16* __restrict__ BTa, const __hip_bfloat16* __restrict__ BTb, int ldbt,
    const float* __restrict__ bias,
    float* __restrict__ Cf, __hip_bfloat16* __restrict__ Cb,
    int M, int Nc, int accumulate, int do_relu,
    int gridX, int nwg)
{
    __shared__ __align__(16) __hip_bfloat16 As[2][TBM * TBK];   // 2 x 16KB
    __shared__ __align__(16) __hip_bfloat16 Bs[2][TBN * TBK];   // 2 x 16KB

    // bijective XCD swizzle (m204)
    int bid = blockIdx.x;
    int qq = nwg >> 3, rr = nwg & 7;
    int xcd = bid & 7, ii = bid >> 3;
    int wg = (xcd < rr ? xcd * (qq + 1) : rr * (qq + 1) + (xcd - rr) * qq) + ii;
    const int bm = (wg / gridX) * TBM;
    const int bn = (wg % gridX) * TBN;

    const int tid  = threadIdx.x;
    const int lane = tid & 63;
    const int wv   = tid >> 6;      // 0..3
    const int wr   = wv >> 1;       // 0..1
    const int wc   = wv & 1;        // 0..1
    const int r15  = lane & 15;
    const int ksel = lane >> 4;
    const int rsw  = (r15 & 7) << 3;

    const int srow = tid >> 3;                          // 0..31 (row within 32-row segment)
    const int swz8 = ((tid & 7) ^ (srow & 7)) * 8;      // T2 pre-swizzled source col

    const int Ktot = K1 + K2;
    const int nT   = Ktot / TBK;    // even for all our K (36, 20, 16, 8)
    const int nIt  = nT / 2;

    // stage 2 of the 4 A-insts of K-tile kt into buffer bi (c0 in {0,2})
    auto stageA = [&](int kt, int bi, int c0) {
        int k0 = kt * TBK;
        const __hip_bfloat16* base = A1; int ld = lda1;
        if (k0 >= K1) { base = A2; ld = lda2; k0 -= K1; }
        #pragma unroll
        for (int c = c0; c < c0 + 2; ++c) {
            int gr = bm + c * 32 + srow; if (gr >= M) gr = M - 1;
            const __hip_bfloat16* gp = base + (size_t)gr * ld + k0 + swz8;
            __builtin_amdgcn_global_load_lds(
                (const __attribute__((address_space(1))) void*)gp,
                (__attribute__((address_space(3))) void*)&As[bi][c * 2048 + tid * 8], 16, 0, 0);
        }
    };
    auto stageB = [&](int kt, int bi, int c0) {
        int k0 = kt * TBK;
        const __hip_bfloat16* base = BTa;
        if (k0 >= K1) { base = BTb; k0 -= K1; }
        #pragma unroll
        for (int c = c0; c < c0 + 2; ++c) {
            int n0 = bn + c * 32 + srow;
            const __hip_bfloat16* gp = base + (size_t)n0 * ldbt + k0 + swz8;
            __builtin_amdgcn_global_load_lds(
                (const __attribute__((address_space(1))) void*)gp,
                (__attribute__((address_space(3))) void*)&Bs[bi][c * 2048 + tid * 8], 16, 0, 0);
        }
    };

    short8 a[2][2], b[4][2];
    auto loadA2 = [&](int bi, int fr0) {
        #pragma unroll
        for (int i2 = 0; i2 < 2; ++i2)
            #pragma unroll
            for (int h = 0; h < 2; ++h)
                a[i2][h] = *(const short8*)&As[bi][(wr * 64 + (fr0 + i2) * 16 + r15) * 64 +
                                                   ((h * 32 + ksel * 8) ^ rsw)];
    };
    auto loadB2 = [&](int bi, int fc0) {
        #pragma unroll
        for (int j2 = 0; j2 < 2; ++j2)
            #pragma unroll
            for (int h = 0; h < 2; ++h)
                b[fc0 + j2][h] = *(const short8*)&Bs[bi][(wc * 64 + (fc0 + j2) * 16 + r15) * 64 +
                                                         ((h * 32 + ksel * 8) ^ rsw)];
    };

    f32x4 acc[4][4] = {};

    // prologue: kt0 full (8 insts) + B(kt1) (4 insts); wait oldest 8
    stageA(0, 0, 0); stageA(0, 0, 2); stageB(0, 0, 0); stageB(0, 0, 2);
    stageB(1, 1, 0); stageB(1, 1, 2);
    VMW(4);
    BARX;

    for (int it = 0; it < nIt; ++it) {
        const int kt0 = 2 * it, kt1 = 2 * it + 1;
        const bool last = (it == nIt - 1);
        // ---- half 0: consume buf0 (kt0) ----
        loadA2(0, 0); loadB2(0, 0); stageA(kt1, 1, 0);
        BARX; MFMA_Q(0, 0); BARX;
        loadB2(0, 2); stageA(kt1, 1, 2);
        BARX; MFMA_Q(0, 1); BARX;
        loadA2(0, 2); if (!last) stageB(kt0 + 2, 0, 0);
        BARX; MFMA_Q(1, 0); BARX;
        if (!last) stageB(kt0 + 2, 0, 2);
        BARX; MFMA_Q(1, 1);
        if (last) { VMW(0); } else { VMW(4); }
        BARX;
        // ---- half 1: consume buf1 (kt1) ----
        loadA2(1, 0); loadB2(1, 0); if (!last) stageA(kt0 + 2, 0, 0);
        BARX; MFMA_Q(0, 0); BARX;
        loadB2(1, 2); if (!last) stageA(kt0 + 2, 0, 2);
        BARX; MFMA_Q(0, 1); BARX;
        loadA2(1, 2); if (!last) stageB(kt1 + 2, 1, 0);
        BARX; MFMA_Q(1, 0); BARX;
        if (!last) stageB(kt1 + 2, 1, 2);
        BARX; MFMA_Q(1, 1);
        if (!last) { VMW(4); }
        BARX;
    }

    // epilogue
    float bv[4];
    #pragma unroll
    for (int fc = 0; fc < 4; ++fc)
        bv[fc] = bias ? bias[bn + wc * 64 + fc * 16 + r15] : 0.0f;

    #pragma unroll
    for (int fr = 0; fr < 4; ++fr) {
        #pragma unroll
        for (int q2 = 0; q2 < 4; ++q2) {
            int row = bm + wr * 64 + fr * 16 + ksel * 4 + q2;
            if (row >= M) continue;
            #pragma unroll
            for (int fc = 0; fc < 4; ++fc) {
                int col = bn + wc * 64 + fc * 16 + r15;
                float v = acc[fr][fc][q2] + bv[fc];
                size_t off = (size_t)row * Nc + col;
                if (accumulate) v += Cf[off];
                if (do_relu) v = fmaxf(v, 0.0f);
                if (Cf) Cf[off] = v;
                if (Cb) Cb[off] = __float2bfloat16(v);
            }
        }
    }
}

extern "C" void kernel_launch(void* const* d_in, const int* in_sizes, int n_in,
                              void* d_out, int out_size, void* d_ws, size_t ws_size,
                              hipStream_t stream) {
    const float* x     = (const float*)d_in[0];
    const void*  eidx  = d_in[1];
    const void*  etype = d_in[2];
    const float* w1    = (const float*)d_in[3];
    const float* root1 = (const float*)d_in[4];
    const float* b1    = (const float*)d_in[5];
    const float* w2    = (const float*)d_in[6];
    const float* root2 = (const float*)d_in[7];
    const float* b2    = (const float*)d_in[8];

    float* h_out = (float*)d_out;
    float* emb   = (float*)d_out + (size_t)N_NODES * F_OUT;

    char* ws = (char*)d_ws;
    size_t off = 0;
    auto take = [&](size_t bytes) { char* p = ws + off; off = (off + bytes + 255) & ~(size_t)255; return p; };
    int*      flag    = (int*)take(256);
    unsigned* cnt8    = (unsigned*)take((size_t)N_NODES * N_REL * 4);
    float*    invc    = (float*)take((size_t)N_NODES * N_REL * 4);
    int*      offsets = (int*)take(((size_t)N_NODES + 1) * 4);
    int*      cursor  = (int*)take((size_t)N_NODES * 4);
    unsigned* ebuf    = (unsigned*)take((size_t)N_EDGES * 4);
    __hip_bfloat16* xb   = (__hip_bfloat16*)take((size_t)N_NODES * F_IN * 2);
    __hip_bfloat16* embb = (__hip_bfloat16*)take((size_t)N_NODES * F_HID * 2);
    __hip_bfloat16* bt1  = (__hip_bfloat16*)take((size_t)F_HID * (N_REL * F_IN + F_IN) * 2);
    __hip_bfloat16* bt2  = (__hip_bfloat16*)take((size_t)NC2 * F_HID * 2);

    size_t avail = (ws_size > off) ? (ws_size - off) : 0;
    size_t agg8bytes = (size_t)N_NODES * N_REL * F_IN * 2;
    size_t zbytes    = (size_t)N_NODES * NC2 * 2;
    int CR = (avail >= agg8bytes) ? 8 : 4;
    size_t ubytes = agg8bytes > zbytes ? agg8bytes : zbytes;
    if (CR == 4) ubytes = zbytes;
    char* uni = take(ubytes);
    __hip_bfloat16* aggb = (__hip_bfloat16*)uni;
    __hip_bfloat16* z    = (__hip_bfloat16*)uni;

    detect64_kernel<<<1, 64, 0, stream>>>((const int*)etype, flag);
    (void)hipMemsetAsync(cnt8, 0, (size_t)N_NODES * N_REL * 4, stream);
    (void)hipMemsetAsync(cursor, 0, (size_t)N_NODES * 4, stream);
    count_kernel<<<(N_EDGES + 255) / 256, 256, 0, stream>>>(etype, eidx, flag, cnt8);
    inv_kernel<<<(N_NODES * N_REL + 255) / 256, 256, 0, stream>>>(cnt8, invc);
    scan_kernel<<<1, 1024, 0, stream>>>(cnt8, offsets);
    build_kernel<<<(N_EDGES + 255) / 256, 256, 0, stream>>>(eidx, etype, flag, offsets, cursor, ebuf);

    cvt_bf16_kernel<<<(N_NODES * F_IN / 4 + 255) / 256, 256, 0, stream>>>(
        x, xb, (long long)N_NODES * F_IN / 4);
    {
        int tot = F_HID * (N_REL * F_IN + F_IN);
        make_bt1_kernel<<<(tot + 255) / 256, 256, 0, stream>>>(w1, root1, bt1);
        tot = NC2 * F_HID;
        make_bt2_kernel<<<(tot + 255) / 256, 256, 0, stream>>>(w2, root2, bt2);
    }

    const int MBLK = (N_NODES + TBM - 1) / TBM;       // 391
    const int GWAVE_BLOCKS = (N_NODES * 64 + 255) / 256;

    // ---------------- layer 1 (8-phase 128x128 GEMM) ----------------
    for (int r0 = 0; r0 < N_REL; r0 += CR) {
        if (CR == 8)
            gather1_kernel<8><<<GWAVE_BLOCKS, 256, 0, stream>>>(xb, ebuf, offsets, invc, aggb, r0);
        else
            gather1_kernel<4><<<GWAVE_BLOCKS, 256, 0, stream>>>(xb, ebuf, offsets, invc, aggb, r0);
        int first = (r0 == 0), last = (r0 + CR >= N_REL);
        int gX = F_HID / TBN, nwg = gX * MBLK;        // 4 x 391
        gemm8p_kernel<<<nwg, 256, 0, stream>>>(
            aggb, CR * F_IN, CR * F_IN,
            first ? xb : nullptr, first ? F_IN : 0, F_IN,
            bt1 + (size_t)r0 * F_IN, bt1 + (size_t)N_REL * F_IN, N_REL * F_IN + F_IN,
            first ? b1 : nullptr,
            emb, last ? embb : nullptr,
            N_NODES, F_HID, first ? 0 : 1, last ? 1 : 0,
            gX, nwg);
    }

    // ---------------- layer 2 (same kernel, Nc=1152=9x128) ----------------
    {
        int gX = NC2 / TBN, nwg = gX * MBLK;          // 9 x 391
        gemm8p_kernel<<<nwg, 256, 0, stream>>>(
            embb, F_HID, F_HID, nullptr, 0, 0,
            bt2, nullptr, F_HID,
            nullptr, nullptr, z, N_NODES, NC2, 0, 0,
            gX, nwg);
    }

    gather2_kernel<<<GWAVE_BLOCKS, 256, 0, stream>>>(z, ebuf, offsets, invc, b2, h_out);
}

// Round 9
// 713.149 us; speedup vs baseline: 7.0671x; 1.0415x over previous
//
#include <hip/hip_runtime.h>
#include <hip/hip_bf16.h>
#include <cstddef>
#include <cstdint>

#define N_NODES 50000
#define N_EDGES 800000
#define N_REL 8
#define F_IN 256
#define F_HID 512
#define F_OUT 128
#define NC2 (N_REL * F_OUT + F_OUT)   // 1152

typedef __attribute__((ext_vector_type(8))) short short8;
typedef __attribute__((ext_vector_type(4))) float f32x4;

__device__ __forceinline__ float bf2f(unsigned short u) {
    return __uint_as_float(((unsigned)u) << 16);
}
__device__ __forceinline__ unsigned short f2bf(float f) {
    __hip_bfloat16 h = __float2bfloat16(f);
    return *reinterpret_cast<unsigned short*>(&h);
}

// ---------- int64-vs-int32 edge dtype detection ----------
__global__ void detect64_kernel(const int* __restrict__ et, int* __restrict__ flag) {
    int v = et[2 * threadIdx.x + 1];
    unsigned long long any = __ballot(v != 0);
    if (threadIdx.x == 0) flag[0] = (any == 0ULL) ? 1 : 0;
}

__device__ __forceinline__ long long ld_idx(const void* __restrict__ p, size_t i, int is64) {
    return is64 ? ((const long long*)p)[i] : (long long)((const int*)p)[i];
}

__global__ void count_kernel(const void* __restrict__ etype, const void* __restrict__ eidx,
                             const int* __restrict__ flag, unsigned* __restrict__ cnt8) {
    int e = blockIdx.x * blockDim.x + threadIdx.x;
    if (e >= N_EDGES) return;
    int is64 = flag[0];
    long long rt  = ld_idx(etype, e, is64);
    long long dst = ld_idx(eidx, (size_t)N_EDGES + e, is64);
    atomicAdd(&cnt8[dst * N_REL + rt], 1u);
}

__global__ void inv_kernel(const unsigned* __restrict__ cnt8, float* __restrict__ invc) {
    int i = blockIdx.x * blockDim.x + threadIdx.x;
    if (i >= N_NODES * N_REL) return;
    unsigned c = cnt8[i];
    invc[i] = 1.0f / (float)(c ? c : 1u);
}

__global__ __launch_bounds__(1024) void scan_kernel(const unsigned* __restrict__ cnt8,
                                                    int* __restrict__ offsets) {
    __shared__ int lds[1024];
    const int t = threadIdx.x;
    const int CH = (N_NODES + 1023) / 1024;
    int lo = t * CH;
    int hi = lo + CH; if (hi > N_NODES) hi = N_NODES;
    if (lo > N_NODES) lo = N_NODES;
    int s = 0;
    for (int i = lo; i < hi; ++i) {
        int c = 0;
        #pragma unroll
        for (int r = 0; r < N_REL; ++r) c += (int)cnt8[i * N_REL + r];
        s += c;
    }
    lds[t] = s;
    __syncthreads();
    for (int o = 1; o < 1024; o <<= 1) {
        int v = (t >= o) ? lds[t - o] : 0;
        __syncthreads();
        lds[t] += v;
        __syncthreads();
    }
    int run = (t == 0) ? 0 : lds[t - 1];
    for (int i = lo; i < hi; ++i) {
        offsets[i] = run;
        int c = 0;
        #pragma unroll
        for (int r = 0; r < N_REL; ++r) c += (int)cnt8[i * N_REL + r];
        run += c;
    }
    if (t == 1023) offsets[N_NODES] = run;
}

__global__ void build_kernel(const void* __restrict__ eidx, const void* __restrict__ etype,
                             const int* __restrict__ flag, const int* __restrict__ offsets,
                             int* __restrict__ cursor, unsigned* __restrict__ ebuf) {
    int e = blockIdx.x * blockDim.x + threadIdx.x;
    if (e >= N_EDGES) return;
    int is64 = flag[0];
    int rt  = (int)ld_idx(etype, e, is64);
    int src = (int)ld_idx(eidx, e, is64);
    int dst = (int)ld_idx(eidx, (size_t)N_EDGES + e, is64);
    int pos = offsets[dst] + atomicAdd(&cursor[dst], 1);
    ebuf[pos] = ((unsigned)src << 3) | (unsigned)rt;
}

__global__ void cvt_bf16_kernel(const float* __restrict__ in, __hip_bfloat16* __restrict__ out,
                                long long n4) {
    long long g = (long long)blockIdx.x * blockDim.x + threadIdx.x;
    if (g >= n4) return;
    float4 v = ((const float4*)in)[g];
    unsigned short o[4];
    o[0] = f2bf(v.x); o[1] = f2bf(v.y); o[2] = f2bf(v.z); o[3] = f2bf(v.w);
    *(short4*)&out[4 * g] = *(const short4*)o;
}

__global__ void make_bt1_kernel(const float* __restrict__ w1, const float* __restrict__ root1,
                                __hip_bfloat16* __restrict__ bt) {
    int g = blockIdx.x * blockDim.x + threadIdx.x;
    const int Kt = N_REL * F_IN + F_IN;
    if (g >= F_HID * Kt) return;
    int n = g / Kt, k = g % Kt;
    float v;
    if (k < N_REL * F_IN) v = w1[(size_t)(k >> 8) * F_IN * F_HID + (size_t)(k & 255) * F_HID + n];
    else                  v = root1[(size_t)(k - N_REL * F_IN) * F_HID + n];
    bt[g] = __float2bfloat16(v);
}

__global__ void make_bt2_kernel(const float* __restrict__ w2, const float* __restrict__ root2,
                                __hip_bfloat16* __restrict__ bt) {
    int g = blockIdx.x * blockDim.x + threadIdx.x;
    if (g >= NC2 * F_HID) return;
    int n = g / F_HID, k = g % F_HID;
    float v = (n < N_REL * F_OUT)
                  ? w2[(size_t)(n >> 7) * F_HID * F_OUT + (size_t)k * F_OUT + (n & 127)]
                  : root2[(size_t)k * F_OUT + (n - N_REL * F_OUT)];
    bt[g] = __float2bfloat16(v);
}

// ---------- layer-1 gather ----------
template <int CR>
__global__ __launch_bounds__(256) void gather1_kernel(
    const __hip_bfloat16* __restrict__ xb, const unsigned* __restrict__ ebuf,
    const int* __restrict__ offsets, const float* __restrict__ invc,
    __hip_bfloat16* __restrict__ aggb, int r0)
{
    int wid  = (blockIdx.x * blockDim.x + threadIdx.x) >> 6;
    int lane = threadIdx.x & 63;
    if (wid >= N_NODES) return;
    int e0 = offsets[wid], e1 = offsets[wid + 1];
    float acc[CR][4];
    #pragma unroll
    for (int c = 0; c < CR; ++c)
        #pragma unroll
        for (int j = 0; j < 4; ++j) acc[c][j] = 0.0f;

    for (int e = e0; e < e1; ++e) {
        unsigned u = ebuf[e];
        int rl = (int)(u & 7u) - r0;
        if (CR < N_REL && (unsigned)rl >= (unsigned)CR) continue;
        unsigned src = u >> 3;
        short4 v = *(const short4*)&xb[(size_t)src * F_IN + lane * 4];
        float f0 = bf2f((unsigned short)v.x), f1 = bf2f((unsigned short)v.y);
        float f2 = bf2f((unsigned short)v.z), f3 = bf2f((unsigned short)v.w);
        int rls = __builtin_amdgcn_readfirstlane(rl);
        #pragma unroll
        for (int c = 0; c < CR; ++c)
            if (rls == c) { acc[c][0] += f0; acc[c][1] += f1; acc[c][2] += f2; acc[c][3] += f3; }
    }
    #pragma unroll
    for (int c = 0; c < CR; ++c) {
        float s = invc[(size_t)wid * N_REL + r0 + c];
        unsigned short o[4];
        o[0] = f2bf(acc[c][0] * s);
        o[1] = f2bf(acc[c][1] * s);
        o[2] = f2bf(acc[c][2] * s);
        o[3] = f2bf(acc[c][3] * s);
        *(short4*)&aggb[((size_t)wid * CR + c) * F_IN + lane * 4] = *(const short4*)o;
    }
}

// ---------- layer-2 gather + root + bias + log_softmax ----------
__global__ __launch_bounds__(256) void gather2_kernel(
    const __hip_bfloat16* __restrict__ z, const unsigned* __restrict__ ebuf,
    const int* __restrict__ offsets, const float* __restrict__ invc,
    const float* __restrict__ b2, float* __restrict__ h)
{
    int wid  = (blockIdx.x * blockDim.x + threadIdx.x) >> 6;
    int lane = threadIdx.x & 63;
    if (wid >= N_NODES) return;
    int e0 = offsets[wid], e1 = offsets[wid + 1];
    float a0 = 0.0f, a1 = 0.0f;
    for (int e = e0; e < e1; ++e) {
        unsigned u = ebuf[e];
        int rt = (int)(u & 7u);
        unsigned src = u >> 3;
        float s = invc[(size_t)wid * N_REL + rt];
        unsigned pv = *(const unsigned*)&z[(size_t)src * NC2 + rt * F_OUT + lane * 2];
        a0 += s * bf2f((unsigned short)(pv & 0xffffu));
        a1 += s * bf2f((unsigned short)(pv >> 16));
    }
    unsigned rv = *(const unsigned*)&z[(size_t)wid * NC2 + N_REL * F_OUT + lane * 2];
    a0 += bf2f((unsigned short)(rv & 0xffffu)) + b2[lane * 2];
    a1 += bf2f((unsigned short)(rv >> 16))     + b2[lane * 2 + 1];

    float m = fmaxf(a0, a1);
    #pragma unroll
    for (int o = 32; o > 0; o >>= 1) m = fmaxf(m, __shfl_xor(m, o));
    float sum = expf(a0 - m) + expf(a1 - m);
    #pragma unroll
    for (int o = 32; o > 0; o >>= 1) sum += __shfl_xor(sum, o);
    float lse = m + logf(sum);
    h[(size_t)wid * F_OUT + lane * 2]     = a0 - lse;
    h[(size_t)wid * F_OUT + lane * 2 + 1] = a1 - lse;
}

#define BARX do { __builtin_amdgcn_s_barrier(); __builtin_amdgcn_sched_barrier(0); } while (0)
#define VMW(N) asm volatile("s_waitcnt vmcnt(" #N ")" ::: "memory")

// ================= 256x256 8-wave 8-phase counted-vmcnt GEMM (m201 port) =================
// 512 thd = 8 waves (2M x 4N), wave out 128x64 (acc[8][4]). BK=64. LDS 128KB:
// As/Bs[2 buf][2 half x 128 x 64]. Half-tile stage = 2 gload_lds/thread.
// Ledger (2 K-tiles/iter, kt0 in b0, kt1 in b1; steady state 4 in flight):
//   enter: [B(kt1) 4] outstanding.
//   ph1 +A0(kt1)->b1 ph2 +A1(kt1)->b1 ph3 +B0(kt0+2)->b0 ph4 +B1(kt0+2)->b0
//   VMW(4): retire B(kt1)4+A(kt1)4 -> b1 ready; B(kt0+2) in flight.
//   ph5 +A0(kt0+2)->b0 ph6 +A1(kt0+2)->b0 ph7 +B0(kt1+2)->b1 ph8 +B1(kt1+2)->b1
//   VMW(4): retire B(kt0+2)4+A(kt0+2)4 -> b0 ready; invariant restored.
// Reads are consumed by same-phase MFMA (lgkm waits) before the trailing
// barrier, so every region write is >=1 full barrier after its last read.
#define QBM 256
#define QBN 256
#define QBK 64

#define MQ256(QR, QC) do {                                                         \
    __builtin_amdgcn_s_setprio(1);                                                 \
    _Pragma("unroll") for (int i2 = 0; i2 < 4; ++i2)                               \
    _Pragma("unroll") for (int j2 = 0; j2 < 2; ++j2)                               \
    _Pragma("unroll") for (int h = 0; h < 2; ++h)                                  \
        acc[(QR)*4 + i2][(QC)*2 + j2] = __builtin_amdgcn_mfma_f32_16x16x32_bf16(   \
            a[i2][h], b[(QC)*2 + j2][h], acc[(QR)*4 + i2][(QC)*2 + j2], 0, 0, 0);  \
    __builtin_amdgcn_s_setprio(0); } while (0)

__global__ __launch_bounds__(512, 1) void gemm256_kernel(
    const __hip_bfloat16* __restrict__ A1, int K1, int lda1,
    const __hip_bfloat16* __restrict__ A2, int K2, int lda2,
    const __hip_bfloat16* __restrict__ BTa, const __hip_bfloat16* __restrict__ BTb, int ldbt,
    const float* __restrict__ bias,
    float* __restrict__ Cf, __hip_bfloat16* __restrict__ Cb,
    int M, int Nc, int accumulate, int do_relu,
    int gridX, int nwg)
{
    __shared__ __align__(16) __hip_bfloat16 As[2][2 * 8192];   // 64 KB
    __shared__ __align__(16) __hip_bfloat16 Bs[2][2 * 8192];   // 64 KB

    // bijective XCD swizzle (m204)
    int bid = blockIdx.x;
    int qq = nwg >> 3, rr = nwg & 7;
    int xcd = bid & 7, ii = bid >> 3;
    int wg = (xcd < rr ? xcd * (qq + 1) : rr * (qq + 1) + (xcd - rr) * qq) + ii;
    const int bm = (wg / gridX) * QBM;
    const int bn = (wg % gridX) * QBN;

    const int tid  = threadIdx.x;
    const int lane = tid & 63;
    const int wv   = tid >> 6;      // 0..7
    const int wr   = wv >> 2;       // 0..1 (M half)
    const int wc   = wv & 3;        // 0..3 (64-col strip)
    const int r15  = lane & 15;
    const int ksel = lane >> 4;
    const int rsw  = (r15 & 7) << 3;

    const int srow = tid >> 3;                          // 0..63
    const int swz8 = ((tid & 7) ^ (srow & 7)) * 8;      // T2 pre-swizzled source col

    const int Ktot = K1 + K2;
    const int nT   = Ktot / QBK;    // even (36 / 20 / 16)
    const int nIt  = nT / 2;

    // stage one half-tile (128 rows x 64 k) = 2 gload_lds/thread
    auto stageA = [&](int kt, int bi, int hh) {
        int k0 = kt * QBK;
        const __hip_bfloat16* base = A1; int ld = lda1;
        if (k0 >= K1) { base = A2; ld = lda2; k0 -= K1; }
        #pragma unroll
        for (int c = 0; c < 2; ++c) {
            int gr = bm + hh * 128 + c * 64 + srow; if (gr >= M) gr = M - 1;
            const __hip_bfloat16* gp = base + (size_t)gr * ld + k0 + swz8;
            __builtin_amdgcn_global_load_lds(
                (const __attribute__((address_space(1))) void*)gp,
                (__attribute__((address_space(3))) void*)&As[bi][hh * 8192 + c * 4096 + tid * 8],
                16, 0, 0);
        }
    };
    auto stageB = [&](int kt, int bi, int hh) {
        int k0 = kt * QBK;
        const __hip_bfloat16* base = BTa;
        if (k0 >= K1) { base = BTb; k0 -= K1; }
        #pragma unroll
        for (int c = 0; c < 2; ++c) {
            int n0 = bn + hh * 128 + c * 64 + srow;
            const __hip_bfloat16* gp = base + (size_t)n0 * ldbt + k0 + swz8;
            __builtin_amdgcn_global_load_lds(
                (const __attribute__((address_space(1))) void*)gp,
                (__attribute__((address_space(3))) void*)&Bs[bi][hh * 8192 + c * 4096 + tid * 8],
                16, 0, 0);
        }
    };

    short8 a[4][2], b[4][2];
    // load a-frags fr = qr*4 .. qr*4+3 (wave M rows wr*128 + fr*16 + r15)
    auto loadA4 = [&](int bi, int qr) {
        #pragma unroll
        for (int i2 = 0; i2 < 4; ++i2)
            #pragma unroll
            for (int h = 0; h < 2; ++h)
                a[i2][h] = *(const short8*)&As[bi][wr * 8192 +
                    ((qr * 4 + i2) * 16 + r15) * 64 + ((h * 32 + ksel * 8) ^ rsw)];
    };
    // load b-frags fc = qc*2 .. qc*2+1 (wave N rows wc*64 + fc*16 + r15)
    auto loadB2q = [&](int bi, int qc) {
        #pragma unroll
        for (int j2 = 0; j2 < 2; ++j2)
            #pragma unroll
            for (int h = 0; h < 2; ++h)
                b[qc * 2 + j2][h] = *(const short8*)&Bs[bi][(wc >> 1) * 8192 +
                    ((wc & 1) * 64 + (qc * 2 + j2) * 16 + r15) * 64 +
                    ((h * 32 + ksel * 8) ^ rsw)];
    };

    f32x4 acc[8][4] = {};

    // prologue: kt0 all 4 halves (8 loads) + kt1 B halves (4 loads)
    stageA(0, 0, 0); stageA(0, 0, 1); stageB(0, 0, 0); stageB(0, 0, 1);
    stageB(1, 1, 0); stageB(1, 1, 1);
    VMW(4);   // retire kt0's 8 -> b0 ready; B(kt1) in flight
    BARX;

    for (int it = 0; it < nIt; ++it) {
        const int kt1 = 2 * it + 1;
        const bool last = (it == nIt - 1);
        // ---- half 0: consume b0 (kt0) ----
        loadA4(0, 0); loadB2q(0, 0); stageA(kt1, 1, 0);
        BARX; MQ256(0, 0); BARX;
        loadB2q(0, 1); stageA(kt1, 1, 1);
        BARX; MQ256(0, 1); BARX;
        loadA4(0, 1); if (!last) stageB(kt1 + 1, 0, 0);
        BARX; MQ256(1, 0); BARX;
        if (!last) stageB(kt1 + 1, 0, 1);
        BARX; MQ256(1, 1);
        if (last) { VMW(0); } else { VMW(4); }
        BARX;
        // ---- half 1: consume b1 (kt1) ----
        loadA4(1, 0); loadB2q(1, 0); if (!last) stageA(kt1 + 1, 0, 0);
        BARX; MQ256(0, 0); BARX;
        loadB2q(1, 1); if (!last) stageA(kt1 + 1, 0, 1);
        BARX; MQ256(0, 1); BARX;
        loadA4(1, 1); if (!last) stageB(kt1 + 2, 1, 0);
        BARX; MQ256(1, 0); BARX;
        if (!last) stageB(kt1 + 2, 1, 1);
        BARX; MQ256(1, 1);
        if (!last) { VMW(4); }
        BARX;
    }

    // epilogue
    float bv[4];
    #pragma unroll
    for (int fc = 0; fc < 4; ++fc)
        bv[fc] = bias ? bias[bn + wc * 64 + fc * 16 + r15] : 0.0f;

    #pragma unroll
    for (int fr = 0; fr < 8; ++fr) {
        #pragma unroll
        for (int q2 = 0; q2 < 4; ++q2) {
            int row = bm + wr * 128 + fr * 16 + ksel * 4 + q2;
            if (row >= M) continue;
            #pragma unroll
            for (int fc = 0; fc < 4; ++fc) {
                int col = bn + wc * 64 + fc * 16 + r15;
                float v = acc[fr][fc][q2] + bv[fc];
                size_t off = (size_t)row * Nc + col;
                if (accumulate) v += Cf[off];
                if (do_relu) v = fmaxf(v, 0.0f);
                if (Cf) Cf[off] = v;
                if (Cb) Cb[off] = __float2bfloat16(v);
            }
        }
    }
}

// ======== 8-phase 128x128 4-wave GEMM (layer 2, Nc=1152) — unchanged R8 kernel ========
#define TBM 128
#define TBN 128
#define TBK 64

#define MFMA_Q(QR, QC) do {                                                        \
    __builtin_amdgcn_s_setprio(1);                                                 \
    _Pragma("unroll") for (int i2 = 0; i2 < 2; ++i2)                               \
    _Pragma("unroll") for (int j2 = 0; j2 < 2; ++j2)                               \
    _Pragma("unroll") for (int h = 0; h < 2; ++h)                                  \
        acc[(QR)*2 + i2][(QC)*2 + j2] = __builtin_amdgcn_mfma_f32_16x16x32_bf16(   \
            a[i2][h], b[(QC)*2 + j2][h], acc[(QR)*2 + i2][(QC)*2 + j2], 0, 0, 0);  \
    __builtin_amdgcn_s_setprio(0); } while (0)

__global__ __launch_bounds__(256, 2) void gemm8p_kernel(
    const __hip_bfloat16* __restrict__ A1, int K1, int lda1,
    const __hip_bfloat16* __restrict__ A2, int K2, int lda2,
    const __hip_bfloat16* __restrict__ BTa, const __hip_bfloat16* __restrict__ BTb, int ldbt,
    const float* __restrict__ bias,
    float* __restrict__ Cf, __hip_bfloat16* __restrict__ Cb,
    int M, int Nc, int accumulate, int do_relu,
    int gridX, int nwg)
{
    __shared__ __align__(16) __hip_bfloat16 As[2][TBM * TBK];
    __shared__ __align__(16) __hip_bfloat16 Bs[2][TBN * TBK];

    int bid = blockIdx.x;
    int qq = nwg >> 3, rr = nwg & 7;
    int xcd = bid & 7, ii = bid >> 3;
    int wg = (xcd < rr ? xcd * (qq + 1) : rr * (qq + 1) + (xcd - rr) * qq) + ii;
    const int bm = (wg / gridX) * TBM;
    const int bn = (wg % gridX) * TBN;

    const int tid  = threadIdx.x;
    const int lane = tid & 63;
    const int wv   = tid >> 6;
    const int wr   = wv >> 1;
    const int wc   = wv & 1;
    const int r15  = lane & 15;
    const int ksel = lane >> 4;
    const int rsw  = (r15 & 7) << 3;

    const int srow = tid >> 3;
    const int swz8 = ((tid & 7) ^ (srow & 7)) * 8;

    const int Ktot = K1 + K2;
    const int nT   = Ktot / TBK;
    const int nIt  = nT / 2;

    auto stageA = [&](int kt, int bi, int c0) {
        int k0 = kt * TBK;
        const __hip_bfloat16* base = A1; int ld = lda1;
        if (k0 >= K1) { base = A2; ld = lda2; k0 -= K1; }
        #pragma unroll
        for (int c = c0; c < c0 + 2; ++c) {
            int gr = bm + c * 32 + srow; if (gr >= M) gr = M - 1;
            const __hip_bfloat16* gp = base + (size_t)gr * ld + k0 + swz8;
            __builtin_amdgcn_global_load_lds(
                (const __attribute__((address_space(1))) void*)gp,
                (__attribute__((address_space(3))) void*)&As[bi][c * 2048 + tid * 8], 16, 0, 0);
        }
    };
    auto stageB = [&](int kt, int bi, int c0) {
        int k0 = kt * TBK;
        const __hip_bfloat16* base = BTa;
        if (k0 >= K1) { base = BTb; k0 -= K1; }
        #pragma unroll
        for (int c = c0; c < c0 + 2; ++c) {
            int n0 = bn + c * 32 + srow;
            const __hip_bfloat16* gp = base + (size_t)n0 * ldbt + k0 + swz8;
            __builtin_amdgcn_global_load_lds(
                (const __attribute__((address_space(1))) void*)gp,
                (__attribute__((address_space(3))) void*)&Bs[bi][c * 2048 + tid * 8], 16, 0, 0);
        }
    };

    short8 a[2][2], b[4][2];
    auto loadA2 = [&](int bi, int fr0) {
        #pragma unroll
        for (int i2 = 0; i2 < 2; ++i2)
            #pragma unroll
            for (int h = 0; h < 2; ++h)
                a[i2][h] = *(const short8*)&As[bi][(wr * 64 + (fr0 + i2) * 16 + r15) * 64 +
                                                   ((h * 32 + ksel * 8) ^ rsw)];
    };
    auto loadB2 = [&](int bi, int fc0) {
        #pragma unroll
        for (int j2 = 0; j2 < 2; ++j2)
            #pragma unroll
            for (int h = 0; h < 2; ++h)
                b[fc0 + j2][h] = *(const short8*)&Bs[bi][(wc * 64 + (fc0 + j2) * 16 + r15) * 64 +
                                                         ((h * 32 + ksel * 8) ^ rsw)];
    };

    f32x4 acc[4][4] = {};

    stageA(0, 0, 0); stageA(0, 0, 2); stageB(0, 0, 0); stageB(0, 0, 2);
    stageB(1, 1, 0); stageB(1, 1, 2);
    VMW(4);
    BARX;

    for (int it = 0; it < nIt; ++it) {
        const int kt0 = 2 * it, kt1 = 2 * it + 1;
        const bool last = (it == nIt - 1);
        loadA2(0, 0); loadB2(0, 0); stageA(kt1, 1, 0);
        BARX; MFMA_Q(0, 0); BARX;
        loadB2(0, 2); stageA(kt1, 1, 2);
        BARX; MFMA_Q(0, 1); BARX;
        loadA2(0, 2); if (!last) stageB(kt0 + 2, 0, 0);
        BARX; MFMA_Q(1, 0); BARX;
        if (!last) stageB(kt0 + 2, 0, 2);
        BARX; MFMA_Q(1, 1);
        if (last) { VMW(0); } else { VMW(4); }
        BARX;
        loadA2(1, 0); loadB2(1, 0); if (!last) stageA(kt0 + 2, 0, 0);
        BARX; MFMA_Q(0, 0); BARX;
        loadB2(1, 2); if (!last) stageA(kt0 + 2, 0, 2);
        BARX; MFMA_Q(0, 1); BARX;
        loadA2(1, 2); if (!last) stageB(kt1 + 2, 1, 0);
        BARX; MFMA_Q(1, 0); BARX;
        if (!last) stageB(kt1 + 2, 1, 2);
        BARX; MFMA_Q(1, 1);
        if (!last) { VMW(4); }
        BARX;
    }

    float bv[4];
    #pragma unroll
    for (int fc = 0; fc < 4; ++fc)
        bv[fc] = bias ? bias[bn + wc * 64 + fc * 16 + r15] : 0.0f;

    #pragma unroll
    for (int fr = 0; fr < 4; ++fr) {
        #pragma unroll
        for (int q2 = 0; q2 < 4; ++q2) {
            int row = bm + wr * 64 + fr * 16 + ksel * 4 + q2;
            if (row >= M) continue;
            #pragma unroll
            for (int fc = 0; fc < 4; ++fc) {
                int col = bn + wc * 64 + fc * 16 + r15;
                float v = acc[fr][fc][q2] + bv[fc];
                size_t off = (size_t)row * Nc + col;
                if (accumulate) v += Cf[off];
                if (do_relu) v = fmaxf(v, 0.0f);
                if (Cf) Cf[off] = v;
                if (Cb) Cb[off] = __float2bfloat16(v);
            }
        }
    }
}

extern "C" void kernel_launch(void* const* d_in, const int* in_sizes, int n_in,
                              void* d_out, int out_size, void* d_ws, size_t ws_size,
                              hipStream_t stream) {
    const float* x     = (const float*)d_in[0];
    const void*  eidx  = d_in[1];
    const void*  etype = d_in[2];
    const float* w1    = (const float*)d_in[3];
    const float* root1 = (const float*)d_in[4];
    const float* b1    = (const float*)d_in[5];
    const float* w2    = (const float*)d_in[6];
    const float* root2 = (const float*)d_in[7];
    const float* b2    = (const float*)d_in[8];

    float* h_out = (float*)d_out;
    float* emb   = (float*)d_out + (size_t)N_NODES * F_OUT;

    char* ws = (char*)d_ws;
    size_t off = 0;
    auto take = [&](size_t bytes) { char* p = ws + off; off = (off + bytes + 255) & ~(size_t)255; return p; };
    int*      flag    = (int*)take(256);
    unsigned* cnt8    = (unsigned*)take((size_t)N_NODES * N_REL * 4);
    float*    invc    = (float*)take((size_t)N_NODES * N_REL * 4);
    int*      offsets = (int*)take(((size_t)N_NODES + 1) * 4);
    int*      cursor  = (int*)take((size_t)N_NODES * 4);
    unsigned* ebuf    = (unsigned*)take((size_t)N_EDGES * 4);
    __hip_bfloat16* xb   = (__hip_bfloat16*)take((size_t)N_NODES * F_IN * 2);
    __hip_bfloat16* embb = (__hip_bfloat16*)take((size_t)N_NODES * F_HID * 2);
    __hip_bfloat16* bt1  = (__hip_bfloat16*)take((size_t)F_HID * (N_REL * F_IN + F_IN) * 2);
    __hip_bfloat16* bt2  = (__hip_bfloat16*)take((size_t)NC2 * F_HID * 2);

    size_t avail = (ws_size > off) ? (ws_size - off) : 0;
    size_t agg8bytes = (size_t)N_NODES * N_REL * F_IN * 2;
    size_t zbytes    = (size_t)N_NODES * NC2 * 2;
    int CR = (avail >= agg8bytes) ? 8 : 4;
    size_t ubytes = agg8bytes > zbytes ? agg8bytes : zbytes;
    if (CR == 4) ubytes = zbytes;
    char* uni = take(ubytes);
    __hip_bfloat16* aggb = (__hip_bfloat16*)uni;
    __hip_bfloat16* z    = (__hip_bfloat16*)uni;

    detect64_kernel<<<1, 64, 0, stream>>>((const int*)etype, flag);
    (void)hipMemsetAsync(cnt8, 0, (size_t)N_NODES * N_REL * 4, stream);
    (void)hipMemsetAsync(cursor, 0, (size_t)N_NODES * 4, stream);
    count_kernel<<<(N_EDGES + 255) / 256, 256, 0, stream>>>(etype, eidx, flag, cnt8);
    inv_kernel<<<(N_NODES * N_REL + 255) / 256, 256, 0, stream>>>(cnt8, invc);
    scan_kernel<<<1, 1024, 0, stream>>>(cnt8, offsets);
    build_kernel<<<(N_EDGES + 255) / 256, 256, 0, stream>>>(eidx, etype, flag, offsets, cursor, ebuf);

    cvt_bf16_kernel<<<(N_NODES * F_IN / 4 + 255) / 256, 256, 0, stream>>>(
        x, xb, (long long)N_NODES * F_IN / 4);
    {
        int tot = F_HID * (N_REL * F_IN + F_IN);
        make_bt1_kernel<<<(tot + 255) / 256, 256, 0, stream>>>(w1, root1, bt1);
        tot = NC2 * F_HID;
        make_bt2_kernel<<<(tot + 255) / 256, 256, 0, stream>>>(w2, root2, bt2);
    }

    const int MBLK  = (N_NODES + TBM - 1) / TBM;      // 391 (128 tile)
    const int MBLKQ = (N_NODES + QBM - 1) / QBM;      // 196 (256 tile)
    const int GWAVE_BLOCKS = (N_NODES * 64 + 255) / 256;

    // ---------------- layer 1 (256x256 8-wave 8-phase GEMM) ----------------
    for (int r0 = 0; r0 < N_REL; r0 += CR) {
        if (CR == 8)
            gather1_kernel<8><<<GWAVE_BLOCKS, 256, 0, stream>>>(xb, ebuf, offsets, invc, aggb, r0);
        else
            gather1_kernel<4><<<GWAVE_BLOCKS, 256, 0, stream>>>(xb, ebuf, offsets, invc, aggb, r0);
        int first = (r0 == 0), last = (r0 + CR >= N_REL);
        int gX = F_HID / QBN, nwg = gX * MBLKQ;       // 2 x 196 = 392
        gemm256_kernel<<<nwg, 512, 0, stream>>>(
            aggb, CR * F_IN, CR * F_IN,
            first ? xb : nullptr, first ? F_IN : 0, F_IN,
            bt1 + (size_t)r0 * F_IN, bt1 + (size_t)N_REL * F_IN, N_REL * F_IN + F_IN,
            first ? b1 : nullptr,
            emb, last ? embb : nullptr,
            N_NODES, F_HID, first ? 0 : 1, last ? 1 : 0,
            gX, nwg);
    }

    // ---------------- layer 2 (128x128 8-phase GEMM, Nc=1152) ----------------
    {
        int gX = NC2 / TBN, nwg = gX * MBLK;          // 9 x 391
        gemm8p_kernel<<<nwg, 256, 0, stream>>>(
            embb, F_HID, F_HID, nullptr, 0, 0,
            bt2, nullptr, F_HID,
            nullptr, nullptr, z, N_NODES, NC2, 0, 0,
            gX, nwg);
    }

    gather2_kernel<<<GWAVE_BLOCKS, 256, 0, stream>>>(z, ebuf, offsets, invc, b2, h_out);
}

// Round 10
// 567.636 us; speedup vs baseline: 8.8788x; 1.2564x over previous
//
#include <hip/hip_runtime.h>
#include <hip/hip_bf16.h>
#include <cstddef>
#include <cstdint>

#define N_NODES 50000
#define N_EDGES 800000
#define N_REL 8
#define F_IN 256
#define F_HID 512
#define F_OUT 128
#define NC2 (N_REL * F_OUT + F_OUT)   // 1152
#define NSEG (N_NODES * N_REL)        // 400000
#define SCAN_NB ((NSEG + 1023) / 1024) // 391

typedef __attribute__((ext_vector_type(8))) short short8;
typedef __attribute__((ext_vector_type(4))) float f32x4;

__device__ __forceinline__ float bf2f(unsigned short u) {
    return __uint_as_float(((unsigned)u) << 16);
}
__device__ __forceinline__ unsigned short f2bf(float f) {
    __hip_bfloat16 h = __float2bfloat16(f);
    return *reinterpret_cast<unsigned short*>(&h);
}

// ---------- int64-vs-int32 edge dtype detection ----------
__global__ void detect64_kernel(const int* __restrict__ et, int* __restrict__ flag) {
    int v = et[2 * threadIdx.x + 1];
    unsigned long long any = __ballot(v != 0);
    if (threadIdx.x == 0) flag[0] = (any == 0ULL) ? 1 : 0;
}

__device__ __forceinline__ long long ld_idx(const void* __restrict__ p, size_t i, int is64) {
    return is64 ? ((const long long*)p)[i] : (long long)((const int*)p)[i];
}

__global__ void count_kernel(const void* __restrict__ etype, const void* __restrict__ eidx,
                             const int* __restrict__ flag, unsigned* __restrict__ cnt8) {
    int e = blockIdx.x * blockDim.x + threadIdx.x;
    if (e >= N_EDGES) return;
    int is64 = flag[0];
    long long rt  = ld_idx(etype, e, is64);
    long long dst = ld_idx(eidx, (size_t)N_EDGES + e, is64);
    atomicAdd(&cnt8[dst * N_REL + rt], 1u);
}

// ---------- parallel seg-level exclusive scan (3 kernels) + invc ----------
__global__ __launch_bounds__(1024) void scan1_kernel(const unsigned* __restrict__ cnt8,
                                                     float* __restrict__ invc,
                                                     int* __restrict__ soff,
                                                     int* __restrict__ bsum) {
    __shared__ int lds[1024];
    int t = threadIdx.x;
    int i = blockIdx.x * 1024 + t;
    int c = (i < NSEG) ? (int)cnt8[i] : 0;
    if (i < NSEG) invc[i] = 1.0f / (float)(c ? c : 1);
    lds[t] = c;
    __syncthreads();
    for (int o = 1; o < 1024; o <<= 1) {
        int v = (t >= o) ? lds[t - o] : 0;
        __syncthreads();
        lds[t] += v;
        __syncthreads();
    }
    if (i < NSEG) soff[i] = lds[t] - c;     // exclusive within block
    if (t == 1023) bsum[blockIdx.x] = lds[1023];
}

__global__ __launch_bounds__(512) void scan2_kernel(int* __restrict__ bsum) {
    __shared__ int lds[512];
    int t = threadIdx.x;
    int v = (t < SCAN_NB) ? bsum[t] : 0;
    lds[t] = v;
    __syncthreads();
    for (int o = 1; o < 512; o <<= 1) {
        int x = (t >= o) ? lds[t - o] : 0;
        __syncthreads();
        lds[t] += x;
        __syncthreads();
    }
    if (t < SCAN_NB) bsum[t] = lds[t] - v;  // exclusive block prefix
}

__global__ void scan3_kernel(int* __restrict__ soff, const int* __restrict__ bsum) {
    int g = blockIdx.x * blockDim.x + threadIdx.x;
    if (g < NSEG) soff[g] += bsum[g >> 10];
    if (g == 0) soff[NSEG] = N_EDGES;
}

// ---------- bucket edges into seg-sorted CSR: ebuf[pos] = (src<<3)|rel ----------
__global__ void build_kernel(const void* __restrict__ eidx, const void* __restrict__ etype,
                             const int* __restrict__ flag, const int* __restrict__ soff,
                             int* __restrict__ cursor, unsigned* __restrict__ ebuf) {
    int e = blockIdx.x * blockDim.x + threadIdx.x;
    if (e >= N_EDGES) return;
    int is64 = flag[0];
    int rt  = (int)ld_idx(etype, e, is64);
    int src = (int)ld_idx(eidx, e, is64);
    int dst = (int)ld_idx(eidx, (size_t)N_EDGES + e, is64);
    int seg = dst * N_REL + rt;
    int pos = soff[seg] + atomicAdd(&cursor[seg], 1);
    ebuf[pos] = ((unsigned)src << 3) | (unsigned)rt;
}

__global__ void cvt_bf16_kernel(const float* __restrict__ in, __hip_bfloat16* __restrict__ out,
                                long long n4) {
    long long g = (long long)blockIdx.x * blockDim.x + threadIdx.x;
    if (g >= n4) return;
    float4 v = ((const float4*)in)[g];
    unsigned short o[4];
    o[0] = f2bf(v.x); o[1] = f2bf(v.y); o[2] = f2bf(v.z); o[3] = f2bf(v.w);
    *(short4*)&out[4 * g] = *(const short4*)o;
}

__global__ void make_bt1_kernel(const float* __restrict__ w1, const float* __restrict__ root1,
                                __hip_bfloat16* __restrict__ bt) {
    int g = blockIdx.x * blockDim.x + threadIdx.x;
    const int Kt = N_REL * F_IN + F_IN;
    if (g >= F_HID * Kt) return;
    int n = g / Kt, k = g % Kt;
    float v;
    if (k < N_REL * F_IN) v = w1[(size_t)(k >> 8) * F_IN * F_HID + (size_t)(k & 255) * F_HID + n];
    else                  v = root1[(size_t)(k - N_REL * F_IN) * F_HID + n];
    bt[g] = __float2bfloat16(v);
}

__global__ void make_bt2_kernel(const float* __restrict__ w2, const float* __restrict__ root2,
                                __hip_bfloat16* __restrict__ bt) {
    int g = blockIdx.x * blockDim.x + threadIdx.x;
    if (g >= NC2 * F_HID) return;
    int n = g / F_HID, k = g % F_HID;
    float v = (n < N_REL * F_OUT)
                  ? w2[(size_t)(n >> 7) * F_HID * F_OUT + (size_t)k * F_OUT + (n & 127)]
                  : root2[(size_t)k * F_OUT + (n - N_REL * F_OUT)];
    bt[g] = __float2bfloat16(v);
}

// ---------- layer-1 gather (seg-sorted edges, unroll-2) ----------
template <int CR>
__global__ __launch_bounds__(256) void gather1_kernel(
    const __hip_bfloat16* __restrict__ xb, const unsigned* __restrict__ ebuf,
    const int* __restrict__ soff, const float* __restrict__ invc,
    __hip_bfloat16* __restrict__ aggb, int r0)
{
    int wid  = (blockIdx.x * blockDim.x + threadIdx.x) >> 6;
    int lane = threadIdx.x & 63;
    if (wid >= N_NODES) return;
    int e0 = soff[wid * N_REL + r0];
    int e1 = soff[wid * N_REL + r0 + CR];
    float acc[CR][4];
    #pragma unroll
    for (int c = 0; c < CR; ++c)
        #pragma unroll
        for (int j = 0; j < 4; ++j) acc[c][j] = 0.0f;

    int e = e0;
    for (; e + 2 <= e1; e += 2) {
        unsigned u0 = ebuf[e], u1 = ebuf[e + 1];
        short4 v0 = *(const short4*)&xb[(size_t)(u0 >> 3) * F_IN + lane * 4];
        short4 v1 = *(const short4*)&xb[(size_t)(u1 >> 3) * F_IN + lane * 4];
        int rl0 = __builtin_amdgcn_readfirstlane((int)(u0 & 7u) - r0);
        int rl1 = __builtin_amdgcn_readfirstlane((int)(u1 & 7u) - r0);
        #pragma unroll
        for (int c = 0; c < CR; ++c)
            if (rl0 == c) {
                acc[c][0] += bf2f((unsigned short)v0.x); acc[c][1] += bf2f((unsigned short)v0.y);
                acc[c][2] += bf2f((unsigned short)v0.z); acc[c][3] += bf2f((unsigned short)v0.w);
            }
        #pragma unroll
        for (int c = 0; c < CR; ++c)
            if (rl1 == c) {
                acc[c][0] += bf2f((unsigned short)v1.x); acc[c][1] += bf2f((unsigned short)v1.y);
                acc[c][2] += bf2f((unsigned short)v1.z); acc[c][3] += bf2f((unsigned short)v1.w);
            }
    }
    if (e < e1) {
        unsigned u0 = ebuf[e];
        short4 v0 = *(const short4*)&xb[(size_t)(u0 >> 3) * F_IN + lane * 4];
        int rl0 = __builtin_amdgcn_readfirstlane((int)(u0 & 7u) - r0);
        #pragma unroll
        for (int c = 0; c < CR; ++c)
            if (rl0 == c) {
                acc[c][0] += bf2f((unsigned short)v0.x); acc[c][1] += bf2f((unsigned short)v0.y);
                acc[c][2] += bf2f((unsigned short)v0.z); acc[c][3] += bf2f((unsigned short)v0.w);
            }
    }

    #pragma unroll
    for (int c = 0; c < CR; ++c) {
        float s = invc[(size_t)wid * N_REL + r0 + c];
        unsigned short o[4];
        o[0] = f2bf(acc[c][0] * s);
        o[1] = f2bf(acc[c][1] * s);
        o[2] = f2bf(acc[c][2] * s);
        o[3] = f2bf(acc[c][3] * s);
        *(short4*)&aggb[((size_t)wid * CR + c) * F_IN + lane * 4] = *(const short4*)o;
    }
}

// ---------- layer-2 gather + root + bias + log_softmax (deferred scale, unroll-2) ----------
__global__ __launch_bounds__(256) void gather2_kernel(
    const __hip_bfloat16* __restrict__ z, const unsigned* __restrict__ ebuf,
    const int* __restrict__ soff, const float* __restrict__ invc,
    const float* __restrict__ b2, float* __restrict__ h)
{
    int wid  = (blockIdx.x * blockDim.x + threadIdx.x) >> 6;
    int lane = threadIdx.x & 63;
    if (wid >= N_NODES) return;
    int e0 = soff[wid * N_REL];
    int e1 = soff[wid * N_REL + N_REL];
    float t0[N_REL], t1[N_REL];
    #pragma unroll
    for (int c = 0; c < N_REL; ++c) { t0[c] = 0.0f; t1[c] = 0.0f; }

    int e = e0;
    for (; e + 2 <= e1; e += 2) {
        unsigned u0 = ebuf[e], u1 = ebuf[e + 1];
        unsigned pv0 = *(const unsigned*)&z[(size_t)(u0 >> 3) * NC2 + (u0 & 7u) * F_OUT + lane * 2];
        unsigned pv1 = *(const unsigned*)&z[(size_t)(u1 >> 3) * NC2 + (u1 & 7u) * F_OUT + lane * 2];
        int r0s = __builtin_amdgcn_readfirstlane((int)(u0 & 7u));
        int r1s = __builtin_amdgcn_readfirstlane((int)(u1 & 7u));
        float p00 = bf2f((unsigned short)(pv0 & 0xffffu)), p01 = bf2f((unsigned short)(pv0 >> 16));
        float p10 = bf2f((unsigned short)(pv1 & 0xffffu)), p11 = bf2f((unsigned short)(pv1 >> 16));
        #pragma unroll
        for (int c = 0; c < N_REL; ++c)
            if (r0s == c) { t0[c] += p00; t1[c] += p01; }
        #pragma unroll
        for (int c = 0; c < N_REL; ++c)
            if (r1s == c) { t0[c] += p10; t1[c] += p11; }
    }
    if (e < e1) {
        unsigned u0 = ebuf[e];
        unsigned pv0 = *(const unsigned*)&z[(size_t)(u0 >> 3) * NC2 + (u0 & 7u) * F_OUT + lane * 2];
        int r0s = __builtin_amdgcn_readfirstlane((int)(u0 & 7u));
        float p00 = bf2f((unsigned short)(pv0 & 0xffffu)), p01 = bf2f((unsigned short)(pv0 >> 16));
        #pragma unroll
        for (int c = 0; c < N_REL; ++c)
            if (r0s == c) { t0[c] += p00; t1[c] += p01; }
    }

    unsigned rv = *(const unsigned*)&z[(size_t)wid * NC2 + N_REL * F_OUT + lane * 2];
    float a0 = bf2f((unsigned short)(rv & 0xffffu)) + b2[lane * 2];
    float a1 = bf2f((unsigned short)(rv >> 16))     + b2[lane * 2 + 1];
    #pragma unroll
    for (int c = 0; c < N_REL; ++c) {
        float s = invc[(size_t)wid * N_REL + c];
        a0 = fmaf(s, t0[c], a0);
        a1 = fmaf(s, t1[c], a1);
    }

    float m = fmaxf(a0, a1);
    #pragma unroll
    for (int o = 32; o > 0; o >>= 1) m = fmaxf(m, __shfl_xor(m, o));
    float sum = expf(a0 - m) + expf(a1 - m);
    #pragma unroll
    for (int o = 32; o > 0; o >>= 1) sum += __shfl_xor(sum, o);
    float lse = m + logf(sum);
    h[(size_t)wid * F_OUT + lane * 2]     = a0 - lse;
    h[(size_t)wid * F_OUT + lane * 2 + 1] = a1 - lse;
}

#define BARX do { __builtin_amdgcn_s_barrier(); __builtin_amdgcn_sched_barrier(0); } while (0)
#define VMW(N) asm volatile("s_waitcnt vmcnt(" #N ")" ::: "memory")

// ================= 256x256 8-wave 8-phase counted-vmcnt GEMM (verified R9) =================
#define QBM 256
#define QBN 256
#define QBK 64

#define MQ256(QR, QC) do {                                                         \
    __builtin_amdgcn_s_setprio(1);                                                 \
    _Pragma("unroll") for (int i2 = 0; i2 < 4; ++i2)                               \
    _Pragma("unroll") for (int j2 = 0; j2 < 2; ++j2)                               \
    _Pragma("unroll") for (int h = 0; h < 2; ++h)                                  \
        acc[(QR)*4 + i2][(QC)*2 + j2] = __builtin_amdgcn_mfma_f32_16x16x32_bf16(   \
            a[i2][h], b[(QC)*2 + j2][h], acc[(QR)*4 + i2][(QC)*2 + j2], 0, 0, 0);  \
    __builtin_amdgcn_s_setprio(0); } while (0)

__global__ __launch_bounds__(512, 1) void gemm256_kernel(
    const __hip_bfloat16* __restrict__ A1, int K1, int lda1,
    const __hip_bfloat16* __restrict__ A2, int K2, int lda2,
    const __hip_bfloat16* __restrict__ BTa, const __hip_bfloat16* __restrict__ BTb, int ldbt,
    const float* __restrict__ bias,
    float* __restrict__ Cf, __hip_bfloat16* __restrict__ Cb,
    int M, int Nc, int accumulate, int do_relu,
    int gridX, int nwg)
{
    __shared__ __align__(16) __hip_bfloat16 As[2][2 * 8192];
    __shared__ __align__(16) __hip_bfloat16 Bs[2][2 * 8192];

    int bid = blockIdx.x;
    int qq = nwg >> 3, rr = nwg & 7;
    int xcd = bid & 7, ii = bid >> 3;
    int wg = (xcd < rr ? xcd * (qq + 1) : rr * (qq + 1) + (xcd - rr) * qq) + ii;
    const int bm = (wg / gridX) * QBM;
    const int bn = (wg % gridX) * QBN;

    const int tid  = threadIdx.x;
    const int lane = tid & 63;
    const int wv   = tid >> 6;
    const int wr   = wv >> 2;
    const int wc   = wv & 3;
    const int r15  = lane & 15;
    const int ksel = lane >> 4;
    const int rsw  = (r15 & 7) << 3;

    const int srow = tid >> 3;
    const int swz8 = ((tid & 7) ^ (srow & 7)) * 8;

    const int Ktot = K1 + K2;
    const int nT   = Ktot / QBK;
    const int nIt  = nT / 2;

    auto stageA = [&](int kt, int bi, int hh) {
        int k0 = kt * QBK;
        const __hip_bfloat16* base = A1; int ld = lda1;
        if (k0 >= K1) { base = A2; ld = lda2; k0 -= K1; }
        #pragma unroll
        for (int c = 0; c < 2; ++c) {
            int gr = bm + hh * 128 + c * 64 + srow; if (gr >= M) gr = M - 1;
            const __hip_bfloat16* gp = base + (size_t)gr * ld + k0 + swz8;
            __builtin_amdgcn_global_load_lds(
                (const __attribute__((address_space(1))) void*)gp,
                (__attribute__((address_space(3))) void*)&As[bi][hh * 8192 + c * 4096 + tid * 8],
                16, 0, 0);
        }
    };
    auto stageB = [&](int kt, int bi, int hh) {
        int k0 = kt * QBK;
        const __hip_bfloat16* base = BTa;
        if (k0 >= K1) { base = BTb; k0 -= K1; }
        #pragma unroll
        for (int c = 0; c < 2; ++c) {
            int n0 = bn + hh * 128 + c * 64 + srow;
            const __hip_bfloat16* gp = base + (size_t)n0 * ldbt + k0 + swz8;
            __builtin_amdgcn_global_load_lds(
                (const __attribute__((address_space(1))) void*)gp,
                (__attribute__((address_space(3))) void*)&Bs[bi][hh * 8192 + c * 4096 + tid * 8],
                16, 0, 0);
        }
    };

    short8 a[4][2], b[4][2];
    auto loadA4 = [&](int bi, int qr) {
        #pragma unroll
        for (int i2 = 0; i2 < 4; ++i2)
            #pragma unroll
            for (int h = 0; h < 2; ++h)
                a[i2][h] = *(const short8*)&As[bi][wr * 8192 +
                    ((qr * 4 + i2) * 16 + r15) * 64 + ((h * 32 + ksel * 8) ^ rsw)];
    };
    auto loadB2q = [&](int bi, int qc) {
        #pragma unroll
        for (int j2 = 0; j2 < 2; ++j2)
            #pragma unroll
            for (int h = 0; h < 2; ++h)
                b[qc * 2 + j2][h] = *(const short8*)&Bs[bi][(wc >> 1) * 8192 +
                    ((wc & 1) * 64 + (qc * 2 + j2) * 16 + r15) * 64 +
                    ((h * 32 + ksel * 8) ^ rsw)];
    };

    f32x4 acc[8][4] = {};

    stageA(0, 0, 0); stageA(0, 0, 1); stageB(0, 0, 0); stageB(0, 0, 1);
    stageB(1, 1, 0); stageB(1, 1, 1);
    VMW(4);
    BARX;

    for (int it = 0; it < nIt; ++it) {
        const int kt1 = 2 * it + 1;
        const bool last = (it == nIt - 1);
        loadA4(0, 0); loadB2q(0, 0); stageA(kt1, 1, 0);
        BARX; MQ256(0, 0); BARX;
        loadB2q(0, 1); stageA(kt1, 1, 1);
        BARX; MQ256(0, 1); BARX;
        loadA4(0, 1); if (!last) stageB(kt1 + 1, 0, 0);
        BARX; MQ256(1, 0); BARX;
        if (!last) stageB(kt1 + 1, 0, 1);
        BARX; MQ256(1, 1);
        if (last) { VMW(0); } else { VMW(4); }
        BARX;
        loadA4(1, 0); loadB2q(1, 0); if (!last) stageA(kt1 + 1, 0, 0);
        BARX; MQ256(0, 0); BARX;
        loadB2q(1, 1); if (!last) stageA(kt1 + 1, 0, 1);
        BARX; MQ256(0, 1); BARX;
        loadA4(1, 1); if (!last) stageB(kt1 + 2, 1, 0);
        BARX; MQ256(1, 0); BARX;
        if (!last) stageB(kt1 + 2, 1, 1);
        BARX; MQ256(1, 1);
        if (!last) { VMW(4); }
        BARX;
    }

    float bv[4];
    #pragma unroll
    for (int fc = 0; fc < 4; ++fc)
        bv[fc] = bias ? bias[bn + wc * 64 + fc * 16 + r15] : 0.0f;

    #pragma unroll
    for (int fr = 0; fr < 8; ++fr) {
        #pragma unroll
        for (int q2 = 0; q2 < 4; ++q2) {
            int row = bm + wr * 128 + fr * 16 + ksel * 4 + q2;
            if (row >= M) continue;
            #pragma unroll
            for (int fc = 0; fc < 4; ++fc) {
                int col = bn + wc * 64 + fc * 16 + r15;
                float v = acc[fr][fc][q2] + bv[fc];
                size_t off = (size_t)row * Nc + col;
                if (accumulate) v += Cf[off];
                if (do_relu) v = fmaxf(v, 0.0f);
                if (Cf) Cf[off] = v;
                if (Cb) Cb[off] = __float2bfloat16(v);
            }
        }
    }
}

// ======== 8-phase 128x128 4-wave GEMM (layer 2, Nc=1152) — verified R8 kernel ========
#define TBM 128
#define TBN 128
#define TBK 64

#define MFMA_Q(QR, QC) do {                                                        \
    __builtin_amdgcn_s_setprio(1);                                                 \
    _Pragma("unroll") for (int i2 = 0; i2 < 2; ++i2)                               \
    _Pragma("unroll") for (int j2 = 0; j2 < 2; ++j2)                               \
    _Pragma("unroll") for (int h = 0; h < 2; ++h)                                  \
        acc[(QR)*2 + i2][(QC)*2 + j2] = __builtin_amdgcn_mfma_f32_16x16x32_bf16(   \
            a[i2][h], b[(QC)*2 + j2][h], acc[(QR)*2 + i2][(QC)*2 + j2], 0, 0, 0);  \
    __builtin_amdgcn_s_setprio(0); } while (0)

__global__ __launch_bounds__(256, 2) void gemm8p_kernel(
    const __hip_bfloat16* __restrict__ A1, int K1, int lda1,
    const __hip_bfloat16* __restrict__ A2, int K2, int lda2,
    const __hip_bfloat16* __restrict__ BTa, const __hip_bfloat16* __restrict__ BTb, int ldbt,
    const float* __restrict__ bias,
    float* __restrict__ Cf, __hip_bfloat16* __restrict__ Cb,
    int M, int Nc, int accumulate, int do_relu,
    int gridX, int nwg)
{
    __shared__ __align__(16) __hip_bfloat16 As[2][TBM * TBK];
    __shared__ __align__(16) __hip_bfloat16 Bs[2][TBN * TBK];

    int bid = blockIdx.x;
    int qq = nwg >> 3, rr = nwg & 7;
    int xcd = bid & 7, ii = bid >> 3;
    int wg = (xcd < rr ? xcd * (qq + 1) : rr * (qq + 1) + (xcd - rr) * qq) + ii;
    const int bm = (wg / gridX) * TBM;
    const int bn = (wg % gridX) * TBN;

    const int tid  = threadIdx.x;
    const int lane = tid & 63;
    const int wv   = tid >> 6;
    const int wr   = wv >> 1;
    const int wc   = wv & 1;
    const int r15  = lane & 15;
    const int ksel = lane >> 4;
    const int rsw  = (r15 & 7) << 3;

    const int srow = tid >> 3;
    const int swz8 = ((tid & 7) ^ (srow & 7)) * 8;

    const int Ktot = K1 + K2;
    const int nT   = Ktot / TBK;
    const int nIt  = nT / 2;

    auto stageA = [&](int kt, int bi, int c0) {
        int k0 = kt * TBK;
        const __hip_bfloat16* base = A1; int ld = lda1;
        if (k0 >= K1) { base = A2; ld = lda2; k0 -= K1; }
        #pragma unroll
        for (int c = c0; c < c0 + 2; ++c) {
            int gr = bm + c * 32 + srow; if (gr >= M) gr = M - 1;
            const __hip_bfloat16* gp = base + (size_t)gr * ld + k0 + swz8;
            __builtin_amdgcn_global_load_lds(
                (const __attribute__((address_space(1))) void*)gp,
                (__attribute__((address_space(3))) void*)&As[bi][c * 2048 + tid * 8], 16, 0, 0);
        }
    };
    auto stageB = [&](int kt, int bi, int c0) {
        int k0 = kt * TBK;
        const __hip_bfloat16* base = BTa;
        if (k0 >= K1) { base = BTb; k0 -= K1; }
        #pragma unroll
        for (int c = c0; c < c0 + 2; ++c) {
            int n0 = bn + c * 32 + srow;
            const __hip_bfloat16* gp = base + (size_t)n0 * ldbt + k0 + swz8;
            __builtin_amdgcn_global_load_lds(
                (const __attribute__((address_space(1))) void*)gp,
                (__attribute__((address_space(3))) void*)&Bs[bi][c * 2048 + tid * 8], 16, 0, 0);
        }
    };

    short8 a[2][2], b[4][2];
    auto loadA2 = [&](int bi, int fr0) {
        #pragma unroll
        for (int i2 = 0; i2 < 2; ++i2)
            #pragma unroll
            for (int h = 0; h < 2; ++h)
                a[i2][h] = *(const short8*)&As[bi][(wr * 64 + (fr0 + i2) * 16 + r15) * 64 +
                                                   ((h * 32 + ksel * 8) ^ rsw)];
    };
    auto loadB2 = [&](int bi, int fc0) {
        #pragma unroll
        for (int j2 = 0; j2 < 2; ++j2)
            #pragma unroll
            for (int h = 0; h < 2; ++h)
                b[fc0 + j2][h] = *(const short8*)&Bs[bi][(wc * 64 + (fc0 + j2) * 16 + r15) * 64 +
                                                         ((h * 32 + ksel * 8) ^ rsw)];
    };

    f32x4 acc[4][4] = {};

    stageA(0, 0, 0); stageA(0, 0, 2); stageB(0, 0, 0); stageB(0, 0, 2);
    stageB(1, 1, 0); stageB(1, 1, 2);
    VMW(4);
    BARX;

    for (int it = 0; it < nIt; ++it) {
        const int kt0 = 2 * it, kt1 = 2 * it + 1;
        const bool last = (it == nIt - 1);
        loadA2(0, 0); loadB2(0, 0); stageA(kt1, 1, 0);
        BARX; MFMA_Q(0, 0); BARX;
        loadB2(0, 2); stageA(kt1, 1, 2);
        BARX; MFMA_Q(0, 1); BARX;
        loadA2(0, 2); if (!last) stageB(kt0 + 2, 0, 0);
        BARX; MFMA_Q(1, 0); BARX;
        if (!last) stageB(kt0 + 2, 0, 2);
        BARX; MFMA_Q(1, 1);
        if (last) { VMW(0); } else { VMW(4); }
        BARX;
        loadA2(1, 0); loadB2(1, 0); if (!last) stageA(kt0 + 2, 0, 0);
        BARX; MFMA_Q(0, 0); BARX;
        loadB2(1, 2); if (!last) stageA(kt0 + 2, 0, 2);
        BARX; MFMA_Q(0, 1); BARX;
        loadA2(1, 2); if (!last) stageB(kt1 + 2, 1, 0);
        BARX; MFMA_Q(1, 0); BARX;
        if (!last) stageB(kt1 + 2, 1, 2);
        BARX; MFMA_Q(1, 1);
        if (!last) { VMW(4); }
        BARX;
    }

    float bv[4];
    #pragma unroll
    for (int fc = 0; fc < 4; ++fc)
        bv[fc] = bias ? bias[bn + wc * 64 + fc * 16 + r15] : 0.0f;

    #pragma unroll
    for (int fr = 0; fr < 4; ++fr) {
        #pragma unroll
        for (int q2 = 0; q2 < 4; ++q2) {
            int row = bm + wr * 64 + fr * 16 + ksel * 4 + q2;
            if (row >= M) continue;
            #pragma unroll
            for (int fc = 0; fc < 4; ++fc) {
                int col = bn + wc * 64 + fc * 16 + r15;
                float v = acc[fr][fc][q2] + bv[fc];
                size_t off = (size_t)row * Nc + col;
                if (accumulate) v += Cf[off];
                if (do_relu) v = fmaxf(v, 0.0f);
                if (Cf) Cf[off] = v;
                if (Cb) Cb[off] = __float2bfloat16(v);
            }
        }
    }
}

extern "C" void kernel_launch(void* const* d_in, const int* in_sizes, int n_in,
                              void* d_out, int out_size, void* d_ws, size_t ws_size,
                              hipStream_t stream) {
    const float* x     = (const float*)d_in[0];
    const void*  eidx  = d_in[1];
    const void*  etype = d_in[2];
    const float* w1    = (const float*)d_in[3];
    const float* root1 = (const float*)d_in[4];
    const float* b1    = (const float*)d_in[5];
    const float* w2    = (const float*)d_in[6];
    const float* root2 = (const float*)d_in[7];
    const float* b2    = (const float*)d_in[8];

    float* h_out = (float*)d_out;
    float* emb   = (float*)d_out + (size_t)N_NODES * F_OUT;

    char* ws = (char*)d_ws;
    size_t off = 0;
    auto take = [&](size_t bytes) { char* p = ws + off; off = (off + bytes + 255) & ~(size_t)255; return p; };
    int*      flag    = (int*)take(256);
    unsigned* cnt8    = (unsigned*)take((size_t)NSEG * 4);
    float*    invc    = (float*)take((size_t)NSEG * 4);
    int*      soff    = (int*)take(((size_t)NSEG + 1) * 4);
    int*      cursor  = (int*)take((size_t)NSEG * 4);
    int*      bsum    = (int*)take((size_t)SCAN_NB * 4);
    unsigned* ebuf    = (unsigned*)take((size_t)N_EDGES * 4);
    __hip_bfloat16* xb   = (__hip_bfloat16*)take((size_t)N_NODES * F_IN * 2);
    __hip_bfloat16* embb = (__hip_bfloat16*)take((size_t)N_NODES * F_HID * 2);
    __hip_bfloat16* bt1  = (__hip_bfloat16*)take((size_t)F_HID * (N_REL * F_IN + F_IN) * 2);
    __hip_bfloat16* bt2  = (__hip_bfloat16*)take((size_t)NC2 * F_HID * 2);

    size_t avail = (ws_size > off) ? (ws_size - off) : 0;
    size_t agg8bytes = (size_t)N_NODES * N_REL * F_IN * 2;
    size_t zbytes    = (size_t)N_NODES * NC2 * 2;
    int CR = (avail >= agg8bytes) ? 8 : 4;
    size_t ubytes = agg8bytes > zbytes ? agg8bytes : zbytes;
    if (CR == 4) ubytes = zbytes;
    char* uni = take(ubytes);
    __hip_bfloat16* aggb = (__hip_bfloat16*)uni;
    __hip_bfloat16* z    = (__hip_bfloat16*)uni;

    detect64_kernel<<<1, 64, 0, stream>>>((const int*)etype, flag);
    (void)hipMemsetAsync(cnt8, 0, (size_t)NSEG * 4, stream);
    (void)hipMemsetAsync(cursor, 0, (size_t)NSEG * 4, stream);
    count_kernel<<<(N_EDGES + 255) / 256, 256, 0, stream>>>(etype, eidx, flag, cnt8);
    scan1_kernel<<<SCAN_NB, 1024, 0, stream>>>(cnt8, invc, soff, bsum);
    scan2_kernel<<<1, 512, 0, stream>>>(bsum);
    scan3_kernel<<<(NSEG + 1023) / 1024, 1024, 0, stream>>>(soff, bsum);
    build_kernel<<<(N_EDGES + 255) / 256, 256, 0, stream>>>(eidx, etype, flag, soff, cursor, ebuf);

    cvt_bf16_kernel<<<(N_NODES * F_IN / 4 + 255) / 256, 256, 0, stream>>>(
        x, xb, (long long)N_NODES * F_IN / 4);
    {
        int tot = F_HID * (N_REL * F_IN + F_IN);
        make_bt1_kernel<<<(tot + 255) / 256, 256, 0, stream>>>(w1, root1, bt1);
        tot = NC2 * F_HID;
        make_bt2_kernel<<<(tot + 255) / 256, 256, 0, stream>>>(w2, root2, bt2);
    }

    const int MBLK  = (N_NODES + TBM - 1) / TBM;      // 391 (128 tile)
    const int MBLKQ = (N_NODES + QBM - 1) / QBM;      // 196 (256 tile)
    const int GWAVE_BLOCKS = (N_NODES * 64 + 255) / 256;

    // ---------------- layer 1 (256x256 8-wave 8-phase GEMM) ----------------
    for (int r0 = 0; r0 < N_REL; r0 += CR) {
        if (CR == 8)
            gather1_kernel<8><<<GWAVE_BLOCKS, 256, 0, stream>>>(xb, ebuf, soff, invc, aggb, r0);
        else
            gather1_kernel<4><<<GWAVE_BLOCKS, 256, 0, stream>>>(xb, ebuf, soff, invc, aggb, r0);
        int first = (r0 == 0), last = (r0 + CR >= N_REL);
        int gX = F_HID / QBN, nwg = gX * MBLKQ;
        gemm256_kernel<<<nwg, 512, 0, stream>>>(
            aggb, CR * F_IN, CR * F_IN,
            first ? xb : nullptr, first ? F_IN : 0, F_IN,
            bt1 + (size_t)r0 * F_IN, bt1 + (size_t)N_REL * F_IN, N_REL * F_IN + F_IN,
            first ? b1 : nullptr,
            emb, last ? embb : nullptr,
            N_NODES, F_HID, first ? 0 : 1, last ? 1 : 0,
            gX, nwg);
    }

    // ---------------- layer 2 (128x128 8-phase GEMM, Nc=1152) ----------------
    {
        int gX = NC2 / TBN, nwg = gX * MBLK;
        gemm8p_kernel<<<nwg, 256, 0, stream>>>(
            embb, F_HID, F_HID, nullptr, 0, 0,
            bt2, nullptr, F_HID,
            nullptr, nullptr, z, N_NODES, NC2, 0, 0,
            gX, nwg);
    }

    gather2_kernel<<<GWAVE_BLOCKS, 256, 0, stream>>>(z, ebuf, soff, invc, b2, h_out);
}